// Round 1
// baseline (3547.214 us; speedup 1.0000x reference)
//
#include <hip/hip_runtime.h>
#include <cstdint>
#include <cstddef>

// ---------------- constants ----------------
static const int B_ = 32, N_ = 512, C_ = 1024, C2_ = 1026, CC2_ = 2052;
static const int S0_ = 256, S1_ = 64, K_ = 16, OUT_ = 3584;

// ---------------- transpose feat_map (C,H,W) -> (H*W, C) ----------------
__global__ __launch_bounds__(256) void k_transpose_fm(const float* __restrict__ f,
                                                      float* __restrict__ fmT) {
  int o = blockIdx.x * 256 + threadIdx.x;  // o = yx*1024 + c
  int c = o & 1023, yx = o >> 10;
  fmT[o] = f[c * 1024 + yx];
}

// ---------------- bilinear sample -> X0 rows [feat(1024) | p0 | p1] ----------------
__global__ __launch_bounds__(256) void k_bilinear(const float* __restrict__ points,
                                                  const float* __restrict__ fmT,
                                                  float* __restrict__ X0) {
  int r = blockIdx.x;  // b*512+n
  float p0 = points[r * 2 + 0], p1 = points[r * 2 + 1];
  // grid = 2*p[::-1]-1 ; x from p1, y from p0 ; exact op-order, no contraction
  float g0 = __fsub_rn(__fmul_rn(2.0f, p1), 1.0f);
  float g1 = __fsub_rn(__fmul_rn(2.0f, p0), 1.0f);
  float x = __fmul_rn(__fmul_rn(__fadd_rn(g0, 1.0f), 0.5f), 31.0f);
  float y = __fmul_rn(__fmul_rn(__fadd_rn(g1, 1.0f), 0.5f), 31.0f);
  float x0f = floorf(x), y0f = floorf(y);
  float wx = __fsub_rn(x, x0f), wy = __fsub_rn(y, y0f);
  int x0i = (int)fminf(fmaxf(x0f, 0.f), 31.f);
  int x1i = (int)fminf(fmaxf(__fadd_rn(x0f, 1.f), 0.f), 31.f);
  int y0i = (int)fminf(fmaxf(y0f, 0.f), 31.f);
  int y1i = (int)fminf(fmaxf(__fadd_rn(y0f, 1.f), 0.f), 31.f);
  float omwx = __fsub_rn(1.f, wx), omwy = __fsub_rn(1.f, wy);
  size_t i00 = (size_t)(y0i * 32 + x0i) * 1024;
  size_t i01 = (size_t)(y0i * 32 + x1i) * 1024;
  size_t i10 = (size_t)(y1i * 32 + x0i) * 1024;
  size_t i11 = (size_t)(y1i * 32 + x1i) * 1024;
  int t = threadIdx.x;
  float* xr = X0 + (size_t)r * C2_;
#pragma unroll
  for (int i = 0; i < 4; i++) {
    int c = t + 256 * i;
    float f00 = fmT[i00 + c], f01 = fmT[i01 + c], f10 = fmT[i10 + c], f11 = fmT[i11 + c];
    float t1 = f00 * omwx * omwy;
    float t2 = f01 * wx * omwy;
    float t3 = f10 * omwx * wy;
    float t4 = f11 * wx * wy;
    xr[c] = ((t1 + t2) + t3) + t4;
  }
  if (t == 0) { xr[1024] = p0; xr[1025] = p1; }
}

// ---------------- dvec[c] = sum_d db[d]*aw[c,d] ----------------
__global__ __launch_bounds__(256) void k_dvec(const float* __restrict__ db,
                                              const float* __restrict__ aw,
                                              float* __restrict__ dvec) {
  int c = blockIdx.x * 256 + threadIdx.x;
  if (c >= C_) return;
  float s = 0.f;
  const float* wr = aw + (size_t)c * CC2_;
  for (int d = 0; d < C2_; d++) s += db[d] * wr[d];
  dvec[c] = s;
}

// ---------------- FPS: one wave per batch ----------------
template <int NPL>
__global__ __launch_bounds__(64) void k_fps(int Np, int nsub, const float* __restrict__ pts,
                                            int stride, int* __restrict__ out_idx) {
  int b = blockIdx.x;
  int lane = threadIdx.x;
  const float* pb = pts + (size_t)b * Np * stride;
  float px[NPL], py[NPL], dist[NPL];
#pragma unroll
  for (int i = 0; i < NPL; i++) {
    int j = lane + 64 * i;
    px[i] = pb[(size_t)j * stride + 0];
    py[i] = pb[(size_t)j * stride + 1];
    dist[i] = 1e10f;
  }
  int far = 0;
  for (int s = 0; s < nsub; s++) {
    if (lane == 0) out_idx[b * nsub + s] = far;
    float fx = pb[(size_t)far * stride + 0];
    float fy = pb[(size_t)far * stride + 1];
    float bv = -INFINITY; int bi = 0x7fffffff;
#pragma unroll
    for (int i = 0; i < NPL; i++) {
      float dx = __fsub_rn(px[i], fx), dy = __fsub_rn(py[i], fy);
      float d = __fadd_rn(__fmul_rn(dx, dx), __fmul_rn(dy, dy));
      dist[i] = fminf(dist[i], d);
      int j = lane + 64 * i;
      if (dist[i] > bv || (dist[i] == bv && j < bi)) { bv = dist[i]; bi = j; }
    }
#pragma unroll
    for (int off = 32; off; off >>= 1) {
      float ov = __shfl_xor(bv, off);
      int oi = __shfl_xor(bi, off);
      if (ov > bv || (ov == bv && oi < bi)) { bv = ov; bi = oi; }
    }
    far = bi;
  }
}

// ---------------- rows[r] = (r/S)*Np + fps[r] ----------------
__global__ __launch_bounds__(256) void k_make_rows(int S, int Np, const int* __restrict__ fps,
                                                   int* __restrict__ rows) {
  int r = blockIdx.x * 256 + threadIdx.x;
  rows[r] = (r / S) * Np + fps[r];
}

// ---------------- kNN: one wave per (b,s); k smallest with stable tie-break ----------------
template <int NPL>
__global__ __launch_bounds__(64) void k_knn(int S, int Np, const float* __restrict__ pts,
                                            int stride, const int* __restrict__ rows,
                                            int* __restrict__ nn) {
  int bs = blockIdx.x;
  int b = bs / S;
  int lane = threadIdx.x;
  const float* pb = pts + (size_t)b * Np * stride;
  int arow = rows[bs];
  float ax = pts[(size_t)arow * stride + 0];
  float ay = pts[(size_t)arow * stride + 1];
  float d2[NPL];
#pragma unroll
  for (int i = 0; i < NPL; i++) {
    int j = lane + 64 * i;
    float dx = __fsub_rn(ax, pb[(size_t)j * stride + 0]);
    float dy = __fsub_rn(ay, pb[(size_t)j * stride + 1]);
    d2[i] = __fadd_rn(__fmul_rn(dx, dx), __fmul_rn(dy, dy));
  }
  unsigned mask = 0;
  for (int k = 0; k < K_; k++) {
    float bv = INFINITY; int bi = 0x7fffffff;
#pragma unroll
    for (int i = 0; i < NPL; i++) {
      int j = lane + 64 * i;
      bool used = (mask >> i) & 1u;
      if (!used && (d2[i] < bv || (d2[i] == bv && j < bi))) { bv = d2[i]; bi = j; }
    }
#pragma unroll
    for (int off = 32; off; off >>= 1) {
      float ov = __shfl_xor(bv, off);
      int oi = __shfl_xor(bi, off);
      if (ov < bv || (ov == bv && oi < bi)) { bv = ov; bi = oi; }
    }
    if ((bi & 63) == lane) mask |= 1u << (bi >> 6);
    if (lane == 0) nn[bs * K_ + k] = bi;
  }
}

// ---------------- generic f32 GEMM: C[M,N] = A(rowidx)[M,K] dot W[N, woff+K] (+bias) ----------------
// 64x64 tile, 256 threads, 4x4 micro-tile, K-tile 16. gridDim.z>1 -> partial slabs.
__global__ __launch_bounds__(256) void k_gemm(int M, int N, int K, const float* __restrict__ A,
                                              int lda, const int* __restrict__ rowidx,
                                              const float* __restrict__ W, int ldw, int woff,
                                              const float* __restrict__ bias,
                                              float* __restrict__ C, int ldc, int kchunk) {
  __shared__ float As[16][64];
  __shared__ float Bs[16][64];
  int t = threadIdx.x;
  int tx = t & 15, ty = t >> 4;
  int col0 = blockIdx.x * 64, row0 = blockIdx.y * 64;
  int k0 = blockIdx.z * kchunk;
  int k1 = min(K, k0 + kchunk);
  float* Cp = C;
  if (gridDim.z > 1) Cp += (size_t)blockIdx.z * M * ldc;
  float acc[4][4] = {{0.f}};
  int lr = t >> 2, lq = t & 3;
  for (int kt = k0; kt < k1; kt += 16) {
    int kk = kt + lq * 4;
    {
      int r = row0 + lr;
      float vx = 0.f, vy = 0.f, vz = 0.f, vw = 0.f;
      if (r < M) {
        int garow = rowidx ? rowidx[r] : r;
        const float* ap = A + (size_t)garow * lda + kk;
        if (kk + 0 < k1) vx = ap[0];
        if (kk + 1 < k1) vy = ap[1];
        if (kk + 2 < k1) vz = ap[2];
        if (kk + 3 < k1) vw = ap[3];
      }
      As[lq * 4 + 0][lr] = vx; As[lq * 4 + 1][lr] = vy;
      As[lq * 4 + 2][lr] = vz; As[lq * 4 + 3][lr] = vw;
      int cix = col0 + lr;
      float wx = 0.f, wy = 0.f, wz = 0.f, ww = 0.f;
      if (cix < N) {
        const float* wp = W + (size_t)cix * ldw + woff + kk;
        if (kk + 0 < k1) wx = wp[0];
        if (kk + 1 < k1) wy = wp[1];
        if (kk + 2 < k1) wz = wp[2];
        if (kk + 3 < k1) ww = wp[3];
      }
      Bs[lq * 4 + 0][lr] = wx; Bs[lq * 4 + 1][lr] = wy;
      Bs[lq * 4 + 2][lr] = wz; Bs[lq * 4 + 3][lr] = ww;
    }
    __syncthreads();
#pragma unroll
    for (int kkk = 0; kkk < 16; kkk++) {
      float4 a4 = *(const float4*)&As[kkk][ty << 2];
      float4 b4 = *(const float4*)&Bs[kkk][tx << 2];
      float av[4] = {a4.x, a4.y, a4.z, a4.w};
      float bv[4] = {b4.x, b4.y, b4.z, b4.w};
#pragma unroll
      for (int i = 0; i < 4; i++)
#pragma unroll
        for (int j = 0; j < 4; j++) acc[i][j] += av[i] * bv[j];
    }
    __syncthreads();
  }
  bool addb = (bias != nullptr) && (gridDim.z == 1);
#pragma unroll
  for (int i = 0; i < 4; i++) {
    int r = row0 + (ty << 2) + i;
    if (r >= M) continue;
#pragma unroll
    for (int j = 0; j < 4; j++) {
      int c = col0 + (tx << 2) + j;
      if (c >= N) continue;
      float o = acc[i][j];
      if (addb) o += bias[c];
      Cp[(size_t)r * ldc + c] = o;
    }
  }
}

// ---------------- fused stage: gather G + base, relu, LN, max over k ----------------
__global__ __launch_bounds__(256) void k_fused_stage(
    int S, int Np, const float* __restrict__ G, const float* __restrict__ P,
    const float* __restrict__ dvec, const int* __restrict__ rows, const int* __restrict__ nn,
    const float* __restrict__ lng, const float* __restrict__ lnb,
    const float* __restrict__ prev_pts, int pts_stride, float* __restrict__ Xout, int ld_out) {
  int bs = blockIdx.x;
  int b = bs / S;
  int t = threadIdx.x;
  int arow = rows[bs];
  float base[4], acc[4];
#pragma unroll
  for (int i = 0; i < 4; i++) {
    int c = t + 256 * i;
    base[i] = P[(size_t)bs * C_ + c] - G[(size_t)arow * C_ + c] + dvec[c];
    acc[i] = -INFINITY;
  }
  __shared__ float red[2][4];
  int lane = t & 63, w = t >> 6;
  for (int k = 0; k < K_; k++) {
    int g = nn[bs * K_ + k];
    const float* Gr = G + (size_t)(b * Np + g) * C_;
    float v[4];
    float s1 = 0.f, s2 = 0.f;
#pragma unroll
    for (int i = 0; i < 4; i++) {
      float x = Gr[t + 256 * i] + base[i];
      x = fmaxf(x, 0.f);
      v[i] = x;
      s1 += x;
      s2 += x * x;
    }
#pragma unroll
    for (int off = 32; off; off >>= 1) {
      s1 += __shfl_xor(s1, off);
      s2 += __shfl_xor(s2, off);
    }
    if (lane == 0) { red[0][w] = s1; red[1][w] = s2; }
    __syncthreads();
    float fs1 = red[0][0] + red[0][1] + red[0][2] + red[0][3];
    float fs2 = red[1][0] + red[1][1] + red[1][2] + red[1][3];
    __syncthreads();
    float mu = fs1 * (1.f / 1024.f);
    float var = fs2 * (1.f / 1024.f) - mu * mu;
    float rstd = 1.f / sqrtf(var + 1e-5f);
#pragma unroll
    for (int i = 0; i < 4; i++) {
      int c = t + 256 * i;
      float nv = (v[i] - mu) * rstd * lng[c] + lnb[c];
      acc[i] = fmaxf(acc[i], nv);
    }
  }
#pragma unroll
  for (int i = 0; i < 4; i++) Xout[(size_t)bs * ld_out + t + 256 * i] = acc[i];
  if (prev_pts && t == 0) {
    Xout[(size_t)bs * ld_out + 1024] = prev_pts[(size_t)arow * pts_stride + 0];
    Xout[(size_t)bs * ld_out + 1025] = prev_pts[(size_t)arow * pts_stride + 1];
  }
}

// ---------------- reduce K-split partials + bias ----------------
__global__ __launch_bounds__(256) void k_reduce(int total, int Ncols, int nz,
                                                const float* __restrict__ part,
                                                const float* __restrict__ bias,
                                                float* __restrict__ out) {
  int i = blockIdx.x * 256 + threadIdx.x;
  if (i >= total) return;
  float s = bias[i % Ncols];
  for (int z = 0; z < nz; z++) s += part[(size_t)z * total + i];
  out[i] = s;
}

// ---------------- launch ----------------
extern "C" void kernel_launch(void* const* d_in, const int* in_sizes, int n_in, void* d_out,
                              int out_size, void* d_ws, size_t ws_size, hipStream_t stream) {
  (void)in_sizes; (void)n_in; (void)out_size; (void)ws_size;
  const float* points = (const float*)d_in[0];
  const float* feat_map = (const float*)d_in[1];
  const float* dw0 = (const float*)d_in[2];
  const float* db0 = (const float*)d_in[3];
  const float* aw0 = (const float*)d_in[4];
  const float* ab0 = (const float*)d_in[5];
  const float* lg0 = (const float*)d_in[6];
  const float* lb0 = (const float*)d_in[7];
  const float* dw1 = (const float*)d_in[8];
  const float* db1 = (const float*)d_in[9];
  const float* aw1 = (const float*)d_in[10];
  const float* ab1 = (const float*)d_in[11];
  const float* lg1 = (const float*)d_in[12];
  const float* lb1 = (const float*)d_in[13];
  const float* fw = (const float*)d_in[14];
  const float* fb = (const float*)d_in[15];
  const float* dmw = (const float*)d_in[16];
  const float* dmb = (const float*)d_in[17];
  float* out = (float*)d_out;

  char* wsb = (char*)d_ws;
  size_t off = 0;
  auto alloc = [&](size_t bytes) -> void* {
    void* p = wsb + off;
    off = (off + bytes + 255) & ~(size_t)255;
    return p;
  };
  float* fmT = (float*)alloc((size_t)1024 * 1024 * 4);
  float* X0 = (float*)alloc((size_t)B_ * N_ * C2_ * 4);
  float* F0 = (float*)alloc((size_t)B_ * N_ * C2_ * 4);
  float* G0 = (float*)alloc((size_t)B_ * N_ * C_ * 4);
  float* P0 = (float*)alloc((size_t)B_ * S0_ * C_ * 4);
  float* fts2 = (float*)alloc((size_t)B_ * S1_ * C_ * 4);
  float* dv0 = (float*)alloc(1024 * 4);
  float* dv1 = (float*)alloc(1024 * 4);
  int* fps0 = (int*)alloc(B_ * S0_ * 4);
  int* rows0 = (int*)alloc(B_ * S0_ * 4);
  int* nn0 = (int*)alloc(B_ * S0_ * K_ * 4);
  int* fps1 = (int*)alloc(B_ * S1_ * 4);
  int* rows1 = (int*)alloc(B_ * S1_ * 4);
  int* nn1 = (int*)alloc(B_ * S1_ * K_ * 4);
  float* hpart = (float*)alloc((size_t)32 * B_ * C_ * 4);
  float* hid = (float*)alloc((size_t)B_ * C_ * 4);
  float* opart = (float*)alloc((size_t)4 * B_ * OUT_ * 4);
  // aliases (stage-0 buffers are dead by the time stage-1 writes them)
  float* X1 = X0;
  float* F1 = F0;
  float* G1 = G0;
  float* P1 = P0;

  k_transpose_fm<<<4096, 256, 0, stream>>>(feat_map, fmT);
  k_bilinear<<<B_ * N_, 256, 0, stream>>>(points, fmT, X0);
  k_dvec<<<4, 256, 0, stream>>>(db0, aw0, dv0);
  k_dvec<<<4, 256, 0, stream>>>(db1, aw1, dv1);

  // ---- stage 0 ----
  k_fps<8><<<B_, 64, 0, stream>>>(N_, S0_, points, 2, fps0);
  k_make_rows<<<(B_ * S0_) / 256, 256, 0, stream>>>(S0_, N_, fps0, rows0);
  k_knn<8><<<B_ * S0_, 64, 0, stream>>>(S0_, N_, points, 2, rows0, nn0);
  {
    dim3 g((C2_ + 63) / 64, (B_ * N_ + 63) / 64, 1);
    k_gemm<<<g, 256, 0, stream>>>(B_ * N_, C2_, C2_, X0, C2_, nullptr, dw0, C2_, 0, nullptr, F0,
                                  C2_, C2_);
  }
  {
    dim3 g((C_ + 63) / 64, (B_ * S0_ + 63) / 64, 1);
    k_gemm<<<g, 256, 0, stream>>>(B_ * S0_, C_, C2_, X0, C2_, rows0, aw0, CC2_, C2_, ab0, P0, C_,
                                  C2_);
  }
  {
    dim3 g((C_ + 63) / 64, (B_ * N_ + 63) / 64, 1);
    k_gemm<<<g, 256, 0, stream>>>(B_ * N_, C_, C2_, F0, C2_, nullptr, aw0, CC2_, 0, nullptr, G0,
                                  C_, C2_);
  }
  k_fused_stage<<<B_ * S0_, 256, 0, stream>>>(S0_, N_, G0, P0, dv0, rows0, nn0, lg0, lb0, points,
                                              2, X1, C2_);

  // ---- stage 1 ----
  k_fps<4><<<B_, 64, 0, stream>>>(S0_, S1_, X1 + 1024, C2_, fps1);
  k_make_rows<<<(B_ * S1_) / 256, 256, 0, stream>>>(S1_, S0_, fps1, rows1);
  k_knn<4><<<B_ * S1_, 64, 0, stream>>>(S1_, S0_, X1 + 1024, C2_, rows1, nn1);
  {
    dim3 g((C2_ + 63) / 64, (B_ * S0_ + 63) / 64, 1);
    k_gemm<<<g, 256, 0, stream>>>(B_ * S0_, C2_, C2_, X1, C2_, nullptr, dw1, C2_, 0, nullptr, F1,
                                  C2_, C2_);
  }
  {
    dim3 g((C_ + 63) / 64, (B_ * S1_ + 63) / 64, 1);
    k_gemm<<<g, 256, 0, stream>>>(B_ * S1_, C_, C2_, X1, C2_, rows1, aw1, CC2_, C2_, ab1, P1, C_,
                                  C2_);
  }
  {
    dim3 g((C_ + 63) / 64, (B_ * S0_ + 63) / 64, 1);
    k_gemm<<<g, 256, 0, stream>>>(B_ * S0_, C_, C2_, F1, C2_, nullptr, aw1, CC2_, 0, nullptr, G1,
                                  C_, C2_);
  }
  k_fused_stage<<<B_ * S1_, 256, 0, stream>>>(S1_, S0_, G1, P1, dv1, rows1, nn1, lg1, lb1,
                                              nullptr, 0, fts2, C_);

  // ---- heads ----
  {
    dim3 g((C_ + 63) / 64, 1, 32);  // K-split 32 x 2048
    k_gemm<<<g, 256, 0, stream>>>(B_, C_, C_ * S1_, fts2, C_ * S1_, nullptr, fw, C_ * S1_, 0,
                                  nullptr, hpart, C_, 2048);
  }
  k_reduce<<<(B_ * C_ + 255) / 256, 256, 0, stream>>>(B_ * C_, C_, 32, hpart, fb, hid);
  {
    dim3 g((OUT_ + 63) / 64, 1, 4);  // K-split 4 x 256
    k_gemm<<<g, 256, 0, stream>>>(B_, OUT_, C_, hid, C_, nullptr, dmw, C_, 0, nullptr, opart,
                                  OUT_, 256);
  }
  k_reduce<<<(B_ * OUT_ + 255) / 256, 256, 0, stream>>>(B_ * OUT_, OUT_, 4, opart, dmb, out);
}

// Round 2
// 1097.270 us; speedup vs baseline: 3.2328x; 3.2328x over previous
//
#include <hip/hip_runtime.h>
#include <cstdint>
#include <cstddef>

// ---------------- constants ----------------
static const int B_ = 32, N_ = 512, C_ = 1024, C2_ = 1026, CC2_ = 2052;
static const int S0_ = 256, S1_ = 64, K_ = 16, OUT_ = 3584;
static const int LDP_ = 1152;  // padded C2 (multiple of 128 and 32)

typedef unsigned short ushort;
typedef __attribute__((ext_vector_type(8))) short short8;
typedef __attribute__((ext_vector_type(4))) float f32x4;

__device__ __forceinline__ ushort f2bf(float x) {
  unsigned u = __float_as_uint(x);
  unsigned r = (u + 0x7fffu + ((u >> 16) & 1u)) >> 16;
  return (ushort)r;
}

__device__ __forceinline__ void gload16(const void* g, void* l) {
  __builtin_amdgcn_global_load_lds((const __attribute__((address_space(1))) void*)g,
                                   (__attribute__((address_space(3))) void*)l, 16, 0, 0);
}

// ---------------- transpose feat_map (C,H,W) -> (H*W, C) ----------------
__global__ __launch_bounds__(256) void k_transpose_fm(const float* __restrict__ f,
                                                      float* __restrict__ fmT) {
  int o = blockIdx.x * 256 + threadIdx.x;
  int c = o & 1023, yx = o >> 10;
  fmT[o] = f[c * 1024 + yx];
}

// ---------------- bilinear sample -> Xb0 rows bf16 [feat(1024) | p0 p1 | pad0] ----------------
__global__ __launch_bounds__(256) void k_bilinear(const float* __restrict__ points,
                                                  const float* __restrict__ fmT,
                                                  ushort* __restrict__ X0) {
  int r = blockIdx.x;  // b*512+n
  float p0 = points[r * 2 + 0], p1 = points[r * 2 + 1];
  float g0 = __fsub_rn(__fmul_rn(2.0f, p1), 1.0f);
  float g1 = __fsub_rn(__fmul_rn(2.0f, p0), 1.0f);
  float x = __fmul_rn(__fmul_rn(__fadd_rn(g0, 1.0f), 0.5f), 31.0f);
  float y = __fmul_rn(__fmul_rn(__fadd_rn(g1, 1.0f), 0.5f), 31.0f);
  float x0f = floorf(x), y0f = floorf(y);
  float wx = __fsub_rn(x, x0f), wy = __fsub_rn(y, y0f);
  int x0i = (int)fminf(fmaxf(x0f, 0.f), 31.f);
  int x1i = (int)fminf(fmaxf(__fadd_rn(x0f, 1.f), 0.f), 31.f);
  int y0i = (int)fminf(fmaxf(y0f, 0.f), 31.f);
  int y1i = (int)fminf(fmaxf(__fadd_rn(y0f, 1.f), 0.f), 31.f);
  float omwx = __fsub_rn(1.f, wx), omwy = __fsub_rn(1.f, wy);
  size_t i00 = (size_t)(y0i * 32 + x0i) * 1024;
  size_t i01 = (size_t)(y0i * 32 + x1i) * 1024;
  size_t i10 = (size_t)(y1i * 32 + x0i) * 1024;
  size_t i11 = (size_t)(y1i * 32 + x1i) * 1024;
  int t = threadIdx.x;
  ushort* xr = X0 + (size_t)r * LDP_;
#pragma unroll
  for (int i = 0; i < 4; i++) {
    int c = t + 256 * i;
    float f00 = fmT[i00 + c], f01 = fmT[i01 + c], f10 = fmT[i10 + c], f11 = fmT[i11 + c];
    float t1 = f00 * omwx * omwy;
    float t2 = f01 * wx * omwy;
    float t3 = f10 * omwx * wy;
    float t4 = f11 * wx * wy;
    xr[c] = f2bf(((t1 + t2) + t3) + t4);
  }
  if (t == 0) { xr[1024] = f2bf(p0); xr[1025] = f2bf(p1); }
  if (t < 126) xr[1026 + t] = 0;
}

// ---------------- f32 -> bf16 convert with pad (dst [Rp][dld], zero outside R x Ceff) ----------
__global__ __launch_bounds__(256) void k_cvt(const float* __restrict__ src, int sld, int soff,
                                             int R, int Ceff, ushort* __restrict__ dst, int dld,
                                             unsigned total2) {
  unsigned i = blockIdx.x * 256u + threadIdx.x;
  if (i >= total2) return;
  unsigned e = i * 2u;
  unsigned r = e / (unsigned)dld, c = e % (unsigned)dld;
  float v0 = 0.f, v1 = 0.f;
  if ((int)r < R) {
    const float* sp = src + (size_t)r * sld + soff + c;
    if ((int)c < Ceff) v0 = sp[0];
    if ((int)(c + 1) < Ceff) v1 = sp[1];
  }
  unsigned u = (unsigned)f2bf(v0) | ((unsigned)f2bf(v1) << 16);
  *(unsigned*)(dst + e) = u;
}

// ---------------- dvec[c] = sum_d db[d]*aw[c,d] ----------------
__global__ __launch_bounds__(256) void k_dvec(const float* __restrict__ db,
                                              const float* __restrict__ aw,
                                              float* __restrict__ dvec) {
  int c = blockIdx.x * 256 + threadIdx.x;
  if (c >= C_) return;
  float s = 0.f;
  const float* wr = aw + (size_t)c * CC2_;
  for (int d = 0; d < C2_; d++) s += db[d] * wr[d];
  dvec[c] = s;
}

// ---------------- FPS: one wave per batch (exact f32) ----------------
template <int NPL>
__global__ __launch_bounds__(64) void k_fps(int Np, int nsub, const float* __restrict__ pts,
                                            int stride, int* __restrict__ out_idx) {
  int b = blockIdx.x;
  int lane = threadIdx.x;
  const float* pb = pts + (size_t)b * Np * stride;
  float px[NPL], py[NPL], dist[NPL];
#pragma unroll
  for (int i = 0; i < NPL; i++) {
    int j = lane + 64 * i;
    px[i] = pb[(size_t)j * stride + 0];
    py[i] = pb[(size_t)j * stride + 1];
    dist[i] = 1e10f;
  }
  int far = 0;
  for (int s = 0; s < nsub; s++) {
    if (lane == 0) out_idx[b * nsub + s] = far;
    float fx = pb[(size_t)far * stride + 0];
    float fy = pb[(size_t)far * stride + 1];
    float bv = -INFINITY; int bi = 0x7fffffff;
#pragma unroll
    for (int i = 0; i < NPL; i++) {
      float dx = __fsub_rn(px[i], fx), dy = __fsub_rn(py[i], fy);
      float d = __fadd_rn(__fmul_rn(dx, dx), __fmul_rn(dy, dy));
      dist[i] = fminf(dist[i], d);
      int j = lane + 64 * i;
      if (dist[i] > bv || (dist[i] == bv && j < bi)) { bv = dist[i]; bi = j; }
    }
#pragma unroll
    for (int off = 32; off; off >>= 1) {
      float ov = __shfl_xor(bv, off);
      int oi = __shfl_xor(bi, off);
      if (ov > bv || (ov == bv && oi < bi)) { bv = ov; bi = oi; }
    }
    far = bi;
  }
}

// ---------------- rows[r] = (r/S)*Np + fps[r] ----------------
__global__ __launch_bounds__(256) void k_make_rows(int S, int Np, const int* __restrict__ fps,
                                                   int* __restrict__ rows) {
  int r = blockIdx.x * 256 + threadIdx.x;
  rows[r] = (r / S) * Np + fps[r];
}

// ---------------- kNN: one wave per (b,s) ----------------
template <int NPL>
__global__ __launch_bounds__(64) void k_knn(int S, int Np, const float* __restrict__ pts,
                                            int stride, const int* __restrict__ rows,
                                            int* __restrict__ nn) {
  int bs = blockIdx.x;
  int b = bs / S;
  int lane = threadIdx.x;
  const float* pb = pts + (size_t)b * Np * stride;
  int arow = rows[bs];
  float ax = pts[(size_t)arow * stride + 0];
  float ay = pts[(size_t)arow * stride + 1];
  float d2[NPL];
#pragma unroll
  for (int i = 0; i < NPL; i++) {
    int j = lane + 64 * i;
    float dx = __fsub_rn(ax, pb[(size_t)j * stride + 0]);
    float dy = __fsub_rn(ay, pb[(size_t)j * stride + 1]);
    d2[i] = __fadd_rn(__fmul_rn(dx, dx), __fmul_rn(dy, dy));
  }
  unsigned mask = 0;
  for (int k = 0; k < K_; k++) {
    float bv = INFINITY; int bi = 0x7fffffff;
#pragma unroll
    for (int i = 0; i < NPL; i++) {
      int j = lane + 64 * i;
      bool used = (mask >> i) & 1u;
      if (!used && (d2[i] < bv || (d2[i] == bv && j < bi))) { bv = d2[i]; bi = j; }
    }
#pragma unroll
    for (int off = 32; off; off >>= 1) {
      float ov = __shfl_xor(bv, off);
      int oi = __shfl_xor(bi, off);
      if (ov < bv || (ov == bv && oi < bi)) { bv = ov; bi = oi; }
    }
    if ((bi & 63) == lane) mask |= 1u << (bi >> 6);
    if (lane == 0) nn[bs * K_ + k] = bi;
  }
}

// ---------------- bf16 MFMA GEMM: C[M,cov(N)] = A(rowidx)[M,K]dot W[N,K] ----------------
// 128x128 tile, 4 waves, 16x16x32 MFMA, BK=32, global_load_lds width 16.
// OMODE 0: f32 out (+bias if gridz==1, z-slabs otherwise). OMODE 1: bf16 out, zero for c>=Neff.
template <int OMODE>
__global__ __launch_bounds__(256) void k_mgemm(int M, int Neff, int K,
                                               const ushort* __restrict__ A, int lda,
                                               const int* __restrict__ rowidx,
                                               const ushort* __restrict__ Wt, int ldw,
                                               const float* __restrict__ bias,
                                               void* __restrict__ Cout, int ldc, int kchunk) {
  __shared__ ushort As[128 * 32];
  __shared__ ushort Bs[128 * 32];
  int t = threadIdx.x;
  int w = t >> 6, l = t & 63;
  int row0 = blockIdx.y * 128, col0 = blockIdx.x * 128;
  int k0 = blockIdx.z * kchunk;
  int k1 = min(K, k0 + kchunk);
  f32x4 acc[4][4];
#pragma unroll
  for (int i = 0; i < 4; i++)
#pragma unroll
    for (int j = 0; j < 4; j++) acc[i][j] = (f32x4){0.f, 0.f, 0.f, 0.f};

  int srow = l >> 2;          // 0..15
  int scol = (l & 3) * 8;     // k elem offset
  int ar0 = min(row0 + w * 16 + srow, M - 1);
  int ar1 = min(row0 + 64 + w * 16 + srow, M - 1);
  if (rowidx) { ar0 = rowidx[ar0]; ar1 = rowidx[ar1]; }
  const ushort* gA0 = A + (size_t)ar0 * lda + scol;
  const ushort* gA1 = A + (size_t)ar1 * lda + scol;
  const ushort* gB0 = Wt + (size_t)(col0 + w * 16 + srow) * ldw + scol;
  const ushort* gB1 = Wt + (size_t)(col0 + 64 + w * 16 + srow) * ldw + scol;
  ushort* lA0 = As + w * 512;
  ushort* lA1 = As + 2048 + w * 512;
  ushort* lB0 = Bs + w * 512;
  ushort* lB1 = Bs + 2048 + w * 512;

  int wm = w >> 1, wn = w & 1;
  int fr = l & 15, fg = l >> 4;

  for (int kt = k0; kt < k1; kt += 32) {
    __syncthreads();
    gload16(gA0 + kt, lA0);
    gload16(gA1 + kt, lA1);
    gload16(gB0 + kt, lB0);
    gload16(gB1 + kt, lB1);
    __syncthreads();
    short8 af[4], bf[4];
#pragma unroll
    for (int mi = 0; mi < 4; mi++)
      af[mi] = *(const short8*)&As[(wm * 64 + mi * 16 + fr) * 32 + fg * 8];
#pragma unroll
    for (int ni = 0; ni < 4; ni++)
      bf[ni] = *(const short8*)&Bs[(wn * 64 + ni * 16 + fr) * 32 + fg * 8];
#pragma unroll
    for (int mi = 0; mi < 4; mi++)
#pragma unroll
      for (int ni = 0; ni < 4; ni++)
        acc[mi][ni] = __builtin_amdgcn_mfma_f32_16x16x32_bf16(af[mi], bf[ni], acc[mi][ni], 0, 0, 0);
  }

  if (OMODE == 0) {
    float* C = (float*)Cout + (size_t)blockIdx.z * M * ldc;
    bool addb = (bias != nullptr) && (gridDim.z == 1);
#pragma unroll
    for (int mi = 0; mi < 4; mi++)
#pragma unroll
      for (int ni = 0; ni < 4; ni++)
#pragma unroll
        for (int q = 0; q < 4; q++) {
          int r = row0 + wm * 64 + mi * 16 + fg * 4 + q;
          int c = col0 + wn * 64 + ni * 16 + fr;
          if (r < M) {
            float v = acc[mi][ni][q];
            if (addb) v += bias[c];
            C[(size_t)r * ldc + c] = v;
          }
        }
  } else {
    ushort* C = (ushort*)Cout;
#pragma unroll
    for (int mi = 0; mi < 4; mi++)
#pragma unroll
      for (int ni = 0; ni < 4; ni++)
#pragma unroll
        for (int q = 0; q < 4; q++) {
          int r = row0 + wm * 64 + mi * 16 + fg * 4 + q;
          int c = col0 + wn * 64 + ni * 16 + fr;
          if (r < M) C[(size_t)r * ldc + c] = f2bf(c < Neff ? acc[mi][ni][q] : 0.f);
        }
  }
}

// ---------------- fused stage: gather G + base, relu, LN, max over k -> bf16 ----------------
__global__ __launch_bounds__(256) void k_fused_stage(
    int S, int Np, const float* __restrict__ G, const float* __restrict__ P,
    const float* __restrict__ dvec, const int* __restrict__ rows, const int* __restrict__ nn,
    const float* __restrict__ lng, const float* __restrict__ lnb,
    const float* __restrict__ prev_pts, int pts_stride, ushort* __restrict__ Xout, int ld_out,
    float* __restrict__ coords_out) {
  int bs = blockIdx.x;
  int b = bs / S;
  int t = threadIdx.x;
  int arow = rows[bs];
  float base[4], acc[4];
#pragma unroll
  for (int i = 0; i < 4; i++) {
    int c = t + 256 * i;
    base[i] = P[(size_t)bs * C_ + c] - G[(size_t)arow * C_ + c] + dvec[c];
    acc[i] = -INFINITY;
  }
  __shared__ float red[2][4];
  int lane = t & 63, w = t >> 6;
  for (int k = 0; k < K_; k++) {
    int g = nn[bs * K_ + k];
    const float* Gr = G + (size_t)(b * Np + g) * C_;
    float v[4];
    float s1 = 0.f, s2 = 0.f;
#pragma unroll
    for (int i = 0; i < 4; i++) {
      float x = Gr[t + 256 * i] + base[i];
      x = fmaxf(x, 0.f);
      v[i] = x;
      s1 += x;
      s2 += x * x;
    }
#pragma unroll
    for (int off = 32; off; off >>= 1) {
      s1 += __shfl_xor(s1, off);
      s2 += __shfl_xor(s2, off);
    }
    if (lane == 0) { red[0][w] = s1; red[1][w] = s2; }
    __syncthreads();
    float fs1 = red[0][0] + red[0][1] + red[0][2] + red[0][3];
    float fs2 = red[1][0] + red[1][1] + red[1][2] + red[1][3];
    __syncthreads();
    float mu = fs1 * (1.f / 1024.f);
    float var = fs2 * (1.f / 1024.f) - mu * mu;
    float rstd = 1.f / sqrtf(var + 1e-5f);
#pragma unroll
    for (int i = 0; i < 4; i++) {
      int c = t + 256 * i;
      float nv = (v[i] - mu) * rstd * lng[c] + lnb[c];
      acc[i] = fmaxf(acc[i], nv);
    }
  }
#pragma unroll
  for (int i = 0; i < 4; i++) Xout[(size_t)bs * ld_out + t + 256 * i] = f2bf(acc[i]);
  if (prev_pts) {
    float p0 = prev_pts[(size_t)arow * pts_stride + 0];
    float p1 = prev_pts[(size_t)arow * pts_stride + 1];
    if (t == 0) {
      Xout[(size_t)bs * ld_out + 1024] = f2bf(p0);
      Xout[(size_t)bs * ld_out + 1025] = f2bf(p1);
      coords_out[bs * 2 + 0] = p0;
      coords_out[bs * 2 + 1] = p1;
    }
    if (t < 126) Xout[(size_t)bs * ld_out + 1026 + t] = 0;
  }
}

// ---------------- reduce K-split partials + bias ----------------
__global__ __launch_bounds__(256) void k_reduce(int total, int Ncols, int nz,
                                                const float* __restrict__ part,
                                                const float* __restrict__ bias,
                                                float* __restrict__ out) {
  int i = blockIdx.x * 256 + threadIdx.x;
  if (i >= total) return;
  float s = bias[i % Ncols];
  for (int z = 0; z < nz; z++) s += part[(size_t)z * total + i];
  out[i] = s;
}

// ---------------- launch ----------------
extern "C" void kernel_launch(void* const* d_in, const int* in_sizes, int n_in, void* d_out,
                              int out_size, void* d_ws, size_t ws_size, hipStream_t stream) {
  (void)in_sizes; (void)n_in; (void)out_size; (void)ws_size;
  const float* points = (const float*)d_in[0];
  const float* feat_map = (const float*)d_in[1];
  const float* dw0 = (const float*)d_in[2];
  const float* db0 = (const float*)d_in[3];
  const float* aw0 = (const float*)d_in[4];
  const float* ab0 = (const float*)d_in[5];
  const float* lg0 = (const float*)d_in[6];
  const float* lb0 = (const float*)d_in[7];
  const float* dw1 = (const float*)d_in[8];
  const float* db1 = (const float*)d_in[9];
  const float* aw1 = (const float*)d_in[10];
  const float* ab1 = (const float*)d_in[11];
  const float* lg1 = (const float*)d_in[12];
  const float* lb1 = (const float*)d_in[13];
  const float* fw = (const float*)d_in[14];
  const float* fb = (const float*)d_in[15];
  const float* dmw = (const float*)d_in[16];
  const float* dmb = (const float*)d_in[17];
  float* out = (float*)d_out;

  char* wsb = (char*)d_ws;
  size_t off = 0;
  auto alloc = [&](size_t bytes) -> void* {
    void* p = wsb + off;
    off = (off + bytes + 255) & ~(size_t)255;
    return p;
  };
  // --- transient region (dead before fwb conversion); fwb aliases offset 0 ---
  float* fmT = (float*)alloc((size_t)1024 * 1024 * 4);                 // 4.19 MB
  ushort* Xb0 = (ushort*)alloc((size_t)B_ * N_ * LDP_ * 2);            // 37.75 MB
  ushort* Fb = (ushort*)alloc((size_t)B_ * N_ * LDP_ * 2);             // 37.75 MB
  float* Gf = (float*)alloc((size_t)B_ * N_ * C_ * 4);                 // 67.11 MB -> cum 146.8
  // --- not overlapped by fwb ---
  float* Pf = (float*)alloc((size_t)B_ * S0_ * C_ * 4);                // 33.5 MB
  ushort* Xb1 = (ushort*)alloc((size_t)B_ * S0_ * LDP_ * 2);           // 18.9 MB
  ushort* fts2b = (ushort*)alloc((size_t)B_ * S1_ * C_ * 2);           // 4.2 MB
  float* coords1 = (float*)alloc((size_t)B_ * S0_ * 2 * 4);
  ushort* dwb0 = (ushort*)alloc((size_t)LDP_ * LDP_ * 2);
  ushort* awdb0 = (ushort*)alloc((size_t)C_ * LDP_ * 2);
  ushort* awab0 = (ushort*)alloc((size_t)C_ * LDP_ * 2);
  ushort* dwb1 = (ushort*)alloc((size_t)LDP_ * LDP_ * 2);
  ushort* awdb1 = (ushort*)alloc((size_t)C_ * LDP_ * 2);
  ushort* awab1 = (ushort*)alloc((size_t)C_ * LDP_ * 2);
  ushort* dmwb = (ushort*)alloc((size_t)OUT_ * C_ * 2);
  float* dv0 = (float*)alloc(1024 * 4);
  float* dv1 = (float*)alloc(1024 * 4);
  int* fps0 = (int*)alloc(B_ * S0_ * 4);
  int* rows0 = (int*)alloc(B_ * S0_ * 4);
  int* nn0 = (int*)alloc(B_ * S0_ * K_ * 4);
  int* fps1 = (int*)alloc(B_ * S1_ * 4);
  int* rows1 = (int*)alloc(B_ * S1_ * 4);
  int* nn1 = (int*)alloc(B_ * S1_ * K_ * 4);
  float* hpart = (float*)alloc((size_t)64 * B_ * C_ * 4);              // 8.4 MB
  float* hid = (float*)alloc((size_t)B_ * C_ * 4);
  ushort* hidb = (ushort*)alloc((size_t)B_ * C_ * 2);
  float* opart = (float*)alloc((size_t)4 * B_ * OUT_ * 4);
  // fw bf16 aliases the transient region [0, 134.2 MB) -- used only after stage-1 fused
  ushort* fwb = (ushort*)wsb;

  // ---- weight conversions (small) ----
  {
    unsigned t2;
    t2 = (unsigned)((size_t)LDP_ * LDP_ / 2);
    k_cvt<<<(t2 + 255) / 256, 256, 0, stream>>>(dw0, C2_, 0, C2_, C2_, dwb0, LDP_, t2);
    k_cvt<<<(t2 + 255) / 256, 256, 0, stream>>>(dw1, C2_, 0, C2_, C2_, dwb1, LDP_, t2);
    t2 = (unsigned)((size_t)C_ * LDP_ / 2);
    k_cvt<<<(t2 + 255) / 256, 256, 0, stream>>>(aw0, CC2_, 0, C_, C2_, awdb0, LDP_, t2);
    k_cvt<<<(t2 + 255) / 256, 256, 0, stream>>>(aw0, CC2_, C2_, C_, C2_, awab0, LDP_, t2);
    k_cvt<<<(t2 + 255) / 256, 256, 0, stream>>>(aw1, CC2_, 0, C_, C2_, awdb1, LDP_, t2);
    k_cvt<<<(t2 + 255) / 256, 256, 0, stream>>>(aw1, CC2_, C2_, C_, C2_, awab1, LDP_, t2);
    t2 = (unsigned)((size_t)OUT_ * C_ / 2);
    k_cvt<<<(t2 + 255) / 256, 256, 0, stream>>>(dmw, C_, 0, OUT_, C_, dmwb, C_, t2);
  }
  k_dvec<<<4, 256, 0, stream>>>(db0, aw0, dv0);
  k_dvec<<<4, 256, 0, stream>>>(db1, aw1, dv1);

  k_transpose_fm<<<4096, 256, 0, stream>>>(feat_map, fmT);
  k_bilinear<<<B_ * N_, 256, 0, stream>>>(points, fmT, Xb0);

  // ---- stage 0 ----
  k_fps<8><<<B_, 64, 0, stream>>>(N_, S0_, points, 2, fps0);
  k_make_rows<<<(B_ * S0_) / 256, 256, 0, stream>>>(S0_, N_, fps0, rows0);
  k_knn<8><<<B_ * S0_, 64, 0, stream>>>(S0_, N_, points, 2, rows0, nn0);
  {
    dim3 g(LDP_ / 128, (B_ * N_) / 128, 1);  // F0 -> Fb (bf16, zero-pad cols >= 1026)
    k_mgemm<1><<<g, 256, 0, stream>>>(B_ * N_, C2_, LDP_, Xb0, LDP_, nullptr, dwb0, LDP_, nullptr,
                                      Fb, LDP_, LDP_);
  }
  {
    dim3 g(C_ / 128, (B_ * S0_) / 128, 1);  // P0 (gathered anchors) + ab0
    k_mgemm<0><<<g, 256, 0, stream>>>(B_ * S0_, C_, LDP_, Xb0, LDP_, rows0, awab0, LDP_, ab0, Pf,
                                      C_, LDP_);
  }
  {
    dim3 g(C_ / 128, (B_ * N_) / 128, 1);  // G0 = Fb @ awd^T
    k_mgemm<0><<<g, 256, 0, stream>>>(B_ * N_, C_, LDP_, Fb, LDP_, nullptr, awdb0, LDP_, nullptr,
                                      Gf, C_, LDP_);
  }
  k_fused_stage<<<B_ * S0_, 256, 0, stream>>>(S0_, N_, Gf, Pf, dv0, rows0, nn0, lg0, lb0, points,
                                              2, Xb1, LDP_, coords1);

  // ---- stage 1 ----
  k_fps<4><<<B_, 64, 0, stream>>>(S0_, S1_, coords1, 2, fps1);
  k_make_rows<<<(B_ * S1_) / 256, 256, 0, stream>>>(S1_, S0_, fps1, rows1);
  k_knn<4><<<B_ * S1_, 64, 0, stream>>>(S1_, S0_, coords1, 2, rows1, nn1);
  {
    dim3 g(LDP_ / 128, (B_ * S0_) / 128, 1);  // F1 -> Fb
    k_mgemm<1><<<g, 256, 0, stream>>>(B_ * S0_, C2_, LDP_, Xb1, LDP_, nullptr, dwb1, LDP_, nullptr,
                                      Fb, LDP_, LDP_);
  }
  {
    dim3 g(C_ / 128, (B_ * S1_) / 128, 1);  // P1 + ab1
    k_mgemm<0><<<g, 256, 0, stream>>>(B_ * S1_, C_, LDP_, Xb1, LDP_, rows1, awab1, LDP_, ab1, Pf,
                                      C_, LDP_);
  }
  {
    dim3 g(C_ / 128, (B_ * S0_) / 128, 1);  // G1
    k_mgemm<0><<<g, 256, 0, stream>>>(B_ * S0_, C_, LDP_, Fb, LDP_, nullptr, awdb1, LDP_, nullptr,
                                      Gf, C_, LDP_);
  }
  k_fused_stage<<<B_ * S1_, 256, 0, stream>>>(S1_, S0_, Gf, Pf, dv1, rows1, nn1, lg1, lb1,
                                              nullptr, 0, fts2b, C_, nullptr);

  // ---- heads ----
  {
    // convert fw -> bf16 (aliases now-dead transient region)
    unsigned t2 = (unsigned)((size_t)C_ * 65536 / 2);
    k_cvt<<<(t2 + 255) / 256, 256, 0, stream>>>(fw, 65536, 0, C_, 65536, fwb, 65536, t2);
  }
  {
    dim3 g(C_ / 128, 1, 64);  // flat: M=32, K=65536, z-split 64 x 1024
    k_mgemm<0><<<g, 256, 0, stream>>>(B_, C_, 65536, fts2b, 65536, nullptr, fwb, 65536, nullptr,
                                      hpart, C_, 1024);
  }
  k_reduce<<<(B_ * C_ + 255) / 256, 256, 0, stream>>>(B_ * C_, C_, 64, hpart, fb, hid);
  {
    unsigned t2 = (unsigned)((size_t)B_ * C_ / 2);
    k_cvt<<<(t2 + 255) / 256, 256, 0, stream>>>(hid, C_, 0, B_, C_, hidb, C_, t2);
  }
  {
    dim3 g(OUT_ / 128, 1, 4);  // dim head: M=32, K=1024, z-split 4 x 256
    k_mgemm<0><<<g, 256, 0, stream>>>(B_, OUT_, C_, hidb, C_, nullptr, dmwb, C_, nullptr, opart,
                                      OUT_, 256);
  }
  k_reduce<<<(B_ * OUT_ + 255) / 256, 256, 0, stream>>>(B_ * OUT_, OUT_, 4, opart, dmb, out);
}

// Round 3
// 861.031 us; speedup vs baseline: 4.1197x; 1.2744x over previous
//
#include <hip/hip_runtime.h>
#include <cstdint>
#include <cstddef>

// ---------------- constants ----------------
static const int B_ = 32, N_ = 512, C_ = 1024, C2_ = 1026, CC2_ = 2052;
static const int S0_ = 256, S1_ = 64, K_ = 16, OUT_ = 3584;
static const int LDP_ = 1152;  // padded C2 (multiple of 128 and 32)

typedef unsigned short ushort;
typedef __attribute__((ext_vector_type(8))) short short8;
typedef __attribute__((ext_vector_type(4))) float f32x4;

__device__ __forceinline__ ushort f2bf(float x) {
  unsigned u = __float_as_uint(x);
  unsigned r = (u + 0x7fffu + ((u >> 16) & 1u)) >> 16;
  return (ushort)r;
}
__device__ __forceinline__ float bf2f(ushort b) {
  return __uint_as_float(((unsigned)b) << 16);
}

__device__ __forceinline__ void gload16(const void* g, void* l) {
  __builtin_amdgcn_global_load_lds((const __attribute__((address_space(1))) void*)g,
                                   (__attribute__((address_space(3))) void*)l, 16, 0, 0);
}

// ---------------- transpose feat_map (C,H,W) -> (H*W, C) ----------------
__global__ __launch_bounds__(256) void k_transpose_fm(const float* __restrict__ f,
                                                      float* __restrict__ fmT) {
  int o = blockIdx.x * 256 + threadIdx.x;
  int c = o & 1023, yx = o >> 10;
  fmT[o] = f[c * 1024 + yx];
}

// ---------------- bilinear sample -> Xb0 rows bf16 [feat(1024) | p0 p1 | pad0] ----------------
__global__ __launch_bounds__(256) void k_bilinear(const float* __restrict__ points,
                                                  const float* __restrict__ fmT,
                                                  ushort* __restrict__ X0) {
  int r = blockIdx.x;  // b*512+n
  float p0 = points[r * 2 + 0], p1 = points[r * 2 + 1];
  float g0 = __fsub_rn(__fmul_rn(2.0f, p1), 1.0f);
  float g1 = __fsub_rn(__fmul_rn(2.0f, p0), 1.0f);
  float x = __fmul_rn(__fmul_rn(__fadd_rn(g0, 1.0f), 0.5f), 31.0f);
  float y = __fmul_rn(__fmul_rn(__fadd_rn(g1, 1.0f), 0.5f), 31.0f);
  float x0f = floorf(x), y0f = floorf(y);
  float wx = __fsub_rn(x, x0f), wy = __fsub_rn(y, y0f);
  int x0i = (int)fminf(fmaxf(x0f, 0.f), 31.f);
  int x1i = (int)fminf(fmaxf(__fadd_rn(x0f, 1.f), 0.f), 31.f);
  int y0i = (int)fminf(fmaxf(y0f, 0.f), 31.f);
  int y1i = (int)fminf(fmaxf(__fadd_rn(y0f, 1.f), 0.f), 31.f);
  float omwx = __fsub_rn(1.f, wx), omwy = __fsub_rn(1.f, wy);
  size_t i00 = (size_t)(y0i * 32 + x0i) * 1024;
  size_t i01 = (size_t)(y0i * 32 + x1i) * 1024;
  size_t i10 = (size_t)(y1i * 32 + x0i) * 1024;
  size_t i11 = (size_t)(y1i * 32 + x1i) * 1024;
  int t = threadIdx.x;
  ushort* xr = X0 + (size_t)r * LDP_;
#pragma unroll
  for (int i = 0; i < 4; i++) {
    int c = t + 256 * i;
    float f00 = fmT[i00 + c], f01 = fmT[i01 + c], f10 = fmT[i10 + c], f11 = fmT[i11 + c];
    float t1 = f00 * omwx * omwy;
    float t2 = f01 * wx * omwy;
    float t3 = f10 * omwx * wy;
    float t4 = f11 * wx * wy;
    xr[c] = f2bf(((t1 + t2) + t3) + t4);
  }
  if (t == 0) { xr[1024] = f2bf(p0); xr[1025] = f2bf(p1); }
  if (t < 126) xr[1026 + t] = 0;
}

// ---------------- f32 -> bf16 convert with pad (dst [Rp][dld], zero outside R x Ceff) ----------
__global__ __launch_bounds__(256) void k_cvt(const float* __restrict__ src, int sld, int soff,
                                             int R, int Ceff, ushort* __restrict__ dst, int dld,
                                             unsigned total2) {
  unsigned i = blockIdx.x * 256u + threadIdx.x;
  if (i >= total2) return;
  unsigned e = i * 2u;
  unsigned r = e / (unsigned)dld, c = e % (unsigned)dld;
  float v0 = 0.f, v1 = 0.f;
  if ((int)r < R) {
    const float* sp = src + (size_t)r * sld + soff + c;
    if ((int)c < Ceff) v0 = sp[0];
    if ((int)(c + 1) < Ceff) v1 = sp[1];
  }
  unsigned u = (unsigned)f2bf(v0) | ((unsigned)f2bf(v1) << 16);
  *(unsigned*)(dst + e) = u;
}

// ---------------- dvec[c] = sum_d db[d]*aw[c,d] ----------------
__global__ __launch_bounds__(256) void k_dvec(const float* __restrict__ db,
                                              const float* __restrict__ aw,
                                              float* __restrict__ dvec) {
  int c = blockIdx.x * 256 + threadIdx.x;
  if (c >= C_) return;
  float s = 0.f;
  const float* wr = aw + (size_t)c * CC2_;
  for (int d = 0; d < C2_; d++) s += db[d] * wr[d];
  dvec[c] = s;
}

// ---------------- FPS: one wave per batch, register-resident, packed u64 argmax ------------
// packed = (dist_bits << 32) | ~j  -> u64 max == (max dist, tie -> smallest j). Exact f32 ops.
template <int NPL>
__global__ __launch_bounds__(64) void k_fps(int Np, int nsub, const float* __restrict__ pts,
                                            int stride, int* __restrict__ out_idx) {
  int b = blockIdx.x;
  int lane = threadIdx.x;
  const float* pb = pts + (size_t)b * Np * stride;
  float px[NPL], py[NPL], dist[NPL];
#pragma unroll
  for (int i = 0; i < NPL; i++) {
    int j = lane + 64 * i;
    px[i] = pb[(size_t)j * stride + 0];
    py[i] = pb[(size_t)j * stride + 1];
    dist[i] = 1e10f;
  }
  int far = 0;
  float fx = pb[0], fy = pb[1];
  for (int s = 0; s < nsub; s++) {
    if (lane == 0) out_idx[b * nsub + s] = far;
    unsigned long long best = 0ull;
#pragma unroll
    for (int i = 0; i < NPL; i++) {
      float dx = __fsub_rn(px[i], fx), dy = __fsub_rn(py[i], fy);
      float d = __fadd_rn(__fmul_rn(dx, dx), __fmul_rn(dy, dy));
      dist[i] = fminf(dist[i], d);
      unsigned long long pk =
          ((unsigned long long)__float_as_uint(dist[i]) << 32) | (unsigned)(~(lane + 64 * i));
      best = pk > best ? pk : best;
    }
#pragma unroll
    for (int off = 32; off; off >>= 1) {
      unsigned long long o = __shfl_xor(best, off);
      best = o > best ? o : best;
    }
    int j = (int)(~(unsigned)best);
    far = j;
    int chunk = j >> 6, owner = j & 63;
    float cx = px[0], cy = py[0];
#pragma unroll
    for (int i = 1; i < NPL; i++) {
      bool c = (chunk == i);
      cx = c ? px[i] : cx;
      cy = c ? py[i] : cy;
    }
    fx = __shfl(cx, owner);
    fy = __shfl(cy, owner);
  }
}

// ---------------- rows[r] = (r/S)*Np + fps[r] ----------------
__global__ __launch_bounds__(256) void k_make_rows(int S, int Np, const int* __restrict__ fps,
                                                   int* __restrict__ rows) {
  int r = blockIdx.x * 256 + threadIdx.x;
  rows[r] = (r / S) * Np + fps[r];
}

// ---------------- kNN: one wave per (b,s) ----------------
template <int NPL>
__global__ __launch_bounds__(64) void k_knn(int S, int Np, const float* __restrict__ pts,
                                            int stride, const int* __restrict__ rows,
                                            int* __restrict__ nn) {
  int bs = blockIdx.x;
  int b = bs / S;
  int lane = threadIdx.x;
  const float* pb = pts + (size_t)b * Np * stride;
  int arow = rows[bs];
  float ax = pts[(size_t)arow * stride + 0];
  float ay = pts[(size_t)arow * stride + 1];
  float d2[NPL];
#pragma unroll
  for (int i = 0; i < NPL; i++) {
    int j = lane + 64 * i;
    float dx = __fsub_rn(ax, pb[(size_t)j * stride + 0]);
    float dy = __fsub_rn(ay, pb[(size_t)j * stride + 1]);
    d2[i] = __fadd_rn(__fmul_rn(dx, dx), __fmul_rn(dy, dy));
  }
  unsigned mask = 0;
  for (int k = 0; k < K_; k++) {
    float bv = INFINITY; int bi = 0x7fffffff;
#pragma unroll
    for (int i = 0; i < NPL; i++) {
      int j = lane + 64 * i;
      bool used = (mask >> i) & 1u;
      if (!used && (d2[i] < bv || (d2[i] == bv && j < bi))) { bv = d2[i]; bi = j; }
    }
#pragma unroll
    for (int off = 32; off; off >>= 1) {
      float ov = __shfl_xor(bv, off);
      int oi = __shfl_xor(bi, off);
      if (ov < bv || (ov == bv && oi < bi)) { bv = ov; bi = oi; }
    }
    if ((bi & 63) == lane) mask |= 1u << (bi >> 6);
    if (lane == 0) nn[bs * K_ + k] = bi;
  }
}

// ---------------- bf16 MFMA GEMM: C[M,cov(N)] = A(rowidx)[M,K]dot W[N,K] ----------------
// OMODE 0: f32 out (+bias if gridz==1, z-slabs otherwise). OMODE 1: bf16 out, zero for c>=Neff.
template <int OMODE>
__global__ __launch_bounds__(256) void k_mgemm(int M, int Neff, int K,
                                               const ushort* __restrict__ A, int lda,
                                               const int* __restrict__ rowidx,
                                               const ushort* __restrict__ Wt, int ldw,
                                               const float* __restrict__ bias,
                                               void* __restrict__ Cout, int ldc, int kchunk) {
  __shared__ ushort As[128 * 32];
  __shared__ ushort Bs[128 * 32];
  int t = threadIdx.x;
  int w = t >> 6, l = t & 63;
  int row0 = blockIdx.y * 128, col0 = blockIdx.x * 128;
  int k0 = blockIdx.z * kchunk;
  int k1 = min(K, k0 + kchunk);
  f32x4 acc[4][4];
#pragma unroll
  for (int i = 0; i < 4; i++)
#pragma unroll
    for (int j = 0; j < 4; j++) acc[i][j] = (f32x4){0.f, 0.f, 0.f, 0.f};

  int srow = l >> 2;
  int scol = (l & 3) * 8;
  int ar0 = min(row0 + w * 16 + srow, M - 1);
  int ar1 = min(row0 + 64 + w * 16 + srow, M - 1);
  if (rowidx) { ar0 = rowidx[ar0]; ar1 = rowidx[ar1]; }
  const ushort* gA0 = A + (size_t)ar0 * lda + scol;
  const ushort* gA1 = A + (size_t)ar1 * lda + scol;
  const ushort* gB0 = Wt + (size_t)(col0 + w * 16 + srow) * ldw + scol;
  const ushort* gB1 = Wt + (size_t)(col0 + 64 + w * 16 + srow) * ldw + scol;
  ushort* lA0 = As + w * 512;
  ushort* lA1 = As + 2048 + w * 512;
  ushort* lB0 = Bs + w * 512;
  ushort* lB1 = Bs + 2048 + w * 512;

  int wm = w >> 1, wn = w & 1;
  int fr = l & 15, fg = l >> 4;

  for (int kt = k0; kt < k1; kt += 32) {
    __syncthreads();
    gload16(gA0 + kt, lA0);
    gload16(gA1 + kt, lA1);
    gload16(gB0 + kt, lB0);
    gload16(gB1 + kt, lB1);
    __syncthreads();
    short8 af[4], bf[4];
#pragma unroll
    for (int mi = 0; mi < 4; mi++)
      af[mi] = *(const short8*)&As[(wm * 64 + mi * 16 + fr) * 32 + fg * 8];
#pragma unroll
    for (int ni = 0; ni < 4; ni++)
      bf[ni] = *(const short8*)&Bs[(wn * 64 + ni * 16 + fr) * 32 + fg * 8];
#pragma unroll
    for (int mi = 0; mi < 4; mi++)
#pragma unroll
      for (int ni = 0; ni < 4; ni++)
        acc[mi][ni] = __builtin_amdgcn_mfma_f32_16x16x32_bf16(af[mi], bf[ni], acc[mi][ni], 0, 0, 0);
  }

  if (OMODE == 0) {
    float* C = (float*)Cout + (size_t)blockIdx.z * M * ldc;
    bool addb = (bias != nullptr) && (gridDim.z == 1);
#pragma unroll
    for (int mi = 0; mi < 4; mi++)
#pragma unroll
      for (int ni = 0; ni < 4; ni++)
#pragma unroll
        for (int q = 0; q < 4; q++) {
          int r = row0 + wm * 64 + mi * 16 + fg * 4 + q;
          int c = col0 + wn * 64 + ni * 16 + fr;
          if (r < M) {
            float v = acc[mi][ni][q];
            if (addb) v += bias[c];
            C[(size_t)r * ldc + c] = v;
          }
        }
  } else {
    ushort* C = (ushort*)Cout;
#pragma unroll
    for (int mi = 0; mi < 4; mi++)
#pragma unroll
      for (int ni = 0; ni < 4; ni++)
#pragma unroll
        for (int q = 0; q < 4; q++) {
          int r = row0 + wm * 64 + mi * 16 + fg * 4 + q;
          int c = col0 + wn * 64 + ni * 16 + fr;
          if (r < M) C[(size_t)r * ldc + c] = f2bf(c < Neff ? acc[mi][ni][q] : 0.f);
        }
  }
}

// ---------------- flat head GEMM with fused f32->bf16 W conversion ----------------
// M=32 rows in registers, no LDS/barriers. Grid: (8 col-blocks, 1, 32 k-chunks of 2048).
__global__ __launch_bounds__(256) void k_flat(const ushort* __restrict__ A,   // [32][65536] bf16
                                              const float* __restrict__ W,    // [1024][65536] f32
                                              float* __restrict__ Cp) {       // [32][32][1024]
  int t = threadIdx.x;
  int w = t >> 6, l = t & 63;
  int fr = l & 15, fg = l >> 4;
  int col0 = blockIdx.x * 128 + w * 32;
  size_t k0 = (size_t)blockIdx.z * 2048;
  f32x4 acc[2][2];
#pragma unroll
  for (int i = 0; i < 2; i++)
#pragma unroll
    for (int j = 0; j < 2; j++) acc[i][j] = (f32x4){0.f, 0.f, 0.f, 0.f};
  const ushort* a0 = A + (size_t)fr * 65536 + k0 + fg * 8;
  const ushort* a1 = A + (size_t)(16 + fr) * 65536 + k0 + fg * 8;
  const float* b0 = W + (size_t)(col0 + fr) * 65536 + k0 + fg * 8;
  const float* b1 = W + (size_t)(col0 + 16 + fr) * 65536 + k0 + fg * 8;
  for (int kt = 0; kt < 2048; kt += 32) {
    short8 af0 = *(const short8*)(a0 + kt);
    short8 af1 = *(const short8*)(a1 + kt);
    float4 p0 = *(const float4*)(b0 + kt);
    float4 p1 = *(const float4*)(b0 + kt + 4);
    float4 q0 = *(const float4*)(b1 + kt);
    float4 q1 = *(const float4*)(b1 + kt + 4);
    short8 bf0, bf1;
    bf0[0] = (short)f2bf(p0.x); bf0[1] = (short)f2bf(p0.y);
    bf0[2] = (short)f2bf(p0.z); bf0[3] = (short)f2bf(p0.w);
    bf0[4] = (short)f2bf(p1.x); bf0[5] = (short)f2bf(p1.y);
    bf0[6] = (short)f2bf(p1.z); bf0[7] = (short)f2bf(p1.w);
    bf1[0] = (short)f2bf(q0.x); bf1[1] = (short)f2bf(q0.y);
    bf1[2] = (short)f2bf(q0.z); bf1[3] = (short)f2bf(q0.w);
    bf1[4] = (short)f2bf(q1.x); bf1[5] = (short)f2bf(q1.y);
    bf1[6] = (short)f2bf(q1.z); bf1[7] = (short)f2bf(q1.w);
    acc[0][0] = __builtin_amdgcn_mfma_f32_16x16x32_bf16(af0, bf0, acc[0][0], 0, 0, 0);
    acc[1][0] = __builtin_amdgcn_mfma_f32_16x16x32_bf16(af1, bf0, acc[1][0], 0, 0, 0);
    acc[0][1] = __builtin_amdgcn_mfma_f32_16x16x32_bf16(af0, bf1, acc[0][1], 0, 0, 0);
    acc[1][1] = __builtin_amdgcn_mfma_f32_16x16x32_bf16(af1, bf1, acc[1][1], 0, 0, 0);
  }
  float* Cz = Cp + (size_t)blockIdx.z * 32 * 1024;
#pragma unroll
  for (int mi = 0; mi < 2; mi++)
#pragma unroll
    for (int ni = 0; ni < 2; ni++)
#pragma unroll
      for (int q = 0; q < 4; q++) {
        int r = mi * 16 + fg * 4 + q;
        int c = col0 + ni * 16 + fr;
        Cz[(size_t)r * 1024 + c] = acc[mi][ni][q];
      }
}

// ---------------- fused stage: gather bf16 G + base, relu, LN, max over k -> bf16 ----------
__global__ __launch_bounds__(256) void k_fused_stage(
    int S, int Np, const ushort* __restrict__ G, const float* __restrict__ P,
    const float* __restrict__ dvec, const int* __restrict__ rows, const int* __restrict__ nn,
    const float* __restrict__ lng, const float* __restrict__ lnb,
    const float* __restrict__ prev_pts, int pts_stride, ushort* __restrict__ Xout, int ld_out,
    float* __restrict__ coords_out) {
  int bs = blockIdx.x;
  int b = bs / S;
  int t = threadIdx.x;
  int c0 = t * 4;
  int arow = rows[bs];
  float base[4], acc[4];
  {
    float4 pv = *(const float4*)(P + (size_t)bs * C_ + c0);
    float4 dv = *(const float4*)(dvec + c0);
    uint2 gv = *(const uint2*)(G + (size_t)arow * C_ + c0);
    float ga[4] = {bf2f((ushort)(gv.x & 0xffff)), bf2f((ushort)(gv.x >> 16)),
                   bf2f((ushort)(gv.y & 0xffff)), bf2f((ushort)(gv.y >> 16))};
    float pvv[4] = {pv.x, pv.y, pv.z, pv.w};
    float dvv[4] = {dv.x, dv.y, dv.z, dv.w};
#pragma unroll
    for (int i = 0; i < 4; i++) {
      base[i] = pvv[i] - ga[i] + dvv[i];
      acc[i] = -INFINITY;
    }
  }
  float4 lgv = *(const float4*)(lng + c0);
  float4 lbv = *(const float4*)(lnb + c0);
  float lg[4] = {lgv.x, lgv.y, lgv.z, lgv.w};
  float lb[4] = {lbv.x, lbv.y, lbv.z, lbv.w};
  __shared__ float red[2][4];
  int lane = t & 63, w = t >> 6;
  for (int k = 0; k < K_; k++) {
    int g = nn[bs * K_ + k];
    const ushort* Gr = G + (size_t)(b * Np + g) * C_;
    uint2 gv = *(const uint2*)(Gr + c0);
    float gn[4] = {bf2f((ushort)(gv.x & 0xffff)), bf2f((ushort)(gv.x >> 16)),
                   bf2f((ushort)(gv.y & 0xffff)), bf2f((ushort)(gv.y >> 16))};
    float v[4];
    float s1 = 0.f, s2 = 0.f;
#pragma unroll
    for (int i = 0; i < 4; i++) {
      float x = gn[i] + base[i];
      x = fmaxf(x, 0.f);
      v[i] = x;
      s1 += x;
      s2 += x * x;
    }
#pragma unroll
    for (int off = 32; off; off >>= 1) {
      s1 += __shfl_xor(s1, off);
      s2 += __shfl_xor(s2, off);
    }
    if (lane == 0) { red[0][w] = s1; red[1][w] = s2; }
    __syncthreads();
    float fs1 = red[0][0] + red[0][1] + red[0][2] + red[0][3];
    float fs2 = red[1][0] + red[1][1] + red[1][2] + red[1][3];
    __syncthreads();
    float mu = fs1 * (1.f / 1024.f);
    float var = fs2 * (1.f / 1024.f) - mu * mu;
    float rstd = 1.f / sqrtf(var + 1e-5f);
#pragma unroll
    for (int i = 0; i < 4; i++) {
      float nv = (v[i] - mu) * rstd * lg[i] + lb[i];
      acc[i] = fmaxf(acc[i], nv);
    }
  }
  {
    unsigned u0 = (unsigned)f2bf(acc[0]) | ((unsigned)f2bf(acc[1]) << 16);
    unsigned u1 = (unsigned)f2bf(acc[2]) | ((unsigned)f2bf(acc[3]) << 16);
    uint2 uv = {u0, u1};
    *(uint2*)(Xout + (size_t)bs * ld_out + c0) = uv;
  }
  if (prev_pts) {
    float p0 = prev_pts[(size_t)arow * pts_stride + 0];
    float p1 = prev_pts[(size_t)arow * pts_stride + 1];
    if (t == 0) {
      Xout[(size_t)bs * ld_out + 1024] = f2bf(p0);
      Xout[(size_t)bs * ld_out + 1025] = f2bf(p1);
      coords_out[bs * 2 + 0] = p0;
      coords_out[bs * 2 + 1] = p1;
    }
    if (t < 126) Xout[(size_t)bs * ld_out + 1026 + t] = 0;
  }
}

// ---------------- reduce K-split partials + bias; OUTBF: write bf16 ----------------
template <int OUTBF>
__global__ __launch_bounds__(256) void k_reduce(int total, int Ncols, int nz,
                                                const float* __restrict__ part,
                                                const float* __restrict__ bias,
                                                void* __restrict__ out) {
  int i = blockIdx.x * 256 + threadIdx.x;
  if (i >= total) return;
  float s = bias[i % Ncols];
  for (int z = 0; z < nz; z++) s += part[(size_t)z * total + i];
  if (OUTBF)
    ((ushort*)out)[i] = f2bf(s);
  else
    ((float*)out)[i] = s;
}

// ---------------- launch ----------------
extern "C" void kernel_launch(void* const* d_in, const int* in_sizes, int n_in, void* d_out,
                              int out_size, void* d_ws, size_t ws_size, hipStream_t stream) {
  (void)in_sizes; (void)n_in; (void)out_size; (void)ws_size;
  const float* points = (const float*)d_in[0];
  const float* feat_map = (const float*)d_in[1];
  const float* dw0 = (const float*)d_in[2];
  const float* db0 = (const float*)d_in[3];
  const float* aw0 = (const float*)d_in[4];
  const float* ab0 = (const float*)d_in[5];
  const float* lg0 = (const float*)d_in[6];
  const float* lb0 = (const float*)d_in[7];
  const float* dw1 = (const float*)d_in[8];
  const float* db1 = (const float*)d_in[9];
  const float* aw1 = (const float*)d_in[10];
  const float* ab1 = (const float*)d_in[11];
  const float* lg1 = (const float*)d_in[12];
  const float* lb1 = (const float*)d_in[13];
  const float* fw = (const float*)d_in[14];
  const float* fb = (const float*)d_in[15];
  const float* dmw = (const float*)d_in[16];
  const float* dmb = (const float*)d_in[17];
  float* out = (float*)d_out;

  char* wsb = (char*)d_ws;
  size_t off = 0;
  auto alloc = [&](size_t bytes) -> void* {
    void* p = wsb + off;
    off = (off + bytes + 255) & ~(size_t)255;
    return p;
  };
  float* fmT = (float*)alloc((size_t)1024 * 1024 * 4);
  ushort* Xb0 = (ushort*)alloc((size_t)B_ * N_ * LDP_ * 2);
  ushort* Fb = (ushort*)alloc((size_t)B_ * N_ * LDP_ * 2);
  ushort* Gb = (ushort*)alloc((size_t)B_ * N_ * C_ * 2);
  float* Pf = (float*)alloc((size_t)B_ * S0_ * C_ * 4);
  ushort* Xb1 = (ushort*)alloc((size_t)B_ * S0_ * LDP_ * 2);
  ushort* fts2b = (ushort*)alloc((size_t)B_ * S1_ * C_ * 2);
  float* coords1 = (float*)alloc((size_t)B_ * S0_ * 2 * 4);
  ushort* dwb0 = (ushort*)alloc((size_t)LDP_ * LDP_ * 2);
  ushort* awdb0 = (ushort*)alloc((size_t)C_ * LDP_ * 2);
  ushort* awab0 = (ushort*)alloc((size_t)C_ * LDP_ * 2);
  ushort* dwb1 = (ushort*)alloc((size_t)LDP_ * LDP_ * 2);
  ushort* awdb1 = (ushort*)alloc((size_t)C_ * LDP_ * 2);
  ushort* awab1 = (ushort*)alloc((size_t)C_ * LDP_ * 2);
  ushort* dmwb = (ushort*)alloc((size_t)OUT_ * C_ * 2);
  float* dv0 = (float*)alloc(1024 * 4);
  float* dv1 = (float*)alloc(1024 * 4);
  int* fps0 = (int*)alloc(B_ * S0_ * 4);
  int* rows0 = (int*)alloc(B_ * S0_ * 4);
  int* nn0 = (int*)alloc(B_ * S0_ * K_ * 4);
  int* fps1 = (int*)alloc(B_ * S1_ * 4);
  int* rows1 = (int*)alloc(B_ * S1_ * 4);
  int* nn1 = (int*)alloc(B_ * S1_ * K_ * 4);
  float* hpart = (float*)alloc((size_t)32 * B_ * C_ * 4);
  ushort* hidb = (ushort*)alloc((size_t)B_ * C_ * 2);
  float* opart = (float*)alloc((size_t)4 * B_ * OUT_ * 4);

  // ---- weight conversions ----
  {
    unsigned t2;
    t2 = (unsigned)((size_t)LDP_ * LDP_ / 2);
    k_cvt<<<(t2 + 255) / 256, 256, 0, stream>>>(dw0, C2_, 0, C2_, C2_, dwb0, LDP_, t2);
    k_cvt<<<(t2 + 255) / 256, 256, 0, stream>>>(dw1, C2_, 0, C2_, C2_, dwb1, LDP_, t2);
    t2 = (unsigned)((size_t)C_ * LDP_ / 2);
    k_cvt<<<(t2 + 255) / 256, 256, 0, stream>>>(aw0, CC2_, 0, C_, C2_, awdb0, LDP_, t2);
    k_cvt<<<(t2 + 255) / 256, 256, 0, stream>>>(aw0, CC2_, C2_, C_, C2_, awab0, LDP_, t2);
    k_cvt<<<(t2 + 255) / 256, 256, 0, stream>>>(aw1, CC2_, 0, C_, C2_, awdb1, LDP_, t2);
    k_cvt<<<(t2 + 255) / 256, 256, 0, stream>>>(aw1, CC2_, C2_, C_, C2_, awab1, LDP_, t2);
    t2 = (unsigned)((size_t)OUT_ * C_ / 2);
    k_cvt<<<(t2 + 255) / 256, 256, 0, stream>>>(dmw, C_, 0, OUT_, C_, dmwb, C_, t2);
  }
  k_dvec<<<4, 256, 0, stream>>>(db0, aw0, dv0);
  k_dvec<<<4, 256, 0, stream>>>(db1, aw1, dv1);

  k_transpose_fm<<<4096, 256, 0, stream>>>(feat_map, fmT);
  k_bilinear<<<B_ * N_, 256, 0, stream>>>(points, fmT, Xb0);

  // ---- stage 0 ----
  k_fps<8><<<B_, 64, 0, stream>>>(N_, S0_, points, 2, fps0);
  k_make_rows<<<(B_ * S0_) / 256, 256, 0, stream>>>(S0_, N_, fps0, rows0);
  k_knn<8><<<B_ * S0_, 64, 0, stream>>>(S0_, N_, points, 2, rows0, nn0);
  {
    dim3 g(LDP_ / 128, (B_ * N_) / 128, 1);
    k_mgemm<1><<<g, 256, 0, stream>>>(B_ * N_, C2_, LDP_, Xb0, LDP_, nullptr, dwb0, LDP_, nullptr,
                                      Fb, LDP_, LDP_);
  }
  {
    dim3 g(C_ / 128, (B_ * S0_) / 128, 1);
    k_mgemm<0><<<g, 256, 0, stream>>>(B_ * S0_, C_, LDP_, Xb0, LDP_, rows0, awab0, LDP_, ab0, Pf,
                                      C_, LDP_);
  }
  {
    dim3 g(C_ / 128, (B_ * N_) / 128, 1);  // G0 bf16
    k_mgemm<1><<<g, 256, 0, stream>>>(B_ * N_, C_, LDP_, Fb, LDP_, nullptr, awdb0, LDP_, nullptr,
                                      Gb, C_, LDP_);
  }
  k_fused_stage<<<B_ * S0_, 256, 0, stream>>>(S0_, N_, Gb, Pf, dv0, rows0, nn0, lg0, lb0, points,
                                              2, Xb1, LDP_, coords1);

  // ---- stage 1 ----
  k_fps<4><<<B_, 64, 0, stream>>>(S0_, S1_, coords1, 2, fps1);
  k_make_rows<<<(B_ * S1_) / 256, 256, 0, stream>>>(S1_, S0_, fps1, rows1);
  k_knn<4><<<B_ * S1_, 64, 0, stream>>>(S1_, S0_, coords1, 2, rows1, nn1);
  {
    dim3 g(LDP_ / 128, (B_ * S0_) / 128, 1);
    k_mgemm<1><<<g, 256, 0, stream>>>(B_ * S0_, C2_, LDP_, Xb1, LDP_, nullptr, dwb1, LDP_, nullptr,
                                      Fb, LDP_, LDP_);
  }
  {
    dim3 g(C_ / 128, (B_ * S1_) / 128, 1);
    k_mgemm<0><<<g, 256, 0, stream>>>(B_ * S1_, C_, LDP_, Xb1, LDP_, rows1, awab1, LDP_, ab1, Pf,
                                      C_, LDP_);
  }
  {
    dim3 g(C_ / 128, (B_ * S0_) / 128, 1);  // G1 bf16
    k_mgemm<1><<<g, 256, 0, stream>>>(B_ * S0_, C_, LDP_, Fb, LDP_, nullptr, awdb1, LDP_, nullptr,
                                      Gb, C_, LDP_);
  }
  k_fused_stage<<<B_ * S1_, 256, 0, stream>>>(S1_, S0_, Gb, Pf, dv1, rows1, nn1, lg1, lb1,
                                              nullptr, 0, fts2b, C_, nullptr);

  // ---- heads ----
  {
    dim3 g(8, 1, 32);  // flat: fused f32 W conversion, K-split 32 x 2048
    k_flat<<<g, 256, 0, stream>>>(fts2b, fw, hpart);
  }
  k_reduce<1><<<(B_ * C_ + 255) / 256, 256, 0, stream>>>(B_ * C_, C_, 32, hpart, fb, hidb);
  {
    dim3 g(OUT_ / 128, 1, 4);  // dim head: M=32, K=1024, z-split 4 x 256
    k_mgemm<0><<<g, 256, 0, stream>>>(B_, OUT_, C_, hidb, C_, nullptr, dmwb, C_, nullptr, opart,
                                      OUT_, 256);
  }
  k_reduce<0><<<(B_ * OUT_ + 255) / 256, 256, 0, stream>>>(B_ * OUT_, OUT_, 4, opart, dmb, out);
}

// Round 4
// 741.056 us; speedup vs baseline: 4.7867x; 1.1619x over previous
//
#include <hip/hip_runtime.h>
#include <cstdint>
#include <cstddef>

// ---------------- constants ----------------
static const int B_ = 32, N_ = 512, C_ = 1024, C2_ = 1026, CC2_ = 2052;
static const int S0_ = 256, S1_ = 64, K_ = 16, OUT_ = 3584;
static const int LDP_ = 1152;  // padded C2 (multiple of 128 and 32)

typedef unsigned short ushort;
typedef __attribute__((ext_vector_type(8))) short short8;
typedef __attribute__((ext_vector_type(4))) float f32x4;

__device__ __forceinline__ ushort f2bf(float x) {
  unsigned u = __float_as_uint(x);
  unsigned r = (u + 0x7fffu + ((u >> 16) & 1u)) >> 16;
  return (ushort)r;
}
__device__ __forceinline__ float bf2f(ushort b) {
  return __uint_as_float(((unsigned)b) << 16);
}

__device__ __forceinline__ void gload16(const void* g, void* l) {
  __builtin_amdgcn_global_load_lds((const __attribute__((address_space(1))) void*)g,
                                   (__attribute__((address_space(3))) void*)l, 16, 0, 0);
}

// ---------------- LDS-tiled transpose feat_map (C,H,W) -> (H*W, C) ----------------
__global__ __launch_bounds__(256) void k_transpose_fm(const float* __restrict__ f,
                                                      float* __restrict__ fmT) {
  __shared__ float tile[32][33];
  int yx0 = blockIdx.x * 32, c0 = blockIdx.y * 32;
  int tx = threadIdx.x & 31, ty = threadIdx.x >> 5;
#pragma unroll
  for (int i = 0; i < 4; i++)
    tile[ty + 8 * i][tx] = f[(size_t)(c0 + ty + 8 * i) * 1024 + yx0 + tx];
  __syncthreads();
#pragma unroll
  for (int i = 0; i < 4; i++)
    fmT[(size_t)(yx0 + ty + 8 * i) * 1024 + c0 + tx] = tile[tx][ty + 8 * i];
}

// ---------------- transpose + convert dw [1026,1026] f32 -> dwT bf16 [1152,1152] ----------
__global__ __launch_bounds__(256) void k_cvtT(const float* __restrict__ src,
                                              ushort* __restrict__ dst) {
  __shared__ float tile[32][33];
  int bx = blockIdx.x * 32;  // src col (d)
  int by = blockIdx.y * 32;  // src row (e)
  int tx = threadIdx.x & 31, ty4 = (threadIdx.x >> 5) * 4;
#pragma unroll
  for (int i = 0; i < 4; i++) {
    int r = by + ty4 + i, c = bx + tx;
    tile[ty4 + i][tx] = (r < C2_ && c < C2_) ? src[(size_t)r * C2_ + c] : 0.f;
  }
  __syncthreads();
#pragma unroll
  for (int i = 0; i < 4; i++) {
    int dr = bx + ty4 + i;  // d
    int dc = by + tx;       // e
    dst[(size_t)dr * LDP_ + dc] = f2bf(tile[tx][ty4 + i]);
  }
}

// ---------------- bilinear sample -> Xb0 rows bf16 [feat(1024) | p0 p1 | pad0] ----------------
__global__ __launch_bounds__(256) void k_bilinear(const float* __restrict__ points,
                                                  const float* __restrict__ fmT,
                                                  ushort* __restrict__ X0) {
  int r = blockIdx.x;  // b*512+n
  float p0 = points[r * 2 + 0], p1 = points[r * 2 + 1];
  float g0 = __fsub_rn(__fmul_rn(2.0f, p1), 1.0f);
  float g1 = __fsub_rn(__fmul_rn(2.0f, p0), 1.0f);
  float x = __fmul_rn(__fmul_rn(__fadd_rn(g0, 1.0f), 0.5f), 31.0f);
  float y = __fmul_rn(__fmul_rn(__fadd_rn(g1, 1.0f), 0.5f), 31.0f);
  float x0f = floorf(x), y0f = floorf(y);
  float wx = __fsub_rn(x, x0f), wy = __fsub_rn(y, y0f);
  int x0i = (int)fminf(fmaxf(x0f, 0.f), 31.f);
  int x1i = (int)fminf(fmaxf(__fadd_rn(x0f, 1.f), 0.f), 31.f);
  int y0i = (int)fminf(fmaxf(y0f, 0.f), 31.f);
  int y1i = (int)fminf(fmaxf(__fadd_rn(y0f, 1.f), 0.f), 31.f);
  float omwx = __fsub_rn(1.f, wx), omwy = __fsub_rn(1.f, wy);
  size_t i00 = (size_t)(y0i * 32 + x0i) * 1024;
  size_t i01 = (size_t)(y0i * 32 + x1i) * 1024;
  size_t i10 = (size_t)(y1i * 32 + x0i) * 1024;
  size_t i11 = (size_t)(y1i * 32 + x1i) * 1024;
  int t = threadIdx.x;
  ushort* xr = X0 + (size_t)r * LDP_;
#pragma unroll
  for (int i = 0; i < 4; i++) {
    int c = t + 256 * i;
    float f00 = fmT[i00 + c], f01 = fmT[i01 + c], f10 = fmT[i10 + c], f11 = fmT[i11 + c];
    float t1 = f00 * omwx * omwy;
    float t2 = f01 * wx * omwy;
    float t3 = f10 * omwx * wy;
    float t4 = f11 * wx * wy;
    xr[c] = f2bf(((t1 + t2) + t3) + t4);
  }
  if (t == 0) { xr[1024] = f2bf(p0); xr[1025] = f2bf(p1); }
  if (t < 126) xr[1026 + t] = 0;
}

// ---------------- f32 -> bf16 convert with pad (dst [Rp][dld], zero outside R x Ceff) ----------
__global__ __launch_bounds__(256) void k_cvt(const float* __restrict__ src, int sld, int soff,
                                             int R, int Ceff, ushort* __restrict__ dst, int dld,
                                             unsigned total2) {
  unsigned i = blockIdx.x * 256u + threadIdx.x;
  if (i >= total2) return;
  unsigned e = i * 2u;
  unsigned r = e / (unsigned)dld, c = e % (unsigned)dld;
  float v0 = 0.f, v1 = 0.f;
  if ((int)r < R) {
    const float* sp = src + (size_t)r * sld + soff + c;
    if ((int)c < Ceff) v0 = sp[0];
    if ((int)(c + 1) < Ceff) v1 = sp[1];
  }
  unsigned u = (unsigned)f2bf(v0) | ((unsigned)f2bf(v1) << 16);
  *(unsigned*)(dst + e) = u;
}

// ---------------- dvec[c] = sum_d db[d]*aw[c,d], one wave per c ----------------
__global__ __launch_bounds__(256) void k_dvec(const float* __restrict__ db,
                                              const float* __restrict__ aw,
                                              float* __restrict__ dvec) {
  int w = threadIdx.x >> 6, lane = threadIdx.x & 63;
  int c = blockIdx.x * 4 + w;
  const float* wr = aw + (size_t)c * CC2_;
  float s = 0.f;
  for (int d = lane; d < C2_; d += 64) s += db[d] * wr[d];
#pragma unroll
  for (int off = 32; off; off >>= 1) s += __shfl_xor(s, off);
  if (lane == 0) dvec[c] = s;
}

// ---------------- FPS: one wave per batch, register-resident, packed u64 argmax ------------
// writes GLOBAL row indices rows[b*nsub+s] = b*Np + far
template <int NPL>
__global__ __launch_bounds__(64) void k_fps(int Np, int nsub, const float* __restrict__ pts,
                                            int stride, int* __restrict__ rows) {
  int b = blockIdx.x;
  int lane = threadIdx.x;
  const float* pb = pts + (size_t)b * Np * stride;
  float px[NPL], py[NPL], dist[NPL];
#pragma unroll
  for (int i = 0; i < NPL; i++) {
    int j = lane + 64 * i;
    px[i] = pb[(size_t)j * stride + 0];
    py[i] = pb[(size_t)j * stride + 1];
    dist[i] = 1e10f;
  }
  int far = 0;
  float fx = pb[0], fy = pb[1];
  for (int s = 0; s < nsub; s++) {
    if (lane == 0) rows[b * nsub + s] = b * Np + far;
    unsigned long long best = 0ull;
#pragma unroll
    for (int i = 0; i < NPL; i++) {
      float dx = __fsub_rn(px[i], fx), dy = __fsub_rn(py[i], fy);
      float d = __fadd_rn(__fmul_rn(dx, dx), __fmul_rn(dy, dy));
      dist[i] = fminf(dist[i], d);
      unsigned long long pk =
          ((unsigned long long)__float_as_uint(dist[i]) << 32) | (unsigned)(~(lane + 64 * i));
      best = pk > best ? pk : best;
    }
#pragma unroll
    for (int off = 32; off; off >>= 1) {
      unsigned long long o = __shfl_xor(best, off);
      best = o > best ? o : best;
    }
    int j = (int)(~(unsigned)best);
    far = j;
    int chunk = j >> 6, owner = j & 63;
    float cx = px[0], cy = py[0];
#pragma unroll
    for (int i = 1; i < NPL; i++) {
      bool c = (chunk == i);
      cx = c ? px[i] : cx;
      cy = c ? py[i] : cy;
    }
    fx = __shfl(cx, owner);
    fy = __shfl(cy, owner);
  }
}

// ---------------- kNN: one wave per (b,s); writes GLOBAL row indices ----------------
template <int NPL>
__global__ __launch_bounds__(64) void k_knn(int S, int Np, const float* __restrict__ pts,
                                            int stride, const int* __restrict__ rows,
                                            int* __restrict__ nn) {
  int bs = blockIdx.x;
  int b = bs / S;
  int lane = threadIdx.x;
  const float* pb = pts + (size_t)b * Np * stride;
  int arow = rows[bs];
  float ax = pts[(size_t)arow * stride + 0];
  float ay = pts[(size_t)arow * stride + 1];
  float d2[NPL];
#pragma unroll
  for (int i = 0; i < NPL; i++) {
    int j = lane + 64 * i;
    float dx = __fsub_rn(ax, pb[(size_t)j * stride + 0]);
    float dy = __fsub_rn(ay, pb[(size_t)j * stride + 1]);
    d2[i] = __fadd_rn(__fmul_rn(dx, dx), __fmul_rn(dy, dy));
  }
  unsigned mask = 0;
  for (int k = 0; k < K_; k++) {
    float bv = INFINITY; int bi = 0x7fffffff;
#pragma unroll
    for (int i = 0; i < NPL; i++) {
      int j = lane + 64 * i;
      bool used = (mask >> i) & 1u;
      if (!used && (d2[i] < bv || (d2[i] == bv && j < bi))) { bv = d2[i]; bi = j; }
    }
#pragma unroll
    for (int off = 32; off; off >>= 1) {
      float ov = __shfl_xor(bv, off);
      int oi = __shfl_xor(bi, off);
      if (ov < bv || (ov == bv && oi < bi)) { bv = ov; bi = oi; }
    }
    if ((bi & 63) == lane) mask |= 1u << (bi >> 6);
    if (lane == 0) nn[bs * K_ + k] = b * Np + bi;
  }
}

// ---------------- bf16 MFMA GEMM: C[M,cov(N)] = A(rowidx)[M,K]dot W[N,K] ----------------
// OMODE 0: f32 out (+bias if gridz==1, z-slabs otherwise). OMODE 1: bf16 out, zero for c>=Neff.
template <int OMODE>
__global__ __launch_bounds__(256) void k_mgemm(int M, int Neff, int K,
                                               const ushort* __restrict__ A, int lda,
                                               const int* __restrict__ rowidx,
                                               const ushort* __restrict__ Wt, int ldw,
                                               const float* __restrict__ bias,
                                               void* __restrict__ Cout, int ldc, int kchunk) {
  __shared__ ushort As[128 * 32];
  __shared__ ushort Bs[128 * 32];
  int t = threadIdx.x;
  int w = t >> 6, l = t & 63;
  int row0 = blockIdx.y * 128, col0 = blockIdx.x * 128;
  int k0 = blockIdx.z * kchunk;
  int k1 = min(K, k0 + kchunk);
  f32x4 acc[4][4];
#pragma unroll
  for (int i = 0; i < 4; i++)
#pragma unroll
    for (int j = 0; j < 4; j++) acc[i][j] = (f32x4){0.f, 0.f, 0.f, 0.f};

  int srow = l >> 2;
  int scol = (l & 3) * 8;
  int ar0 = min(row0 + w * 16 + srow, M - 1);
  int ar1 = min(row0 + 64 + w * 16 + srow, M - 1);
  if (rowidx) { ar0 = rowidx[ar0]; ar1 = rowidx[ar1]; }
  const ushort* gA0 = A + (size_t)ar0 * lda + scol;
  const ushort* gA1 = A + (size_t)ar1 * lda + scol;
  const ushort* gB0 = Wt + (size_t)(col0 + w * 16 + srow) * ldw + scol;
  const ushort* gB1 = Wt + (size_t)(col0 + 64 + w * 16 + srow) * ldw + scol;
  ushort* lA0 = As + w * 512;
  ushort* lA1 = As + 2048 + w * 512;
  ushort* lB0 = Bs + w * 512;
  ushort* lB1 = Bs + 2048 + w * 512;

  int wm = w >> 1, wn = w & 1;
  int fr = l & 15, fg = l >> 4;

  for (int kt = k0; kt < k1; kt += 32) {
    __syncthreads();
    gload16(gA0 + kt, lA0);
    gload16(gA1 + kt, lA1);
    gload16(gB0 + kt, lB0);
    gload16(gB1 + kt, lB1);
    __syncthreads();
    short8 af[4], bf[4];
#pragma unroll
    for (int mi = 0; mi < 4; mi++)
      af[mi] = *(const short8*)&As[(wm * 64 + mi * 16 + fr) * 32 + fg * 8];
#pragma unroll
    for (int ni = 0; ni < 4; ni++)
      bf[ni] = *(const short8*)&Bs[(wn * 64 + ni * 16 + fr) * 32 + fg * 8];
#pragma unroll
    for (int mi = 0; mi < 4; mi++)
#pragma unroll
      for (int ni = 0; ni < 4; ni++)
        acc[mi][ni] = __builtin_amdgcn_mfma_f32_16x16x32_bf16(af[mi], bf[ni], acc[mi][ni], 0, 0, 0);
  }

  if (OMODE == 0) {
    float* C = (float*)Cout + (size_t)blockIdx.z * M * ldc;
    bool addb = (bias != nullptr) && (gridDim.z == 1);
#pragma unroll
    for (int mi = 0; mi < 4; mi++)
#pragma unroll
      for (int ni = 0; ni < 4; ni++)
#pragma unroll
        for (int q = 0; q < 4; q++) {
          int r = row0 + wm * 64 + mi * 16 + fg * 4 + q;
          int c = col0 + wn * 64 + ni * 16 + fr;
          if (r < M) {
            float v = acc[mi][ni][q];
            if (addb) v += bias[c];
            C[(size_t)r * ldc + c] = v;
          }
        }
  } else {
    ushort* C = (ushort*)Cout;
#pragma unroll
    for (int mi = 0; mi < 4; mi++)
#pragma unroll
      for (int ni = 0; ni < 4; ni++)
#pragma unroll
        for (int q = 0; q < 4; q++) {
          int r = row0 + wm * 64 + mi * 16 + fg * 4 + q;
          int c = col0 + wn * 64 + ni * 16 + fr;
          if (r < M) C[(size_t)r * ldc + c] = f2bf(c < Neff ? acc[mi][ni][q] : 0.f);
        }
  }
}

// ---------------- flat head GEMM with fused f32->bf16 W conversion ----------------
__global__ __launch_bounds__(256) void k_flat(const ushort* __restrict__ A,   // [32][65536] bf16
                                              const float* __restrict__ W,    // [1024][65536] f32
                                              float* __restrict__ Cp) {       // [32][32][1024]
  int t = threadIdx.x;
  int w = t >> 6, l = t & 63;
  int fr = l & 15, fg = l >> 4;
  int col0 = blockIdx.x * 128 + w * 32;
  size_t k0 = (size_t)blockIdx.z * 2048;
  f32x4 acc[2][2];
#pragma unroll
  for (int i = 0; i < 2; i++)
#pragma unroll
    for (int j = 0; j < 2; j++) acc[i][j] = (f32x4){0.f, 0.f, 0.f, 0.f};
  const ushort* a0 = A + (size_t)fr * 65536 + k0 + fg * 8;
  const ushort* a1 = A + (size_t)(16 + fr) * 65536 + k0 + fg * 8;
  const float* b0 = W + (size_t)(col0 + fr) * 65536 + k0 + fg * 8;
  const float* b1 = W + (size_t)(col0 + 16 + fr) * 65536 + k0 + fg * 8;
  for (int kt = 0; kt < 2048; kt += 32) {
    short8 af0 = *(const short8*)(a0 + kt);
    short8 af1 = *(const short8*)(a1 + kt);
    float4 p0 = *(const float4*)(b0 + kt);
    float4 p1 = *(const float4*)(b0 + kt + 4);
    float4 q0 = *(const float4*)(b1 + kt);
    float4 q1 = *(const float4*)(b1 + kt + 4);
    short8 bf0, bf1;
    bf0[0] = (short)f2bf(p0.x); bf0[1] = (short)f2bf(p0.y);
    bf0[2] = (short)f2bf(p0.z); bf0[3] = (short)f2bf(p0.w);
    bf0[4] = (short)f2bf(p1.x); bf0[5] = (short)f2bf(p1.y);
    bf0[6] = (short)f2bf(p1.z); bf0[7] = (short)f2bf(p1.w);
    bf1[0] = (short)f2bf(q0.x); bf1[1] = (short)f2bf(q0.y);
    bf1[2] = (short)f2bf(q0.z); bf1[3] = (short)f2bf(q0.w);
    bf1[4] = (short)f2bf(q1.x); bf1[5] = (short)f2bf(q1.y);
    bf1[6] = (short)f2bf(q1.z); bf1[7] = (short)f2bf(q1.w);
    acc[0][0] = __builtin_amdgcn_mfma_f32_16x16x32_bf16(af0, bf0, acc[0][0], 0, 0, 0);
    acc[1][0] = __builtin_amdgcn_mfma_f32_16x16x32_bf16(af1, bf0, acc[1][0], 0, 0, 0);
    acc[0][1] = __builtin_amdgcn_mfma_f32_16x16x32_bf16(af0, bf1, acc[0][1], 0, 0, 0);
    acc[1][1] = __builtin_amdgcn_mfma_f32_16x16x32_bf16(af1, bf1, acc[1][1], 0, 0, 0);
  }
  float* Cz = Cp + (size_t)blockIdx.z * 32 * 1024;
#pragma unroll
  for (int mi = 0; mi < 2; mi++)
#pragma unroll
    for (int ni = 0; ni < 2; ni++)
#pragma unroll
      for (int q = 0; q < 4; q++) {
        int r = mi * 16 + fg * 4 + q;
        int c = col0 + ni * 16 + fr;
        Cz[(size_t)r * 1024 + c] = acc[mi][ni][q];
      }
}

// ---------------- fused stage: gather bf16 G + base, relu, LN, max over k -> bf16 ----------
__global__ __launch_bounds__(256) void k_fused_stage(
    const ushort* __restrict__ G, const float* __restrict__ P, const float* __restrict__ dvec,
    const int* __restrict__ rows, const int* __restrict__ nn, const float* __restrict__ lng,
    const float* __restrict__ lnb, const float* __restrict__ prev_pts, int pts_stride,
    ushort* __restrict__ Xout, int ld_out, float* __restrict__ coords_out) {
  int bs = blockIdx.x;
  int t = threadIdx.x;
  int c0 = t * 4;
  int arow = rows[bs];
  float base[4], acc[4];
  {
    float4 pv = *(const float4*)(P + (size_t)bs * C_ + c0);
    float4 dv = *(const float4*)(dvec + c0);
    uint2 gv = *(const uint2*)(G + (size_t)arow * C_ + c0);
    float ga[4] = {bf2f((ushort)(gv.x & 0xffff)), bf2f((ushort)(gv.x >> 16)),
                   bf2f((ushort)(gv.y & 0xffff)), bf2f((ushort)(gv.y >> 16))};
    float pvv[4] = {pv.x, pv.y, pv.z, pv.w};
    float dvv[4] = {dv.x, dv.y, dv.z, dv.w};
#pragma unroll
    for (int i = 0; i < 4; i++) {
      base[i] = pvv[i] - ga[i] + dvv[i];
      acc[i] = -INFINITY;
    }
  }
  float4 lgv = *(const float4*)(lng + c0);
  float4 lbv = *(const float4*)(lnb + c0);
  float lg[4] = {lgv.x, lgv.y, lgv.z, lgv.w};
  float lb[4] = {lbv.x, lbv.y, lbv.z, lbv.w};
  __shared__ float red[2][4];
  int lane = t & 63, w = t >> 6;
  for (int k = 0; k < K_; k++) {
    int g = nn[bs * K_ + k];
    const ushort* Gr = G + (size_t)g * C_;
    uint2 gv = *(const uint2*)(Gr + c0);
    float gn[4] = {bf2f((ushort)(gv.x & 0xffff)), bf2f((ushort)(gv.x >> 16)),
                   bf2f((ushort)(gv.y & 0xffff)), bf2f((ushort)(gv.y >> 16))};
    float v[4];
    float s1 = 0.f, s2 = 0.f;
#pragma unroll
    for (int i = 0; i < 4; i++) {
      float x = gn[i] + base[i];
      x = fmaxf(x, 0.f);
      v[i] = x;
      s1 += x;
      s2 += x * x;
    }
#pragma unroll
    for (int off = 32; off; off >>= 1) {
      s1 += __shfl_xor(s1, off);
      s2 += __shfl_xor(s2, off);
    }
    if (lane == 0) { red[0][w] = s1; red[1][w] = s2; }
    __syncthreads();
    float fs1 = red[0][0] + red[0][1] + red[0][2] + red[0][3];
    float fs2 = red[1][0] + red[1][1] + red[1][2] + red[1][3];
    __syncthreads();
    float mu = fs1 * (1.f / 1024.f);
    float var = fs2 * (1.f / 1024.f) - mu * mu;
    float rstd = 1.f / sqrtf(var + 1e-5f);
#pragma unroll
    for (int i = 0; i < 4; i++) {
      float nv = (v[i] - mu) * rstd * lg[i] + lb[i];
      acc[i] = fmaxf(acc[i], nv);
    }
  }
  {
    unsigned u0 = (unsigned)f2bf(acc[0]) | ((unsigned)f2bf(acc[1]) << 16);
    unsigned u1 = (unsigned)f2bf(acc[2]) | ((unsigned)f2bf(acc[3]) << 16);
    uint2 uv = {u0, u1};
    *(uint2*)(Xout + (size_t)bs * ld_out + c0) = uv;
  }
  if (prev_pts) {
    float p0 = prev_pts[(size_t)arow * pts_stride + 0];
    float p1 = prev_pts[(size_t)arow * pts_stride + 1];
    if (t == 0) {
      Xout[(size_t)bs * ld_out + 1024] = f2bf(p0);
      Xout[(size_t)bs * ld_out + 1025] = f2bf(p1);
      coords_out[bs * 2 + 0] = p0;
      coords_out[bs * 2 + 1] = p1;
    }
    if (t < 126) Xout[(size_t)bs * ld_out + 1026 + t] = 0;
  }
}

// ---------------- reduce K-split partials + bias; OUTBF: write bf16 ----------------
template <int OUTBF>
__global__ __launch_bounds__(256) void k_reduce(int total, int Ncols, int nz,
                                                const float* __restrict__ part,
                                                const float* __restrict__ bias,
                                                void* __restrict__ out) {
  int i = blockIdx.x * 256 + threadIdx.x;
  if (i >= total) return;
  float s = bias[i % Ncols];
  for (int z = 0; z < nz; z++) s += part[(size_t)z * total + i];
  if (OUTBF)
    ((ushort*)out)[i] = f2bf(s);
  else
    ((float*)out)[i] = s;
}

// ---------------- launch ----------------
extern "C" void kernel_launch(void* const* d_in, const int* in_sizes, int n_in, void* d_out,
                              int out_size, void* d_ws, size_t ws_size, hipStream_t stream) {
  (void)in_sizes; (void)n_in; (void)out_size; (void)ws_size;
  const float* points = (const float*)d_in[0];
  const float* feat_map = (const float*)d_in[1];
  const float* dw0 = (const float*)d_in[2];
  const float* db0 = (const float*)d_in[3];
  const float* aw0 = (const float*)d_in[4];
  const float* ab0 = (const float*)d_in[5];
  const float* lg0 = (const float*)d_in[6];
  const float* lb0 = (const float*)d_in[7];
  const float* dw1 = (const float*)d_in[8];
  const float* db1 = (const float*)d_in[9];
  const float* aw1 = (const float*)d_in[10];
  const float* ab1 = (const float*)d_in[11];
  const float* lg1 = (const float*)d_in[12];
  const float* lb1 = (const float*)d_in[13];
  const float* fw = (const float*)d_in[14];
  const float* fb = (const float*)d_in[15];
  const float* dmw = (const float*)d_in[16];
  const float* dmb = (const float*)d_in[17];
  float* out = (float*)d_out;

  char* wsb = (char*)d_ws;
  size_t off = 0;
  auto alloc = [&](size_t bytes) -> void* {
    void* p = wsb + off;
    off = (off + bytes + 255) & ~(size_t)255;
    return p;
  };
  float* fmT = (float*)alloc((size_t)1024 * 1024 * 4);
  ushort* Xb0 = (ushort*)alloc((size_t)B_ * N_ * LDP_ * 2);
  ushort* Gb = (ushort*)alloc((size_t)B_ * N_ * C_ * 2);
  float* Pf = (float*)alloc((size_t)B_ * S0_ * C_ * 4);
  ushort* Xb1 = (ushort*)alloc((size_t)B_ * S0_ * LDP_ * 2);
  ushort* fts2b = (ushort*)alloc((size_t)B_ * S1_ * C_ * 2);
  float* coords1 = (float*)alloc((size_t)B_ * S0_ * 2 * 4);
  ushort* awdb0 = (ushort*)alloc((size_t)C_ * LDP_ * 2);
  ushort* awab0 = (ushort*)alloc((size_t)C_ * LDP_ * 2);
  ushort* awdb1 = (ushort*)alloc((size_t)C_ * LDP_ * 2);
  ushort* awab1 = (ushort*)alloc((size_t)C_ * LDP_ * 2);
  ushort* dwT0 = (ushort*)alloc((size_t)LDP_ * LDP_ * 2);
  ushort* dwT1 = (ushort*)alloc((size_t)LDP_ * LDP_ * 2);
  ushort* Wcb0 = (ushort*)alloc((size_t)C_ * LDP_ * 2);
  ushort* Wcb1 = (ushort*)alloc((size_t)C_ * LDP_ * 2);
  ushort* dmwb = (ushort*)alloc((size_t)OUT_ * C_ * 2);
  float* dv0 = (float*)alloc(1024 * 4);
  float* dv1 = (float*)alloc(1024 * 4);
  int* rows0 = (int*)alloc(B_ * S0_ * 4);
  int* nn0 = (int*)alloc(B_ * S0_ * K_ * 4);
  int* rows1 = (int*)alloc(B_ * S1_ * 4);
  int* nn1 = (int*)alloc(B_ * S1_ * K_ * 4);
  float* hpart = (float*)alloc((size_t)32 * B_ * C_ * 4);
  ushort* hidb = (ushort*)alloc((size_t)B_ * C_ * 2);
  float* opart = (float*)alloc((size_t)4 * B_ * OUT_ * 4);

  // ---- weight conversions ----
  {
    unsigned t2 = (unsigned)((size_t)C_ * LDP_ / 2);
    k_cvt<<<(t2 + 255) / 256, 256, 0, stream>>>(aw0, CC2_, 0, C_, C2_, awdb0, LDP_, t2);
    k_cvt<<<(t2 + 255) / 256, 256, 0, stream>>>(aw0, CC2_, C2_, C_, C2_, awab0, LDP_, t2);
    k_cvt<<<(t2 + 255) / 256, 256, 0, stream>>>(aw1, CC2_, 0, C_, C2_, awdb1, LDP_, t2);
    k_cvt<<<(t2 + 255) / 256, 256, 0, stream>>>(aw1, CC2_, C2_, C_, C2_, awab1, LDP_, t2);
    t2 = (unsigned)((size_t)OUT_ * C_ / 2);
    k_cvt<<<(t2 + 255) / 256, 256, 0, stream>>>(dmw, C_, 0, OUT_, C_, dmwb, C_, t2);
  }
  {
    dim3 g(36, 36, 1);
    k_cvtT<<<g, 256, 0, stream>>>(dw0, dwT0);
    k_cvtT<<<g, 256, 0, stream>>>(dw1, dwT1);
  }
  // combined weights Wc = awd @ dw  (C[c,d] = sum_e awd[c,e] dw[e,d])
  {
    dim3 g(LDP_ / 128, C_ / 128, 1);
    k_mgemm<1><<<g, 256, 0, stream>>>(C_, C2_, LDP_, awdb0, LDP_, nullptr, dwT0, LDP_, nullptr,
                                      Wcb0, LDP_, LDP_);
    k_mgemm<1><<<g, 256, 0, stream>>>(C_, C2_, LDP_, awdb1, LDP_, nullptr, dwT1, LDP_, nullptr,
                                      Wcb1, LDP_, LDP_);
  }
  k_dvec<<<256, 256, 0, stream>>>(db0, aw0, dv0);
  k_dvec<<<256, 256, 0, stream>>>(db1, aw1, dv1);

  {
    dim3 g(32, 32, 1);
    k_transpose_fm<<<g, 256, 0, stream>>>(feat_map, fmT);
  }
  k_bilinear<<<B_ * N_, 256, 0, stream>>>(points, fmT, Xb0);

  // ---- stage 0 ----
  k_fps<8><<<B_, 64, 0, stream>>>(N_, S0_, points, 2, rows0);
  k_knn<8><<<B_ * S0_, 64, 0, stream>>>(S0_, N_, points, 2, rows0, nn0);
  {
    dim3 g(C_ / 128, (B_ * S0_) / 128, 1);  // P0 (gathered anchors) + ab0
    k_mgemm<0><<<g, 256, 0, stream>>>(B_ * S0_, C_, LDP_, Xb0, LDP_, rows0, awab0, LDP_, ab0, Pf,
                                      C_, LDP_);
  }
  {
    dim3 g(C_ / 128, (B_ * N_) / 128, 1);  // G0 = Xb0 @ Wc0^T  (bf16 out)
    k_mgemm<1><<<g, 256, 0, stream>>>(B_ * N_, C_, LDP_, Xb0, LDP_, nullptr, Wcb0, LDP_, nullptr,
                                      Gb, C_, LDP_);
  }
  k_fused_stage<<<B_ * S0_, 256, 0, stream>>>(Gb, Pf, dv0, rows0, nn0, lg0, lb0, points, 2, Xb1,
                                              LDP_, coords1);

  // ---- stage 1 ----
  k_fps<4><<<B_, 64, 0, stream>>>(S0_, S1_, coords1, 2, rows1);
  k_knn<4><<<B_ * S1_, 64, 0, stream>>>(S1_, S0_, coords1, 2, rows1, nn1);
  {
    dim3 g(C_ / 128, (B_ * S1_) / 128, 1);  // P1 + ab1
    k_mgemm<0><<<g, 256, 0, stream>>>(B_ * S1_, C_, LDP_, Xb1, LDP_, rows1, awab1, LDP_, ab1, Pf,
                                      C_, LDP_);
  }
  {
    dim3 g(C_ / 128, (B_ * S0_) / 128, 1);  // G1 = Xb1 @ Wc1^T
    k_mgemm<1><<<g, 256, 0, stream>>>(B_ * S0_, C_, LDP_, Xb1, LDP_, nullptr, Wcb1, LDP_, nullptr,
                                      Gb, C_, LDP_);
  }
  k_fused_stage<<<B_ * S1_, 256, 0, stream>>>(Gb, Pf, dv1, rows1, nn1, lg1, lb1, nullptr, 0,
                                              fts2b, C_, nullptr);

  // ---- heads ----
  {
    dim3 g(8, 1, 32);  // flat: fused f32 W conversion, K-split 32 x 2048
    k_flat<<<g, 256, 0, stream>>>(fts2b, fw, hpart);
  }
  k_reduce<1><<<(B_ * C_ + 255) / 256, 256, 0, stream>>>(B_ * C_, C_, 32, hpart, fb, hidb);
  {
    dim3 g(OUT_ / 128, 1, 4);  // dim head: M=32, K=1024, z-split 4 x 256
    k_mgemm<0><<<g, 256, 0, stream>>>(B_, OUT_, C_, hidb, C_, nullptr, dmwb, C_, nullptr, opart,
                                      OUT_, 256);
  }
  k_reduce<0><<<(B_ * OUT_ + 255) / 256, 256, 0, stream>>>(B_ * OUT_, OUT_, 4, opart, dmb, out);
}

// Round 5
// 666.769 us; speedup vs baseline: 5.3200x; 1.1114x over previous
//
#include <hip/hip_runtime.h>
#include <cstdint>
#include <cstddef>

// ---------------- constants ----------------
static const int B_ = 32, N_ = 512, C_ = 1024, C2_ = 1026, CC2_ = 2052;
static const int S0_ = 256, S1_ = 64, K_ = 16, OUT_ = 3584;
static const int LDP_ = 1152;  // padded C2 (multiple of 128 and 32)

typedef unsigned short ushort;
typedef __attribute__((ext_vector_type(8))) short short8;
typedef __attribute__((ext_vector_type(4))) float f32x4;

__device__ __forceinline__ ushort f2bf(float x) {
  unsigned u = __float_as_uint(x);
  unsigned r = (u + 0x7fffu + ((u >> 16) & 1u)) >> 16;
  return (ushort)r;
}
__device__ __forceinline__ float bf2f(ushort b) {
  return __uint_as_float(((unsigned)b) << 16);
}

__device__ __forceinline__ void gload16(const void* g, void* l) {
  __builtin_amdgcn_global_load_lds((const __attribute__((address_space(1))) void*)g,
                                   (__attribute__((address_space(3))) void*)l, 16, 0, 0);
}

// ---------------- merged weight prep: cvts + transposes + dvec ----------------
// blocks: [0,9216) aw cvts | [9216,16384) dmw cvt | [16384,18976) dw transposes | [18976,19488) dvec
static const int PREP_CVT = 2304;       // per aw job: 1024*1152/2/256
static const int PREP_DMW = 7168;       // 3584*1024/2/256
static const int PREP_TT = 1296;        // 36x36 tiles
static const int PREP_TOTAL = 4 * PREP_CVT + PREP_DMW + 2 * PREP_TT + 512;

__global__ __launch_bounds__(256) void k_prep(
    const float* __restrict__ aw0, const float* __restrict__ aw1, const float* __restrict__ dmw,
    const float* __restrict__ dw0, const float* __restrict__ dw1, const float* __restrict__ db0,
    const float* __restrict__ ab0, const float* __restrict__ db1, const float* __restrict__ ab1,
    ushort* __restrict__ awdb0, ushort* __restrict__ awab0, ushort* __restrict__ awdb1,
    ushort* __restrict__ awab1, ushort* __restrict__ dmwb, ushort* __restrict__ dwT0,
    ushort* __restrict__ dwT1, float* __restrict__ dvp0, float* __restrict__ dvp1) {
  __shared__ float tile[32][33];
  int bid = blockIdx.x;
  if (bid < 4 * PREP_CVT) {
    int job = bid / PREP_CVT, lb = bid % PREP_CVT;
    const float* src = (job < 2) ? aw0 : aw1;
    int soff = (job & 1) ? C2_ : 0;
    ushort* dst = (job == 0) ? awdb0 : (job == 1) ? awab0 : (job == 2) ? awdb1 : awab1;
    unsigned e = (lb * 256u + threadIdx.x) * 2u;
    unsigned r = e / (unsigned)LDP_, c = e % (unsigned)LDP_;
    float v0 = 0.f, v1 = 0.f;
    const float* sp = src + (size_t)r * CC2_ + soff + c;
    if ((int)c < C2_) v0 = sp[0];
    if ((int)(c + 1) < C2_) v1 = sp[1];
    *(unsigned*)(dst + e) = (unsigned)f2bf(v0) | ((unsigned)f2bf(v1) << 16);
    return;
  }
  bid -= 4 * PREP_CVT;
  if (bid < PREP_DMW) {
    unsigned e = (bid * 256u + threadIdx.x) * 2u;
    float2 v = *(const float2*)(dmw + e);
    *(unsigned*)(dmwb + e) = (unsigned)f2bf(v.x) | ((unsigned)f2bf(v.y) << 16);
    return;
  }
  bid -= PREP_DMW;
  if (bid < 2 * PREP_TT) {
    int which = bid / PREP_TT, id = bid % PREP_TT;
    const float* src = which ? dw1 : dw0;
    ushort* dst = which ? dwT1 : dwT0;
    int bx = (id % 36) * 32, by = (id / 36) * 32;
    int tx = threadIdx.x & 31, ty4 = (threadIdx.x >> 5) * 4;
#pragma unroll
    for (int i = 0; i < 4; i++) {
      int r = by + ty4 + i, c = bx + tx;
      tile[ty4 + i][tx] = (r < C2_ && c < C2_) ? src[(size_t)r * C2_ + c] : 0.f;
    }
    __syncthreads();
#pragma unroll
    for (int i = 0; i < 4; i++) dst[(size_t)(bx + ty4 + i) * LDP_ + by + tx] = f2bf(tile[tx][ty4 + i]);
    return;
  }
  bid -= 2 * PREP_TT;
  // dvec': dvp[c] = ab[c] + sum_d db[d]*aw[c,d]
  int which = bid >> 8;
  int cb = bid & 255;
  const float* aw = which ? aw1 : aw0;
  const float* db = which ? db1 : db0;
  const float* ab = which ? ab1 : ab0;
  float* dvp = which ? dvp1 : dvp0;
  int w = threadIdx.x >> 6, lane = threadIdx.x & 63;
  int c = cb * 4 + w;
  const float* wr = aw + (size_t)c * CC2_;
  float s = 0.f;
  for (int d = lane; d < C2_; d += 64) s += db[d] * wr[d];
#pragma unroll
  for (int off = 32; off; off >>= 1) s += __shfl_xor(s, off);
  if (lane == 0) dvp[c] = ab[c] + s;
}

// ---------------- LDS-tiled transpose feat_map (C,H,W) -> (H*W, C) ----------------
__global__ __launch_bounds__(256) void k_transpose_fm(const float* __restrict__ f,
                                                      float* __restrict__ fmT) {
  __shared__ float tile[32][33];
  int yx0 = blockIdx.x * 32, c0 = blockIdx.y * 32;
  int tx = threadIdx.x & 31, ty = threadIdx.x >> 5;
#pragma unroll
  for (int i = 0; i < 4; i++)
    tile[ty + 8 * i][tx] = f[(size_t)(c0 + ty + 8 * i) * 1024 + yx0 + tx];
  __syncthreads();
#pragma unroll
  for (int i = 0; i < 4; i++)
    fmT[(size_t)(yx0 + ty + 8 * i) * 1024 + c0 + tx] = tile[tx][ty + 8 * i];
}

// ---------------- bilinear sample (vectorized) -> Xb0 rows bf16 ----------------
__global__ __launch_bounds__(256) void k_bilinear(const float* __restrict__ points,
                                                  const float* __restrict__ fmT,
                                                  ushort* __restrict__ X0) {
  int r = blockIdx.x;  // b*512+n
  float p0 = points[r * 2 + 0], p1 = points[r * 2 + 1];
  float g0 = __fsub_rn(__fmul_rn(2.0f, p1), 1.0f);
  float g1 = __fsub_rn(__fmul_rn(2.0f, p0), 1.0f);
  float x = __fmul_rn(__fmul_rn(__fadd_rn(g0, 1.0f), 0.5f), 31.0f);
  float y = __fmul_rn(__fmul_rn(__fadd_rn(g1, 1.0f), 0.5f), 31.0f);
  float x0f = floorf(x), y0f = floorf(y);
  float wx = __fsub_rn(x, x0f), wy = __fsub_rn(y, y0f);
  int x0i = (int)fminf(fmaxf(x0f, 0.f), 31.f);
  int x1i = (int)fminf(fmaxf(__fadd_rn(x0f, 1.f), 0.f), 31.f);
  int y0i = (int)fminf(fmaxf(y0f, 0.f), 31.f);
  int y1i = (int)fminf(fmaxf(__fadd_rn(y0f, 1.f), 0.f), 31.f);
  float omwx = __fsub_rn(1.f, wx), omwy = __fsub_rn(1.f, wy);
  size_t i00 = (size_t)(y0i * 32 + x0i) * 1024;
  size_t i01 = (size_t)(y0i * 32 + x1i) * 1024;
  size_t i10 = (size_t)(y1i * 32 + x0i) * 1024;
  size_t i11 = (size_t)(y1i * 32 + x1i) * 1024;
  int t = threadIdx.x;
  int c0 = t * 4;
  ushort* xr = X0 + (size_t)r * LDP_;
  float4 f00 = *(const float4*)(fmT + i00 + c0);
  float4 f01 = *(const float4*)(fmT + i01 + c0);
  float4 f10 = *(const float4*)(fmT + i10 + c0);
  float4 f11 = *(const float4*)(fmT + i11 + c0);
  float a[4] = {f00.x, f00.y, f00.z, f00.w};
  float b[4] = {f01.x, f01.y, f01.z, f01.w};
  float c[4] = {f10.x, f10.y, f10.z, f10.w};
  float d[4] = {f11.x, f11.y, f11.z, f11.w};
  ushort o[4];
#pragma unroll
  for (int i = 0; i < 4; i++) {
    float t1 = a[i] * omwx * omwy;
    float t2 = b[i] * wx * omwy;
    float t3 = c[i] * omwx * wy;
    float t4 = d[i] * wx * wy;
    o[i] = f2bf(((t1 + t2) + t3) + t4);
  }
  uint2 uv = {(unsigned)o[0] | ((unsigned)o[1] << 16), (unsigned)o[2] | ((unsigned)o[3] << 16)};
  *(uint2*)(xr + c0) = uv;
  if (t == 0) { xr[1024] = f2bf(p0); xr[1025] = f2bf(p1); }
  if (t < 126) xr[1026 + t] = 0;
}

// ---------------- FPS: one wave per batch, register-resident, packed u64 argmax ------------
template <int NPL>
__global__ __launch_bounds__(64) void k_fps(int Np, int nsub, const float* __restrict__ pts,
                                            int stride, int* __restrict__ rows) {
  int b = blockIdx.x;
  int lane = threadIdx.x;
  const float* pb = pts + (size_t)b * Np * stride;
  float px[NPL], py[NPL], dist[NPL];
#pragma unroll
  for (int i = 0; i < NPL; i++) {
    int j = lane + 64 * i;
    px[i] = pb[(size_t)j * stride + 0];
    py[i] = pb[(size_t)j * stride + 1];
    dist[i] = 1e10f;
  }
  int far = 0;
  float fx = pb[0], fy = pb[1];
  for (int s = 0; s < nsub; s++) {
    if (lane == 0) rows[b * nsub + s] = b * Np + far;
    unsigned long long best = 0ull;
#pragma unroll
    for (int i = 0; i < NPL; i++) {
      float dx = __fsub_rn(px[i], fx), dy = __fsub_rn(py[i], fy);
      float d = __fadd_rn(__fmul_rn(dx, dx), __fmul_rn(dy, dy));
      dist[i] = fminf(dist[i], d);
      unsigned long long pk =
          ((unsigned long long)__float_as_uint(dist[i]) << 32) | (unsigned)(~(lane + 64 * i));
      best = pk > best ? pk : best;
    }
#pragma unroll
    for (int off = 32; off; off >>= 1) {
      unsigned long long o = __shfl_xor(best, off);
      best = o > best ? o : best;
    }
    int j = (int)(~(unsigned)best);
    far = j;
    int chunk = j >> 6, owner = j & 63;
    float cx = px[0], cy = py[0];
#pragma unroll
    for (int i = 1; i < NPL; i++) {
      bool cnd = (chunk == i);
      cx = cnd ? px[i] : cx;
      cy = cnd ? py[i] : cy;
    }
    fx = __shfl(cx, owner);
    fy = __shfl(cy, owner);
  }
}

// ---------------- kNN: one wave per (b,s); writes GLOBAL row indices ----------------
template <int NPL>
__global__ __launch_bounds__(64) void k_knn(int S, int Np, const float* __restrict__ pts,
                                            int stride, const int* __restrict__ rows,
                                            int* __restrict__ nn) {
  int bs = blockIdx.x;
  int b = bs / S;
  int lane = threadIdx.x;
  const float* pb = pts + (size_t)b * Np * stride;
  int arow = rows[bs];
  float ax = pts[(size_t)arow * stride + 0];
  float ay = pts[(size_t)arow * stride + 1];
  float d2[NPL];
#pragma unroll
  for (int i = 0; i < NPL; i++) {
    int j = lane + 64 * i;
    float dx = __fsub_rn(ax, pb[(size_t)j * stride + 0]);
    float dy = __fsub_rn(ay, pb[(size_t)j * stride + 1]);
    d2[i] = __fadd_rn(__fmul_rn(dx, dx), __fmul_rn(dy, dy));
  }
  unsigned mask = 0;
  for (int k = 0; k < K_; k++) {
    float bv = INFINITY; int bi = 0x7fffffff;
#pragma unroll
    for (int i = 0; i < NPL; i++) {
      int j = lane + 64 * i;
      bool used = (mask >> i) & 1u;
      if (!used && (d2[i] < bv || (d2[i] == bv && j < bi))) { bv = d2[i]; bi = j; }
    }
#pragma unroll
    for (int off = 32; off; off >>= 1) {
      float ov = __shfl_xor(bv, off);
      int oi = __shfl_xor(bi, off);
      if (ov < bv || (ov == bv && oi < bi)) { bv = ov; bi = oi; }
    }
    if ((bi & 63) == lane) mask |= 1u << (bi >> 6);
    if (lane == 0) nn[bs * K_ + k] = b * Np + bi;
  }
}

// ---------------- bf16 MFMA GEMM ----------------
// OMODE 0: f32 out (+bias if gridz==1, z-slabs otherwise)
// OMODE 1: bf16 out, zero for c>=Neff
// OMODE 2: bf16 out + f32 bias
template <int OMODE>
__global__ __launch_bounds__(256) void k_mgemm(int M, int Neff, int K,
                                               const ushort* __restrict__ A, int lda,
                                               const int* __restrict__ rowidx,
                                               const ushort* __restrict__ Wt, int ldw,
                                               const float* __restrict__ bias,
                                               void* __restrict__ Cout, int ldc, int kchunk) {
  __shared__ ushort As[128 * 32];
  __shared__ ushort Bs[128 * 32];
  int t = threadIdx.x;
  int w = t >> 6, l = t & 63;
  int row0 = blockIdx.y * 128, col0 = blockIdx.x * 128;
  int k0 = blockIdx.z * kchunk;
  int k1 = min(K, k0 + kchunk);
  f32x4 acc[4][4];
#pragma unroll
  for (int i = 0; i < 4; i++)
#pragma unroll
    for (int j = 0; j < 4; j++) acc[i][j] = (f32x4){0.f, 0.f, 0.f, 0.f};

  int srow = l >> 2;
  int scol = (l & 3) * 8;
  int ar0 = min(row0 + w * 16 + srow, M - 1);
  int ar1 = min(row0 + 64 + w * 16 + srow, M - 1);
  if (rowidx) { ar0 = rowidx[ar0]; ar1 = rowidx[ar1]; }
  const ushort* gA0 = A + (size_t)ar0 * lda + scol;
  const ushort* gA1 = A + (size_t)ar1 * lda + scol;
  const ushort* gB0 = Wt + (size_t)(col0 + w * 16 + srow) * ldw + scol;
  const ushort* gB1 = Wt + (size_t)(col0 + 64 + w * 16 + srow) * ldw + scol;
  ushort* lA0 = As + w * 512;
  ushort* lA1 = As + 2048 + w * 512;
  ushort* lB0 = Bs + w * 512;
  ushort* lB1 = Bs + 2048 + w * 512;

  int wm = w >> 1, wn = w & 1;
  int fr = l & 15, fg = l >> 4;

  for (int kt = k0; kt < k1; kt += 32) {
    __syncthreads();
    gload16(gA0 + kt, lA0);
    gload16(gA1 + kt, lA1);
    gload16(gB0 + kt, lB0);
    gload16(gB1 + kt, lB1);
    __syncthreads();
    short8 af[4], bf[4];
#pragma unroll
    for (int mi = 0; mi < 4; mi++)
      af[mi] = *(const short8*)&As[(wm * 64 + mi * 16 + fr) * 32 + fg * 8];
#pragma unroll
    for (int ni = 0; ni < 4; ni++)
      bf[ni] = *(const short8*)&Bs[(wn * 64 + ni * 16 + fr) * 32 + fg * 8];
#pragma unroll
    for (int mi = 0; mi < 4; mi++)
#pragma unroll
      for (int ni = 0; ni < 4; ni++)
        acc[mi][ni] = __builtin_amdgcn_mfma_f32_16x16x32_bf16(af[mi], bf[ni], acc[mi][ni], 0, 0, 0);
  }

  if (OMODE == 0) {
    float* C = (float*)Cout + (size_t)blockIdx.z * M * ldc;
    bool addb = (bias != nullptr) && (gridDim.z == 1);
#pragma unroll
    for (int mi = 0; mi < 4; mi++)
#pragma unroll
      for (int ni = 0; ni < 4; ni++)
#pragma unroll
        for (int q = 0; q < 4; q++) {
          int r = row0 + wm * 64 + mi * 16 + fg * 4 + q;
          int c = col0 + wn * 64 + ni * 16 + fr;
          if (r < M) {
            float v = acc[mi][ni][q];
            if (addb) v += bias[c];
            C[(size_t)r * ldc + c] = v;
          }
        }
  } else if (OMODE == 1) {
    ushort* C = (ushort*)Cout;
#pragma unroll
    for (int mi = 0; mi < 4; mi++)
#pragma unroll
      for (int ni = 0; ni < 4; ni++)
#pragma unroll
        for (int q = 0; q < 4; q++) {
          int r = row0 + wm * 64 + mi * 16 + fg * 4 + q;
          int c = col0 + wn * 64 + ni * 16 + fr;
          if (r < M) C[(size_t)r * ldc + c] = f2bf(c < Neff ? acc[mi][ni][q] : 0.f);
        }
  } else {
    ushort* C = (ushort*)Cout;
#pragma unroll
    for (int mi = 0; mi < 4; mi++)
#pragma unroll
      for (int ni = 0; ni < 4; ni++)
#pragma unroll
        for (int q = 0; q < 4; q++) {
          int r = row0 + wm * 64 + mi * 16 + fg * 4 + q;
          int c = col0 + wn * 64 + ni * 16 + fr;
          if (r < M) C[(size_t)r * ldc + c] = f2bf(acc[mi][ni][q] + bias[c]);
        }
  }
}

// ---------------- flat head GEMM with fused f32->bf16 W conversion ----------------
__global__ __launch_bounds__(256) void k_flat(const ushort* __restrict__ A,   // [32][65536] bf16
                                              const float* __restrict__ W,    // [1024][65536] f32
                                              float* __restrict__ Cp) {       // [32][32][1024]
  int t = threadIdx.x;
  int w = t >> 6, l = t & 63;
  int fr = l & 15, fg = l >> 4;
  int col0 = blockIdx.x * 128 + w * 32;
  size_t k0 = (size_t)blockIdx.z * 2048;
  f32x4 acc[2][2];
#pragma unroll
  for (int i = 0; i < 2; i++)
#pragma unroll
    for (int j = 0; j < 2; j++) acc[i][j] = (f32x4){0.f, 0.f, 0.f, 0.f};
  const ushort* a0 = A + (size_t)fr * 65536 + k0 + fg * 8;
  const ushort* a1 = A + (size_t)(16 + fr) * 65536 + k0 + fg * 8;
  const float* b0 = W + (size_t)(col0 + fr) * 65536 + k0 + fg * 8;
  const float* b1 = W + (size_t)(col0 + 16 + fr) * 65536 + k0 + fg * 8;
  for (int kt = 0; kt < 2048; kt += 32) {
    short8 af0 = *(const short8*)(a0 + kt);
    short8 af1 = *(const short8*)(a1 + kt);
    float4 p0 = *(const float4*)(b0 + kt);
    float4 p1 = *(const float4*)(b0 + kt + 4);
    float4 q0 = *(const float4*)(b1 + kt);
    float4 q1 = *(const float4*)(b1 + kt + 4);
    short8 bf0, bf1;
    bf0[0] = (short)f2bf(p0.x); bf0[1] = (short)f2bf(p0.y);
    bf0[2] = (short)f2bf(p0.z); bf0[3] = (short)f2bf(p0.w);
    bf0[4] = (short)f2bf(p1.x); bf0[5] = (short)f2bf(p1.y);
    bf0[6] = (short)f2bf(p1.z); bf0[7] = (short)f2bf(p1.w);
    bf1[0] = (short)f2bf(q0.x); bf1[1] = (short)f2bf(q0.y);
    bf1[2] = (short)f2bf(q0.z); bf1[3] = (short)f2bf(q0.w);
    bf1[4] = (short)f2bf(q1.x); bf1[5] = (short)f2bf(q1.y);
    bf1[6] = (short)f2bf(q1.z); bf1[7] = (short)f2bf(q1.w);
    acc[0][0] = __builtin_amdgcn_mfma_f32_16x16x32_bf16(af0, bf0, acc[0][0], 0, 0, 0);
    acc[1][0] = __builtin_amdgcn_mfma_f32_16x16x32_bf16(af1, bf0, acc[1][0], 0, 0, 0);
    acc[0][1] = __builtin_amdgcn_mfma_f32_16x16x32_bf16(af0, bf1, acc[0][1], 0, 0, 0);
    acc[1][1] = __builtin_amdgcn_mfma_f32_16x16x32_bf16(af1, bf1, acc[1][1], 0, 0, 0);
  }
  float* Cz = Cp + (size_t)blockIdx.z * 32 * 1024;
#pragma unroll
  for (int mi = 0; mi < 2; mi++)
#pragma unroll
    for (int ni = 0; ni < 2; ni++)
#pragma unroll
      for (int q = 0; q < 4; q++) {
        int r = mi * 16 + fg * 4 + q;
        int c = col0 + ni * 16 + fr;
        Cz[(size_t)r * 1024 + c] = acc[mi][ni][q];
      }
}

// ---------------- fused stage v2: wave-per-k, barrier-free k-loop ----------------
// base = P(bf16, bias-folded) - G[anchor]; per k: relu -> LN (in-wave reduce) -> max
__global__ __launch_bounds__(256) void k_fused_stage(
    const ushort* __restrict__ G, const ushort* __restrict__ Pb, const int* __restrict__ rows,
    const int* __restrict__ nn, const float* __restrict__ lng, const float* __restrict__ lnb,
    const float* __restrict__ prev_pts, int pts_stride, ushort* __restrict__ Xout, int ld_out,
    float* __restrict__ coords_out) {
  __shared__ float sm[4][1024];
  int bs = blockIdx.x;
  int t = threadIdx.x;
  int w = t >> 6, lane = t & 63;
  int c0 = lane * 16;
  int arow = rows[bs];
  float base[16], lg[16], lb[16], acc[16];
  {
    short8 pA = *(const short8*)(Pb + (size_t)bs * C_ + c0);
    short8 pB = *(const short8*)(Pb + (size_t)bs * C_ + c0 + 8);
    short8 gA = *(const short8*)(G + (size_t)arow * C_ + c0);
    short8 gB = *(const short8*)(G + (size_t)arow * C_ + c0 + 8);
#pragma unroll
    for (int i = 0; i < 8; i++) {
      base[i] = bf2f((ushort)pA[i]) - bf2f((ushort)gA[i]);
      base[8 + i] = bf2f((ushort)pB[i]) - bf2f((ushort)gB[i]);
    }
#pragma unroll
    for (int i = 0; i < 4; i++) {
      float4 gv = *(const float4*)(lng + c0 + 4 * i);
      float4 bv = *(const float4*)(lnb + c0 + 4 * i);
      lg[4 * i] = gv.x; lg[4 * i + 1] = gv.y; lg[4 * i + 2] = gv.z; lg[4 * i + 3] = gv.w;
      lb[4 * i] = bv.x; lb[4 * i + 1] = bv.y; lb[4 * i + 2] = bv.z; lb[4 * i + 3] = bv.w;
      acc[4 * i] = -INFINITY; acc[4 * i + 1] = -INFINITY;
      acc[4 * i + 2] = -INFINITY; acc[4 * i + 3] = -INFINITY;
    }
  }
#pragma unroll
  for (int kk = 0; kk < 4; kk++) {
    int g = nn[bs * K_ + w * 4 + kk];
    const ushort* Gr = G + (size_t)g * C_ + c0;
    short8 xA = *(const short8*)(Gr);
    short8 xB = *(const short8*)(Gr + 8);
    float v[16];
    float s1 = 0.f, s2 = 0.f;
#pragma unroll
    for (int i = 0; i < 8; i++) {
      float x = fmaxf(bf2f((ushort)xA[i]) + base[i], 0.f);
      v[i] = x; s1 += x; s2 += x * x;
      float y = fmaxf(bf2f((ushort)xB[i]) + base[8 + i], 0.f);
      v[8 + i] = y; s1 += y; s2 += y * y;
    }
#pragma unroll
    for (int off = 32; off; off >>= 1) {
      s1 += __shfl_xor(s1, off);
      s2 += __shfl_xor(s2, off);
    }
    float mu = s1 * (1.f / 1024.f);
    float var = s2 * (1.f / 1024.f) - mu * mu;
    float rstd = 1.f / sqrtf(var + 1e-5f);
#pragma unroll
    for (int i = 0; i < 16; i++) {
      float nv = (v[i] - mu) * rstd * lg[i] + lb[i];
      acc[i] = fmaxf(acc[i], nv);
    }
  }
#pragma unroll
  for (int i = 0; i < 16; i += 4) {
    f32x4 av = {acc[i], acc[i + 1], acc[i + 2], acc[i + 3]};
    *(f32x4*)&sm[w][c0 + i] = av;
  }
  __syncthreads();
  {
    int cc = t * 4;
    f32x4 m0 = *(const f32x4*)&sm[0][cc];
    f32x4 m1 = *(const f32x4*)&sm[1][cc];
    f32x4 m2 = *(const f32x4*)&sm[2][cc];
    f32x4 m3 = *(const f32x4*)&sm[3][cc];
    ushort o[4];
#pragma unroll
    for (int j = 0; j < 4; j++)
      o[j] = f2bf(fmaxf(fmaxf(m0[j], m1[j]), fmaxf(m2[j], m3[j])));
    uint2 uv = {(unsigned)o[0] | ((unsigned)o[1] << 16), (unsigned)o[2] | ((unsigned)o[3] << 16)};
    *(uint2*)(Xout + (size_t)bs * ld_out + cc) = uv;
  }
  if (prev_pts) {
    float p0 = prev_pts[(size_t)arow * pts_stride + 0];
    float p1 = prev_pts[(size_t)arow * pts_stride + 1];
    if (t == 0) {
      Xout[(size_t)bs * ld_out + 1024] = f2bf(p0);
      Xout[(size_t)bs * ld_out + 1025] = f2bf(p1);
      coords_out[bs * 2 + 0] = p0;
      coords_out[bs * 2 + 1] = p1;
    }
    if (t < 126) Xout[(size_t)bs * ld_out + 1026 + t] = 0;
  }
}

// ---------------- reduce K-split partials + bias; OUTBF: write bf16 ----------------
template <int OUTBF>
__global__ __launch_bounds__(256) void k_reduce(int total, int Ncols, int nz,
                                                const float* __restrict__ part,
                                                const float* __restrict__ bias,
                                                void* __restrict__ out) {
  int i = blockIdx.x * 256 + threadIdx.x;
  if (i >= total) return;
  float s = bias[i % Ncols];
  for (int z = 0; z < nz; z++) s += part[(size_t)z * total + i];
  if (OUTBF)
    ((ushort*)out)[i] = f2bf(s);
  else
    ((float*)out)[i] = s;
}

// ---------------- launch ----------------
extern "C" void kernel_launch(void* const* d_in, const int* in_sizes, int n_in, void* d_out,
                              int out_size, void* d_ws, size_t ws_size, hipStream_t stream) {
  (void)in_sizes; (void)n_in; (void)out_size; (void)ws_size;
  const float* points = (const float*)d_in[0];
  const float* feat_map = (const float*)d_in[1];
  const float* dw0 = (const float*)d_in[2];
  const float* db0 = (const float*)d_in[3];
  const float* aw0 = (const float*)d_in[4];
  const float* ab0 = (const float*)d_in[5];
  const float* lg0 = (const float*)d_in[6];
  const float* lb0 = (const float*)d_in[7];
  const float* dw1 = (const float*)d_in[8];
  const float* db1 = (const float*)d_in[9];
  const float* aw1 = (const float*)d_in[10];
  const float* ab1 = (const float*)d_in[11];
  const float* lg1 = (const float*)d_in[12];
  const float* lb1 = (const float*)d_in[13];
  const float* fw = (const float*)d_in[14];
  const float* fb = (const float*)d_in[15];
  const float* dmw = (const float*)d_in[16];
  const float* dmb = (const float*)d_in[17];
  float* out = (float*)d_out;

  char* wsb = (char*)d_ws;
  size_t off = 0;
  auto alloc = [&](size_t bytes) -> void* {
    void* p = wsb + off;
    off = (off + bytes + 255) & ~(size_t)255;
    return p;
  };
  float* fmT = (float*)alloc((size_t)1024 * 1024 * 4);
  ushort* Xb0 = (ushort*)alloc((size_t)B_ * N_ * LDP_ * 2);
  ushort* Gb = (ushort*)alloc((size_t)B_ * N_ * C_ * 2);
  ushort* Pb = (ushort*)alloc((size_t)B_ * S0_ * C_ * 2);
  ushort* Xb1 = (ushort*)alloc((size_t)B_ * S0_ * LDP_ * 2);
  ushort* fts2b = (ushort*)alloc((size_t)B_ * S1_ * C_ * 2);
  float* coords1 = (float*)alloc((size_t)B_ * S0_ * 2 * 4);
  ushort* awdb0 = (ushort*)alloc((size_t)C_ * LDP_ * 2);
  ushort* awab0 = (ushort*)alloc((size_t)C_ * LDP_ * 2);
  ushort* awdb1 = (ushort*)alloc((size_t)C_ * LDP_ * 2);
  ushort* awab1 = (ushort*)alloc((size_t)C_ * LDP_ * 2);
  ushort* dwT0 = (ushort*)alloc((size_t)LDP_ * LDP_ * 2);
  ushort* dwT1 = (ushort*)alloc((size_t)LDP_ * LDP_ * 2);
  ushort* Wcb0 = (ushort*)alloc((size_t)C_ * LDP_ * 2);
  ushort* Wcb1 = (ushort*)alloc((size_t)C_ * LDP_ * 2);
  ushort* dmwb = (ushort*)alloc((size_t)OUT_ * C_ * 2);
  float* dvp0 = (float*)alloc(1024 * 4);
  float* dvp1 = (float*)alloc(1024 * 4);
  int* rows0 = (int*)alloc(B_ * S0_ * 4);
  int* nn0 = (int*)alloc(B_ * S0_ * K_ * 4);
  int* rows1 = (int*)alloc(B_ * S1_ * 4);
  int* nn1 = (int*)alloc(B_ * S1_ * K_ * 4);
  float* hpart = (float*)alloc((size_t)32 * B_ * C_ * 4);
  ushort* hidb = (ushort*)alloc((size_t)B_ * C_ * 2);
  float* opart = (float*)alloc((size_t)4 * B_ * OUT_ * 4);

  // ---- merged weight prep ----
  k_prep<<<PREP_TOTAL, 256, 0, stream>>>(aw0, aw1, dmw, dw0, dw1, db0, ab0, db1, ab1, awdb0,
                                         awab0, awdb1, awab1, dmwb, dwT0, dwT1, dvp0, dvp1);
  // combined weights Wc = awd @ dw
  {
    dim3 g(LDP_ / 128, C_ / 128, 1);
    k_mgemm<1><<<g, 256, 0, stream>>>(C_, C2_, LDP_, awdb0, LDP_, nullptr, dwT0, LDP_, nullptr,
                                      Wcb0, LDP_, LDP_);
    k_mgemm<1><<<g, 256, 0, stream>>>(C_, C2_, LDP_, awdb1, LDP_, nullptr, dwT1, LDP_, nullptr,
                                      Wcb1, LDP_, LDP_);
  }
  {
    dim3 g(32, 32, 1);
    k_transpose_fm<<<g, 256, 0, stream>>>(feat_map, fmT);
  }
  k_bilinear<<<B_ * N_, 256, 0, stream>>>(points, fmT, Xb0);

  // ---- stage 0 ----
  k_fps<8><<<B_, 64, 0, stream>>>(N_, S0_, points, 2, rows0);
  k_knn<8><<<B_ * S0_, 64, 0, stream>>>(S0_, N_, points, 2, rows0, nn0);
  {
    dim3 g(C_ / 128, (B_ * S0_) / 128, 1);  // P0 bf16, bias = ab0+dvec0
    k_mgemm<2><<<g, 256, 0, stream>>>(B_ * S0_, C_, LDP_, Xb0, LDP_, rows0, awab0, LDP_, dvp0, Pb,
                                      C_, LDP_);
  }
  {
    dim3 g(C_ / 128, (B_ * N_) / 128, 1);  // G0 = Xb0 @ Wc0^T  (bf16 out)
    k_mgemm<1><<<g, 256, 0, stream>>>(B_ * N_, C_, LDP_, Xb0, LDP_, nullptr, Wcb0, LDP_, nullptr,
                                      Gb, C_, LDP_);
  }
  k_fused_stage<<<B_ * S0_, 256, 0, stream>>>(Gb, Pb, rows0, nn0, lg0, lb0, points, 2, Xb1, LDP_,
                                              coords1);

  // ---- stage 1 ----
  k_fps<4><<<B_, 64, 0, stream>>>(S0_, S1_, coords1, 2, rows1);
  k_knn<4><<<B_ * S1_, 64, 0, stream>>>(S1_, S0_, coords1, 2, rows1, nn1);
  {
    dim3 g(C_ / 128, (B_ * S1_) / 128, 1);  // P1 bf16, bias = ab1+dvec1
    k_mgemm<2><<<g, 256, 0, stream>>>(B_ * S1_, C_, LDP_, Xb1, LDP_, rows1, awab1, LDP_, dvp1, Pb,
                                      C_, LDP_);
  }
  {
    dim3 g(C_ / 128, (B_ * S0_) / 128, 1);  // G1 = Xb1 @ Wc1^T
    k_mgemm<1><<<g, 256, 0, stream>>>(B_ * S0_, C_, LDP_, Xb1, LDP_, nullptr, Wcb1, LDP_, nullptr,
                                      Gb, C_, LDP_);
  }
  k_fused_stage<<<B_ * S1_, 256, 0, stream>>>(Gb, Pb, rows1, nn1, lg1, lb1, nullptr, 0, fts2b, C_,
                                              nullptr);

  // ---- heads ----
  {
    dim3 g(8, 1, 32);  // flat: fused f32 W conversion, K-split 32 x 2048
    k_flat<<<g, 256, 0, stream>>>(fts2b, fw, hpart);
  }
  k_reduce<1><<<(B_ * C_ + 255) / 256, 256, 0, stream>>>(B_ * C_, C_, 32, hpart, fb, hidb);
  {
    dim3 g(OUT_ / 128, 1, 4);  // dim head: M=32, K=1024, z-split 4 x 256
    k_mgemm<0><<<g, 256, 0, stream>>>(B_, OUT_, C_, hidb, C_, nullptr, dmwb, C_, nullptr, opart,
                                      OUT_, 256);
  }
  k_reduce<0><<<(B_ * OUT_ + 255) / 256, 256, 0, stream>>>(B_ * OUT_, OUT_, 4, opart, dmb, out);
}

// Round 6
// 551.292 us; speedup vs baseline: 6.4344x; 1.2095x over previous
//
#include <hip/hip_runtime.h>
#include <cstdint>
#include <cstddef>

// ---------------- constants ----------------
static const int B_ = 32, N_ = 512, C_ = 1024, C2_ = 1026, CC2_ = 2052;
static const int S0_ = 256, S1_ = 64, K_ = 16, OUT_ = 3584;
static const int LDP_ = 1152;  // padded C2 (multiple of 128 and 32)

typedef unsigned short ushort;
typedef __attribute__((ext_vector_type(8))) short short8;
typedef __attribute__((ext_vector_type(4))) float f32x4;

__device__ __forceinline__ ushort f2bf(float x) {
  unsigned u = __float_as_uint(x);
  unsigned r = (u + 0x7fffu + ((u >> 16) & 1u)) >> 16;
  return (ushort)r;
}
__device__ __forceinline__ float bf2f(ushort b) {
  return __uint_as_float(((unsigned)b) << 16);
}

__device__ __forceinline__ void gload16(const void* g, void* l) {
  __builtin_amdgcn_global_load_lds((const __attribute__((address_space(1))) void*)g,
                                   (__attribute__((address_space(3))) void*)l, 16, 0, 0);
}

// ================= device GEMM (128x128 tile, 4 waves, 16x16x32 MFMA, BK=32) =================
// OMODE 0: f32 out (+bias if gridz==1, z-slabs otherwise)
// OMODE 1: bf16 out, zero for c>=Neff
// OMODE 2: bf16 out + f32 bias
template <int OMODE>
__device__ __forceinline__ void dev_mgemm(int bx, int by, int bz, int gridz, ushort* As,
                                          ushort* Bs, int M, int Neff, int K,
                                          const ushort* __restrict__ A, int lda,
                                          const int* __restrict__ rowidx,
                                          const ushort* __restrict__ Wt, int ldw,
                                          const float* __restrict__ bias, void* __restrict__ Cout,
                                          int ldc, int kchunk) {
  int t = threadIdx.x;
  int w = t >> 6, l = t & 63;
  int row0 = by * 128, col0 = bx * 128;
  int k0 = bz * kchunk;
  int k1 = min(K, k0 + kchunk);
  f32x4 acc[4][4];
#pragma unroll
  for (int i = 0; i < 4; i++)
#pragma unroll
    for (int j = 0; j < 4; j++) acc[i][j] = (f32x4){0.f, 0.f, 0.f, 0.f};

  int srow = l >> 2;
  int scol = (l & 3) * 8;
  int ar0 = min(row0 + w * 16 + srow, M - 1);
  int ar1 = min(row0 + 64 + w * 16 + srow, M - 1);
  if (rowidx) { ar0 = rowidx[ar0]; ar1 = rowidx[ar1]; }
  const ushort* gA0 = A + (size_t)ar0 * lda + scol;
  const ushort* gA1 = A + (size_t)ar1 * lda + scol;
  const ushort* gB0 = Wt + (size_t)(col0 + w * 16 + srow) * ldw + scol;
  const ushort* gB1 = Wt + (size_t)(col0 + 64 + w * 16 + srow) * ldw + scol;
  ushort* lA0 = As + w * 512;
  ushort* lA1 = As + 2048 + w * 512;
  ushort* lB0 = Bs + w * 512;
  ushort* lB1 = Bs + 2048 + w * 512;

  int wm = w >> 1, wn = w & 1;
  int fr = l & 15, fg = l >> 4;

  for (int kt = k0; kt < k1; kt += 32) {
    __syncthreads();
    gload16(gA0 + kt, lA0);
    gload16(gA1 + kt, lA1);
    gload16(gB0 + kt, lB0);
    gload16(gB1 + kt, lB1);
    __syncthreads();
    short8 af[4], bf[4];
#pragma unroll
    for (int mi = 0; mi < 4; mi++)
      af[mi] = *(const short8*)&As[(wm * 64 + mi * 16 + fr) * 32 + fg * 8];
#pragma unroll
    for (int ni = 0; ni < 4; ni++)
      bf[ni] = *(const short8*)&Bs[(wn * 64 + ni * 16 + fr) * 32 + fg * 8];
#pragma unroll
    for (int mi = 0; mi < 4; mi++)
#pragma unroll
      for (int ni = 0; ni < 4; ni++)
        acc[mi][ni] = __builtin_amdgcn_mfma_f32_16x16x32_bf16(af[mi], bf[ni], acc[mi][ni], 0, 0, 0);
  }

  if (OMODE == 0) {
    float* C = (float*)Cout + (size_t)bz * M * ldc;
    bool addb = (bias != nullptr) && (gridz == 1);
#pragma unroll
    for (int mi = 0; mi < 4; mi++)
#pragma unroll
      for (int ni = 0; ni < 4; ni++)
#pragma unroll
        for (int q = 0; q < 4; q++) {
          int r = row0 + wm * 64 + mi * 16 + fg * 4 + q;
          int c = col0 + wn * 64 + ni * 16 + fr;
          if (r < M) {
            float v = acc[mi][ni][q];
            if (addb) v += bias[c];
            C[(size_t)r * ldc + c] = v;
          }
        }
  } else if (OMODE == 1) {
    ushort* C = (ushort*)Cout;
#pragma unroll
    for (int mi = 0; mi < 4; mi++)
#pragma unroll
      for (int ni = 0; ni < 4; ni++)
#pragma unroll
        for (int q = 0; q < 4; q++) {
          int r = row0 + wm * 64 + mi * 16 + fg * 4 + q;
          int c = col0 + wn * 64 + ni * 16 + fr;
          if (r < M) C[(size_t)r * ldc + c] = f2bf(c < Neff ? acc[mi][ni][q] : 0.f);
        }
  } else {
    ushort* C = (ushort*)Cout;
#pragma unroll
    for (int mi = 0; mi < 4; mi++)
#pragma unroll
      for (int ni = 0; ni < 4; ni++)
#pragma unroll
        for (int q = 0; q < 4; q++) {
          int r = row0 + wm * 64 + mi * 16 + fg * 4 + q;
          int c = col0 + wn * 64 + ni * 16 + fr;
          if (r < M) C[(size_t)r * ldc + c] = f2bf(acc[mi][ni][q] + bias[c]);
        }
  }
}

template <int OMODE>
__global__ __launch_bounds__(256) void k_mgemm(int M, int Neff, int K,
                                               const ushort* __restrict__ A, int lda,
                                               const int* __restrict__ rowidx,
                                               const ushort* __restrict__ Wt, int ldw,
                                               const float* __restrict__ bias,
                                               void* __restrict__ Cout, int ldc, int kchunk) {
  __shared__ ushort As[4096];
  __shared__ ushort Bs[4096];
  dev_mgemm<OMODE>(blockIdx.x, blockIdx.y, blockIdx.z, gridDim.z, As, Bs, M, Neff, K, A, lda,
                   rowidx, Wt, ldw, bias, Cout, ldc, kchunk);
}

// ================= device FPS (wave 0 only), packed u64 argmax, register-resident ============
template <int NPL>
__device__ __forceinline__ void dev_fps(int b, int Np, int nsub, const float* __restrict__ pts,
                                        int stride, int* __restrict__ rows) {
  int lane = threadIdx.x;  // caller guarantees < 64
  const float* pb = pts + (size_t)b * Np * stride;
  float px[NPL], py[NPL], dist[NPL];
#pragma unroll
  for (int i = 0; i < NPL; i++) {
    int j = lane + 64 * i;
    px[i] = pb[(size_t)j * stride + 0];
    py[i] = pb[(size_t)j * stride + 1];
    dist[i] = 1e10f;
  }
  int far = 0;
  float fx = pb[0], fy = pb[1];
  for (int s = 0; s < nsub; s++) {
    if (lane == 0) rows[b * nsub + s] = b * Np + far;
    unsigned long long best = 0ull;
#pragma unroll
    for (int i = 0; i < NPL; i++) {
      float dx = __fsub_rn(px[i], fx), dy = __fsub_rn(py[i], fy);
      float d = __fadd_rn(__fmul_rn(dx, dx), __fmul_rn(dy, dy));
      dist[i] = fminf(dist[i], d);
      unsigned long long pk =
          ((unsigned long long)__float_as_uint(dist[i]) << 32) | (unsigned)(~(lane + 64 * i));
      best = pk > best ? pk : best;
    }
#pragma unroll
    for (int off = 32; off; off >>= 1) {
      unsigned long long o = __shfl_xor(best, off);
      best = o > best ? o : best;
    }
    int j = (int)(~(unsigned)best);
    far = j;
    int chunk = j >> 6, owner = j & 63;
    float cx = px[0], cy = py[0];
#pragma unroll
    for (int i = 1; i < NPL; i++) {
      bool cnd = (chunk == i);
      cx = cnd ? px[i] : cx;
      cy = cnd ? py[i] : cy;
    }
    fx = __shfl(cx, owner);
    fy = __shfl(cy, owner);
  }
}

// ================= device kNN (one wave per query) ==========================================
template <int NPL>
__device__ __forceinline__ void dev_knn(int bs, int S, int Np, const float* __restrict__ pts,
                                        int stride, const int* __restrict__ rows,
                                        int* __restrict__ nn) {
  int b = bs / S;
  int lane = threadIdx.x & 63;
  const float* pb = pts + (size_t)b * Np * stride;
  int arow = rows[bs];
  float ax = pts[(size_t)arow * stride + 0];
  float ay = pts[(size_t)arow * stride + 1];
  float d2[NPL];
#pragma unroll
  for (int i = 0; i < NPL; i++) {
    int j = lane + 64 * i;
    float dx = __fsub_rn(ax, pb[(size_t)j * stride + 0]);
    float dy = __fsub_rn(ay, pb[(size_t)j * stride + 1]);
    d2[i] = __fadd_rn(__fmul_rn(dx, dx), __fmul_rn(dy, dy));
  }
  unsigned mask = 0;
  for (int k = 0; k < K_; k++) {
    float bv = INFINITY;
    int bi = 0x7fffffff;
#pragma unroll
    for (int i = 0; i < NPL; i++) {
      int j = lane + 64 * i;
      bool used = (mask >> i) & 1u;
      if (!used && (d2[i] < bv || (d2[i] == bv && j < bi))) { bv = d2[i]; bi = j; }
    }
#pragma unroll
    for (int off = 32; off; off >>= 1) {
      float ov = __shfl_xor(bv, off);
      int oi = __shfl_xor(bi, off);
      if (ov < bv || (ov == bv && oi < bi)) { bv = ov; bi = oi; }
    }
    if ((bi & 63) == lane) mask |= 1u << (bi >> 6);
    if (lane == 0) nn[bs * K_ + k] = b * Np + bi;
  }
}

// ================= device bilinear ===========================================================
__device__ __forceinline__ void dev_bilinear(int r, const float* __restrict__ points,
                                             const float* __restrict__ fmT,
                                             ushort* __restrict__ X0) {
  float p0 = points[r * 2 + 0], p1 = points[r * 2 + 1];
  float g0 = __fsub_rn(__fmul_rn(2.0f, p1), 1.0f);
  float g1 = __fsub_rn(__fmul_rn(2.0f, p0), 1.0f);
  float x = __fmul_rn(__fmul_rn(__fadd_rn(g0, 1.0f), 0.5f), 31.0f);
  float y = __fmul_rn(__fmul_rn(__fadd_rn(g1, 1.0f), 0.5f), 31.0f);
  float x0f = floorf(x), y0f = floorf(y);
  float wx = __fsub_rn(x, x0f), wy = __fsub_rn(y, y0f);
  int x0i = (int)fminf(fmaxf(x0f, 0.f), 31.f);
  int x1i = (int)fminf(fmaxf(__fadd_rn(x0f, 1.f), 0.f), 31.f);
  int y0i = (int)fminf(fmaxf(y0f, 0.f), 31.f);
  int y1i = (int)fminf(fmaxf(__fadd_rn(y0f, 1.f), 0.f), 31.f);
  float omwx = __fsub_rn(1.f, wx), omwy = __fsub_rn(1.f, wy);
  size_t i00 = (size_t)(y0i * 32 + x0i) * 1024;
  size_t i01 = (size_t)(y0i * 32 + x1i) * 1024;
  size_t i10 = (size_t)(y1i * 32 + x0i) * 1024;
  size_t i11 = (size_t)(y1i * 32 + x1i) * 1024;
  int t = threadIdx.x;
  int c0 = t * 4;
  ushort* xr = X0 + (size_t)r * LDP_;
  float4 f00 = *(const float4*)(fmT + i00 + c0);
  float4 f01 = *(const float4*)(fmT + i01 + c0);
  float4 f10 = *(const float4*)(fmT + i10 + c0);
  float4 f11 = *(const float4*)(fmT + i11 + c0);
  float a[4] = {f00.x, f00.y, f00.z, f00.w};
  float b[4] = {f01.x, f01.y, f01.z, f01.w};
  float c[4] = {f10.x, f10.y, f10.z, f10.w};
  float d[4] = {f11.x, f11.y, f11.z, f11.w};
  ushort o[4];
#pragma unroll
  for (int i = 0; i < 4; i++) {
    float t1 = a[i] * omwx * omwy;
    float t2 = b[i] * wx * omwy;
    float t3 = c[i] * omwx * wy;
    float t4 = d[i] * wx * wy;
    o[i] = f2bf(((t1 + t2) + t3) + t4);
  }
  uint2 uv = {(unsigned)o[0] | ((unsigned)o[1] << 16), (unsigned)o[2] | ((unsigned)o[3] << 16)};
  *(uint2*)(xr + c0) = uv;
  if (t == 0) { xr[1024] = f2bf(p0); xr[1025] = f2bf(p1); }
  if (t < 126) xr[1026 + t] = 0;
}

// ================= merged weight prep: cvts + transposes + dvec + feat_map transpose =========
static const int PREP_CVT = 2304;  // per aw job: 1024*1152/2/256
static const int PREP_DMW = 7168;  // 3584*1024/2/256
static const int PREP_TT = 1296;   // 36x36 tiles
static const int PREP_FMT = 1024;  // 32x32 tiles of feat_map
static const int PREP_TOTAL = 4 * PREP_CVT + PREP_DMW + 2 * PREP_TT + 512 + PREP_FMT;

__global__ __launch_bounds__(256) void k_prep(
    const float* __restrict__ aw0, const float* __restrict__ aw1, const float* __restrict__ dmw,
    const float* __restrict__ dw0, const float* __restrict__ dw1, const float* __restrict__ db0,
    const float* __restrict__ ab0, const float* __restrict__ db1, const float* __restrict__ ab1,
    const float* __restrict__ feat_map, ushort* __restrict__ awdb0, ushort* __restrict__ awab0,
    ushort* __restrict__ awdb1, ushort* __restrict__ awab1, ushort* __restrict__ dmwb,
    ushort* __restrict__ dwT0, ushort* __restrict__ dwT1, float* __restrict__ dvp0,
    float* __restrict__ dvp1, float* __restrict__ fmT) {
  __shared__ float tile[32][33];
  int bid = blockIdx.x;
  if (bid < 4 * PREP_CVT) {
    int job = bid / PREP_CVT, lb = bid % PREP_CVT;
    const float* src = (job < 2) ? aw0 : aw1;
    int soff = (job & 1) ? C2_ : 0;
    ushort* dst = (job == 0) ? awdb0 : (job == 1) ? awab0 : (job == 2) ? awdb1 : awab1;
    unsigned e = (lb * 256u + threadIdx.x) * 2u;
    unsigned r = e / (unsigned)LDP_, c = e % (unsigned)LDP_;
    float v0 = 0.f, v1 = 0.f;
    const float* sp = src + (size_t)r * CC2_ + soff + c;
    if ((int)c < C2_) v0 = sp[0];
    if ((int)(c + 1) < C2_) v1 = sp[1];
    *(unsigned*)(dst + e) = (unsigned)f2bf(v0) | ((unsigned)f2bf(v1) << 16);
    return;
  }
  bid -= 4 * PREP_CVT;
  if (bid < PREP_DMW) {
    unsigned e = (bid * 256u + threadIdx.x) * 2u;
    float2 v = *(const float2*)(dmw + e);
    *(unsigned*)(dmwb + e) = (unsigned)f2bf(v.x) | ((unsigned)f2bf(v.y) << 16);
    return;
  }
  bid -= PREP_DMW;
  if (bid < 2 * PREP_TT) {
    int which = bid / PREP_TT, id = bid % PREP_TT;
    const float* src = which ? dw1 : dw0;
    ushort* dst = which ? dwT1 : dwT0;
    int bx = (id % 36) * 32, by = (id / 36) * 32;
    int tx = threadIdx.x & 31, ty4 = (threadIdx.x >> 5) * 4;
#pragma unroll
    for (int i = 0; i < 4; i++) {
      int r = by + ty4 + i, c = bx + tx;
      tile[ty4 + i][tx] = (r < C2_ && c < C2_) ? src[(size_t)r * C2_ + c] : 0.f;
    }
    __syncthreads();
#pragma unroll
    for (int i = 0; i < 4; i++)
      dst[(size_t)(bx + ty4 + i) * LDP_ + by + tx] = f2bf(tile[tx][ty4 + i]);
    return;
  }
  bid -= 2 * PREP_TT;
  if (bid < 512) {
    // dvec': dvp[c] = ab[c] + sum_d db[d]*aw[c,d]
    int which = bid >> 8;
    int cb = bid & 255;
    const float* aw = which ? aw1 : aw0;
    const float* db = which ? db1 : db0;
    const float* ab = which ? ab1 : ab0;
    float* dvp = which ? dvp1 : dvp0;
    int w = threadIdx.x >> 6, lane = threadIdx.x & 63;
    int c = cb * 4 + w;
    const float* wr = aw + (size_t)c * CC2_;
    float s = 0.f;
    for (int d = lane; d < C2_; d += 64) s += db[d] * wr[d];
#pragma unroll
    for (int off = 32; off; off >>= 1) s += __shfl_xor(s, off);
    if (lane == 0) dvp[c] = ab[c] + s;
    return;
  }
  bid -= 512;
  // feat_map transpose (C,H,W) -> (H*W, C)
  {
    int yx0 = (bid & 31) * 32, c0 = (bid >> 5) * 32;
    int tx = threadIdx.x & 31, ty = threadIdx.x >> 5;
#pragma unroll
    for (int i = 0; i < 4; i++)
      tile[ty + 8 * i][tx] = feat_map[(size_t)(c0 + ty + 8 * i) * 1024 + yx0 + tx];
    __syncthreads();
#pragma unroll
    for (int i = 0; i < 4; i++)
      fmT[(size_t)(yx0 + ty + 8 * i) * 1024 + c0 + tx] = tile[tx][ty + 8 * i];
  }
}

// ================= merged: Wc combine GEMMs + bilinear ======================================
__global__ __launch_bounds__(256) void k_wc_bil(
    const ushort* __restrict__ awdb0, const ushort* __restrict__ dwT0, ushort* __restrict__ Wcb0,
    const ushort* __restrict__ awdb1, const ushort* __restrict__ dwT1, ushort* __restrict__ Wcb1,
    const float* __restrict__ points, const float* __restrict__ fmT, ushort* __restrict__ Xb0) {
  __shared__ ushort As[4096];
  __shared__ ushort Bs[4096];
  int bid = blockIdx.x;
  if (bid < 72) {
    dev_mgemm<1>(bid % 9, bid / 9, 0, 1, As, Bs, C_, C2_, LDP_, awdb0, LDP_, nullptr, dwT0, LDP_,
                 nullptr, Wcb0, LDP_, LDP_);
  } else if (bid < 144) {
    int b2 = bid - 72;
    dev_mgemm<1>(b2 % 9, b2 / 9, 0, 1, As, Bs, C_, C2_, LDP_, awdb1, LDP_, nullptr, dwT1, LDP_,
                 nullptr, Wcb1, LDP_, LDP_);
  } else {
    dev_bilinear(bid - 144, points, fmT, Xb0);
  }
}

// ================= merged: G-GEMM + FPS =====================================================
template <int NPL>
__global__ __launch_bounds__(256) void k_gemm_fps(int Mg, const ushort* __restrict__ A, int lda,
                                                  const ushort* __restrict__ Wt,
                                                  ushort* __restrict__ Gout, int ngemm, int Np,
                                                  int nsub, const float* __restrict__ pts,
                                                  int stride, int* __restrict__ rows) {
  __shared__ ushort As[4096];
  __shared__ ushort Bs[4096];
  int bid = blockIdx.x;
  if (bid < ngemm) {
    dev_mgemm<1>(bid & 7, bid >> 3, 0, 1, As, Bs, Mg, C_, LDP_, A, lda, nullptr, Wt, LDP_, nullptr,
                 Gout, C_, LDP_);
  } else if (threadIdx.x < 64) {
    dev_fps<NPL>(bid - ngemm, Np, nsub, pts, stride, rows);
  }
}

// ================= merged: P-GEMM + kNN (4 queries/block, one per wave) =====================
template <int NPL>
__global__ __launch_bounds__(256) void k_gemm_knn(int Mp, const ushort* __restrict__ A, int lda,
                                                  const int* __restrict__ rowsA,
                                                  const ushort* __restrict__ Wt,
                                                  const float* __restrict__ bias,
                                                  ushort* __restrict__ Pout, int ngemm, int S,
                                                  int Np, const float* __restrict__ pts,
                                                  int stride, const int* __restrict__ rows,
                                                  int* __restrict__ nn) {
  __shared__ ushort As[4096];
  __shared__ ushort Bs[4096];
  int bid = blockIdx.x;
  if (bid < ngemm) {
    dev_mgemm<2>(bid & 7, bid >> 3, 0, 1, As, Bs, Mp, C_, LDP_, A, lda, rowsA, Wt, LDP_, bias,
                 Pout, C_, LDP_);
  } else {
    int w = threadIdx.x >> 6;
    int qid = (bid - ngemm) * 4 + w;
    dev_knn<NPL>(qid, S, Np, pts, stride, rows, nn);
  }
}

// ================= flat head GEMM with fused f32->bf16 W conversion =========================
__global__ __launch_bounds__(256) void k_flat(const ushort* __restrict__ A,  // [32][65536] bf16
                                              const float* __restrict__ W,   // [1024][65536] f32
                                              float* __restrict__ Cp) {      // [32][32][1024]
  int t = threadIdx.x;
  int w = t >> 6, l = t & 63;
  int fr = l & 15, fg = l >> 4;
  int col0 = blockIdx.x * 128 + w * 32;
  size_t k0 = (size_t)blockIdx.z * 2048;
  f32x4 acc[2][2];
#pragma unroll
  for (int i = 0; i < 2; i++)
#pragma unroll
    for (int j = 0; j < 2; j++) acc[i][j] = (f32x4){0.f, 0.f, 0.f, 0.f};
  const ushort* a0 = A + (size_t)fr * 65536 + k0 + fg * 8;
  const ushort* a1 = A + (size_t)(16 + fr) * 65536 + k0 + fg * 8;
  const float* b0 = W + (size_t)(col0 + fr) * 65536 + k0 + fg * 8;
  const float* b1 = W + (size_t)(col0 + 16 + fr) * 65536 + k0 + fg * 8;
  for (int kt = 0; kt < 2048; kt += 32) {
    short8 af0 = *(const short8*)(a0 + kt);
    short8 af1 = *(const short8*)(a1 + kt);
    float4 p0 = *(const float4*)(b0 + kt);
    float4 p1 = *(const float4*)(b0 + kt + 4);
    float4 q0 = *(const float4*)(b1 + kt);
    float4 q1 = *(const float4*)(b1 + kt + 4);
    short8 bf0, bf1;
    bf0[0] = (short)f2bf(p0.x); bf0[1] = (short)f2bf(p0.y);
    bf0[2] = (short)f2bf(p0.z); bf0[3] = (short)f2bf(p0.w);
    bf0[4] = (short)f2bf(p1.x); bf0[5] = (short)f2bf(p1.y);
    bf0[6] = (short)f2bf(p1.z); bf0[7] = (short)f2bf(p1.w);
    bf1[0] = (short)f2bf(q0.x); bf1[1] = (short)f2bf(q0.y);
    bf1[2] = (short)f2bf(q0.z); bf1[3] = (short)f2bf(q0.w);
    bf1[4] = (short)f2bf(q1.x); bf1[5] = (short)f2bf(q1.y);
    bf1[6] = (short)f2bf(q1.z); bf1[7] = (short)f2bf(q1.w);
    acc[0][0] = __builtin_amdgcn_mfma_f32_16x16x32_bf16(af0, bf0, acc[0][0], 0, 0, 0);
    acc[1][0] = __builtin_amdgcn_mfma_f32_16x16x32_bf16(af1, bf0, acc[1][0], 0, 0, 0);
    acc[0][1] = __builtin_amdgcn_mfma_f32_16x16x32_bf16(af0, bf1, acc[0][1], 0, 0, 0);
    acc[1][1] = __builtin_amdgcn_mfma_f32_16x16x32_bf16(af1, bf1, acc[1][1], 0, 0, 0);
  }
  float* Cz = Cp + (size_t)blockIdx.z * 32 * 1024;
#pragma unroll
  for (int mi = 0; mi < 2; mi++)
#pragma unroll
    for (int ni = 0; ni < 2; ni++)
#pragma unroll
      for (int q = 0; q < 4; q++) {
        int r = mi * 16 + fg * 4 + q;
        int c = col0 + ni * 16 + fr;
        Cz[(size_t)r * 1024 + c] = acc[mi][ni][q];
      }
}

// ================= fused stage: wave-per-k, barrier-free k-loop =============================
__global__ __launch_bounds__(256) void k_fused_stage(
    const ushort* __restrict__ G, const ushort* __restrict__ Pb, const int* __restrict__ rows,
    const int* __restrict__ nn, const float* __restrict__ lng, const float* __restrict__ lnb,
    const float* __restrict__ prev_pts, int pts_stride, ushort* __restrict__ Xout, int ld_out,
    float* __restrict__ coords_out) {
  __shared__ float sm[4][1024];
  int bs = blockIdx.x;
  int t = threadIdx.x;
  int w = t >> 6, lane = t & 63;
  int c0 = lane * 16;
  int arow = rows[bs];
  float base[16], lg[16], lb[16], acc[16];
  {
    short8 pA = *(const short8*)(Pb + (size_t)bs * C_ + c0);
    short8 pB = *(const short8*)(Pb + (size_t)bs * C_ + c0 + 8);
    short8 gA = *(const short8*)(G + (size_t)arow * C_ + c0);
    short8 gB = *(const short8*)(G + (size_t)arow * C_ + c0 + 8);
#pragma unroll
    for (int i = 0; i < 8; i++) {
      base[i] = bf2f((ushort)pA[i]) - bf2f((ushort)gA[i]);
      base[8 + i] = bf2f((ushort)pB[i]) - bf2f((ushort)gB[i]);
    }
#pragma unroll
    for (int i = 0; i < 4; i++) {
      float4 gv = *(const float4*)(lng + c0 + 4 * i);
      float4 bv = *(const float4*)(lnb + c0 + 4 * i);
      lg[4 * i] = gv.x; lg[4 * i + 1] = gv.y; lg[4 * i + 2] = gv.z; lg[4 * i + 3] = gv.w;
      lb[4 * i] = bv.x; lb[4 * i + 1] = bv.y; lb[4 * i + 2] = bv.z; lb[4 * i + 3] = bv.w;
      acc[4 * i] = -INFINITY; acc[4 * i + 1] = -INFINITY;
      acc[4 * i + 2] = -INFINITY; acc[4 * i + 3] = -INFINITY;
    }
  }
#pragma unroll
  for (int kk = 0; kk < 4; kk++) {
    int g = nn[bs * K_ + w * 4 + kk];
    const ushort* Gr = G + (size_t)g * C_ + c0;
    short8 xA = *(const short8*)(Gr);
    short8 xB = *(const short8*)(Gr + 8);
    float v[16];
    float s1 = 0.f, s2 = 0.f;
#pragma unroll
    for (int i = 0; i < 8; i++) {
      float x = fmaxf(bf2f((ushort)xA[i]) + base[i], 0.f);
      v[i] = x; s1 += x; s2 += x * x;
      float y = fmaxf(bf2f((ushort)xB[i]) + base[8 + i], 0.f);
      v[8 + i] = y; s1 += y; s2 += y * y;
    }
#pragma unroll
    for (int off = 32; off; off >>= 1) {
      s1 += __shfl_xor(s1, off);
      s2 += __shfl_xor(s2, off);
    }
    float mu = s1 * (1.f / 1024.f);
    float var = s2 * (1.f / 1024.f) - mu * mu;
    float rstd = 1.f / sqrtf(var + 1e-5f);
#pragma unroll
    for (int i = 0; i < 16; i++) {
      float nv = (v[i] - mu) * rstd * lg[i] + lb[i];
      acc[i] = fmaxf(acc[i], nv);
    }
  }
#pragma unroll
  for (int i = 0; i < 16; i += 4) {
    f32x4 av = {acc[i], acc[i + 1], acc[i + 2], acc[i + 3]};
    *(f32x4*)&sm[w][c0 + i] = av;
  }
  __syncthreads();
  {
    int cc = t * 4;
    f32x4 m0 = *(const f32x4*)&sm[0][cc];
    f32x4 m1 = *(const f32x4*)&sm[1][cc];
    f32x4 m2 = *(const f32x4*)&sm[2][cc];
    f32x4 m3 = *(const f32x4*)&sm[3][cc];
    ushort o[4];
#pragma unroll
    for (int j = 0; j < 4; j++)
      o[j] = f2bf(fmaxf(fmaxf(m0[j], m1[j]), fmaxf(m2[j], m3[j])));
    uint2 uv = {(unsigned)o[0] | ((unsigned)o[1] << 16), (unsigned)o[2] | ((unsigned)o[3] << 16)};
    *(uint2*)(Xout + (size_t)bs * ld_out + cc) = uv;
  }
  if (prev_pts) {
    float p0 = prev_pts[(size_t)arow * pts_stride + 0];
    float p1 = prev_pts[(size_t)arow * pts_stride + 1];
    if (t == 0) {
      Xout[(size_t)bs * ld_out + 1024] = f2bf(p0);
      Xout[(size_t)bs * ld_out + 1025] = f2bf(p1);
      coords_out[bs * 2 + 0] = p0;
      coords_out[bs * 2 + 1] = p1;
    }
    if (t < 126) Xout[(size_t)bs * ld_out + 1026 + t] = 0;
  }
}

// ================= reduce K-split partials + bias; OUTBF: write bf16 ========================
template <int OUTBF>
__global__ __launch_bounds__(256) void k_reduce(int total, int Ncols, int nz,
                                                const float* __restrict__ part,
                                                const float* __restrict__ bias,
                                                void* __restrict__ out) {
  int i = blockIdx.x * 256 + threadIdx.x;
  if (i >= total) return;
  float s = bias[i % Ncols];
  for (int z = 0; z < nz; z++) s += part[(size_t)z * total + i];
  if (OUTBF)
    ((ushort*)out)[i] = f2bf(s);
  else
    ((float*)out)[i] = s;
}

// ================= launch ====================================================================
extern "C" void kernel_launch(void* const* d_in, const int* in_sizes, int n_in, void* d_out,
                              int out_size, void* d_ws, size_t ws_size, hipStream_t stream) {
  (void)in_sizes; (void)n_in; (void)out_size; (void)ws_size;
  const float* points = (const float*)d_in[0];
  const float* feat_map = (const float*)d_in[1];
  const float* dw0 = (const float*)d_in[2];
  const float* db0 = (const float*)d_in[3];
  const float* aw0 = (const float*)d_in[4];
  const float* ab0 = (const float*)d_in[5];
  const float* lg0 = (const float*)d_in[6];
  const float* lb0 = (const float*)d_in[7];
  const float* dw1 = (const float*)d_in[8];
  const float* db1 = (const float*)d_in[9];
  const float* aw1 = (const float*)d_in[10];
  const float* ab1 = (const float*)d_in[11];
  const float* lg1 = (const float*)d_in[12];
  const float* lb1 = (const float*)d_in[13];
  const float* fw = (const float*)d_in[14];
  const float* fb = (const float*)d_in[15];
  const float* dmw = (const float*)d_in[16];
  const float* dmb = (const float*)d_in[17];
  float* out = (float*)d_out;

  char* wsb = (char*)d_ws;
  size_t off = 0;
  auto alloc = [&](size_t bytes) -> void* {
    void* p = wsb + off;
    off = (off + bytes + 255) & ~(size_t)255;
    return p;
  };
  float* fmT = (float*)alloc((size_t)1024 * 1024 * 4);
  ushort* Xb0 = (ushort*)alloc((size_t)B_ * N_ * LDP_ * 2);
  ushort* Gb = (ushort*)alloc((size_t)B_ * N_ * C_ * 2);
  ushort* Pb = (ushort*)alloc((size_t)B_ * S0_ * C_ * 2);
  ushort* Xb1 = (ushort*)alloc((size_t)B_ * S0_ * LDP_ * 2);
  ushort* fts2b = (ushort*)alloc((size_t)B_ * S1_ * C_ * 2);
  float* coords1 = (float*)alloc((size_t)B_ * S0_ * 2 * 4);
  ushort* awdb0 = (ushort*)alloc((size_t)C_ * LDP_ * 2);
  ushort* awab0 = (ushort*)alloc((size_t)C_ * LDP_ * 2);
  ushort* awdb1 = (ushort*)alloc((size_t)C_ * LDP_ * 2);
  ushort* awab1 = (ushort*)alloc((size_t)C_ * LDP_ * 2);
  ushort* dwT0 = (ushort*)alloc((size_t)LDP_ * LDP_ * 2);
  ushort* dwT1 = (ushort*)alloc((size_t)LDP_ * LDP_ * 2);
  ushort* Wcb0 = (ushort*)alloc((size_t)C_ * LDP_ * 2);
  ushort* Wcb1 = (ushort*)alloc((size_t)C_ * LDP_ * 2);
  ushort* dmwb = (ushort*)alloc((size_t)OUT_ * C_ * 2);
  float* dvp0 = (float*)alloc(1024 * 4);
  float* dvp1 = (float*)alloc(1024 * 4);
  int* rows0 = (int*)alloc(B_ * S0_ * 4);
  int* nn0 = (int*)alloc(B_ * S0_ * K_ * 4);
  int* rows1 = (int*)alloc(B_ * S1_ * 4);
  int* nn1 = (int*)alloc(B_ * S1_ * K_ * 4);
  float* hpart = (float*)alloc((size_t)32 * B_ * C_ * 4);
  ushort* hidb = (ushort*)alloc((size_t)B_ * C_ * 2);
  float* opart = (float*)alloc((size_t)4 * B_ * OUT_ * 4);

  // 1) weight prep + feat_map transpose
  k_prep<<<PREP_TOTAL, 256, 0, stream>>>(aw0, aw1, dmw, dw0, dw1, db0, ab0, db1, ab1, feat_map,
                                         awdb0, awab0, awdb1, awab1, dmwb, dwT0, dwT1, dvp0, dvp1,
                                         fmT);
  // 2) Wc combine GEMMs + bilinear sample
  k_wc_bil<<<144 + B_ * N_, 256, 0, stream>>>(awdb0, dwT0, Wcb0, awdb1, dwT1, Wcb1, points, fmT,
                                              Xb0);
  // 3) stage 0: G0 GEMM || FPS0
  k_gemm_fps<8><<<1024 + B_, 256, 0, stream>>>(B_ * N_, Xb0, LDP_, Wcb0, Gb, 1024, N_, S0_,
                                               points, 2, rows0);
  // 4) stage 0: P0 GEMM || kNN0
  k_gemm_knn<8><<<512 + (B_ * S0_) / 4, 256, 0, stream>>>(B_ * S0_, Xb0, LDP_, rows0, awab0, dvp0,
                                                          Pb, 512, S0_, N_, points, 2, rows0, nn0);
  // 5) fused stage 0
  k_fused_stage<<<B_ * S0_, 256, 0, stream>>>(Gb, Pb, rows0, nn0, lg0, lb0, points, 2, Xb1, LDP_,
                                              coords1);
  // 6) stage 1: G1 GEMM || FPS1
  k_gemm_fps<4><<<512 + B_, 256, 0, stream>>>(B_ * S0_, Xb1, LDP_, Wcb1, Gb, 512, S0_, S1_,
                                              coords1, 2, rows1);
  // 7) stage 1: P1 GEMM || kNN1
  k_gemm_knn<4><<<128 + (B_ * S1_) / 4, 256, 0, stream>>>(B_ * S1_, Xb1, LDP_, rows1, awab1, dvp1,
                                                          Pb, 128, S1_, S0_, coords1, 2, rows1,
                                                          nn1);
  // 8) fused stage 1
  k_fused_stage<<<B_ * S1_, 256, 0, stream>>>(Gb, Pb, rows1, nn1, lg1, lb1, nullptr, 0, fts2b, C_,
                                              nullptr);
  // 9) flat head (fused f32 W conversion), K-split 32 x 2048
  {
    dim3 g(8, 1, 32);
    k_flat<<<g, 256, 0, stream>>>(fts2b, fw, hpart);
  }
  // 10) reduce -> hid (bf16)
  k_reduce<1><<<(B_ * C_ + 255) / 256, 256, 0, stream>>>(B_ * C_, C_, 32, hpart, fb, hidb);
  // 11) dim head: M=32, K=1024, z-split 4 x 256
  {
    dim3 g(OUT_ / 128, 1, 4);
    k_mgemm<0><<<g, 256, 0, stream>>>(B_, OUT_, C_, hidb, C_, nullptr, dmwb, C_, nullptr, opart,
                                      OUT_, 256);
  }
  // 12) reduce -> out
  k_reduce<0><<<(B_ * OUT_ + 255) / 256, 256, 0, stream>>>(B_ * OUT_, OUT_, 4, opart, dmb, out);
}

// Round 7
// 531.050 us; speedup vs baseline: 6.6796x; 1.0381x over previous
//
#include <hip/hip_runtime.h>
#include <cstdint>
#include <cstddef>

// ---------------- constants ----------------
static const int B_ = 32, N_ = 512, C_ = 1024, C2_ = 1026, CC2_ = 2052;
static const int S0_ = 256, S1_ = 64, K_ = 16, OUT_ = 3584;
static const int LDP_ = 1152;  // padded C2 (multiple of 128 and 32)

typedef unsigned short ushort;
typedef __attribute__((ext_vector_type(8))) short short8;
typedef __attribute__((ext_vector_type(4))) float f32x4;

__device__ __forceinline__ ushort f2bf(float x) {
  unsigned u = __float_as_uint(x);
  unsigned r = (u + 0x7fffu + ((u >> 16) & 1u)) >> 16;
  return (ushort)r;
}
__device__ __forceinline__ float bf2f(ushort b) {
  return __uint_as_float(((unsigned)b) << 16);
}

__device__ __forceinline__ void gload16(const void* g, void* l) {
  __builtin_amdgcn_global_load_lds((const __attribute__((address_space(1))) void*)g,
                                   (__attribute__((address_space(3))) void*)l, 16, 0, 0);
}

// ================= device GEMM (128x128 tile, 4 waves, 16x16x32 MFMA, BK=32) =================
// OMODE 0: f32 out (+bias if gridz==1, z-slabs otherwise)
// OMODE 1: bf16 out, zero for c>=Neff
// OMODE 2: bf16 out + f32 bias
template <int OMODE>
__device__ __forceinline__ void dev_mgemm(int bx, int by, int bz, int gridz, ushort* As,
                                          ushort* Bs, int M, int Neff, int K,
                                          const ushort* __restrict__ A, int lda,
                                          const int* __restrict__ rowidx,
                                          const ushort* __restrict__ Wt, int ldw,
                                          const float* __restrict__ bias, void* __restrict__ Cout,
                                          int ldc, int kchunk) {
  int t = threadIdx.x;
  int w = t >> 6, l = t & 63;
  int row0 = by * 128, col0 = bx * 128;
  int k0 = bz * kchunk;
  int k1 = min(K, k0 + kchunk);
  f32x4 acc[4][4];
#pragma unroll
  for (int i = 0; i < 4; i++)
#pragma unroll
    for (int j = 0; j < 4; j++) acc[i][j] = (f32x4){0.f, 0.f, 0.f, 0.f};

  int srow = l >> 2;
  int scol = (l & 3) * 8;
  int ar0 = min(row0 + w * 16 + srow, M - 1);
  int ar1 = min(row0 + 64 + w * 16 + srow, M - 1);
  if (rowidx) { ar0 = rowidx[ar0]; ar1 = rowidx[ar1]; }
  const ushort* gA0 = A + (size_t)ar0 * lda + scol;
  const ushort* gA1 = A + (size_t)ar1 * lda + scol;
  const ushort* gB0 = Wt + (size_t)(col0 + w * 16 + srow) * ldw + scol;
  const ushort* gB1 = Wt + (size_t)(col0 + 64 + w * 16 + srow) * ldw + scol;
  ushort* lA0 = As + w * 512;
  ushort* lA1 = As + 2048 + w * 512;
  ushort* lB0 = Bs + w * 512;
  ushort* lB1 = Bs + 2048 + w * 512;

  int wm = w >> 1, wn = w & 1;
  int fr = l & 15, fg = l >> 4;

  for (int kt = k0; kt < k1; kt += 32) {
    __syncthreads();
    gload16(gA0 + kt, lA0);
    gload16(gA1 + kt, lA1);
    gload16(gB0 + kt, lB0);
    gload16(gB1 + kt, lB1);
    __syncthreads();
    short8 af[4], bf[4];
#pragma unroll
    for (int mi = 0; mi < 4; mi++)
      af[mi] = *(const short8*)&As[(wm * 64 + mi * 16 + fr) * 32 + fg * 8];
#pragma unroll
    for (int ni = 0; ni < 4; ni++)
      bf[ni] = *(const short8*)&Bs[(wn * 64 + ni * 16 + fr) * 32 + fg * 8];
#pragma unroll
    for (int mi = 0; mi < 4; mi++)
#pragma unroll
      for (int ni = 0; ni < 4; ni++)
        acc[mi][ni] = __builtin_amdgcn_mfma_f32_16x16x32_bf16(af[mi], bf[ni], acc[mi][ni], 0, 0, 0);
  }

  if (OMODE == 0) {
    float* C = (float*)Cout + (size_t)bz * M * ldc;
    bool addb = (bias != nullptr) && (gridz == 1);
#pragma unroll
    for (int mi = 0; mi < 4; mi++)
#pragma unroll
      for (int ni = 0; ni < 4; ni++)
#pragma unroll
        for (int q = 0; q < 4; q++) {
          int r = row0 + wm * 64 + mi * 16 + fg * 4 + q;
          int c = col0 + wn * 64 + ni * 16 + fr;
          if (r < M) {
            float v = acc[mi][ni][q];
            if (addb) v += bias[c];
            C[(size_t)r * ldc + c] = v;
          }
        }
  } else if (OMODE == 1) {
    ushort* C = (ushort*)Cout;
#pragma unroll
    for (int mi = 0; mi < 4; mi++)
#pragma unroll
      for (int ni = 0; ni < 4; ni++)
#pragma unroll
        for (int q = 0; q < 4; q++) {
          int r = row0 + wm * 64 + mi * 16 + fg * 4 + q;
          int c = col0 + wn * 64 + ni * 16 + fr;
          if (r < M) C[(size_t)r * ldc + c] = f2bf(c < Neff ? acc[mi][ni][q] : 0.f);
        }
  } else {
    ushort* C = (ushort*)Cout;
#pragma unroll
    for (int mi = 0; mi < 4; mi++)
#pragma unroll
      for (int ni = 0; ni < 4; ni++)
#pragma unroll
        for (int q = 0; q < 4; q++) {
          int r = row0 + wm * 64 + mi * 16 + fg * 4 + q;
          int c = col0 + wn * 64 + ni * 16 + fr;
          if (r < M) C[(size_t)r * ldc + c] = f2bf(acc[mi][ni][q] + bias[c]);
        }
  }
}

// plain wrapper (x = col, y = row): used for z-split dim head
template <int OMODE>
__global__ __launch_bounds__(256) void k_mgemm(int M, int Neff, int K,
                                               const ushort* __restrict__ A, int lda,
                                               const int* __restrict__ rowidx,
                                               const ushort* __restrict__ Wt, int ldw,
                                               const float* __restrict__ bias,
                                               void* __restrict__ Cout, int ldc, int kchunk) {
  __shared__ ushort As[4096];
  __shared__ ushort Bs[4096];
  dev_mgemm<OMODE>(blockIdx.x, blockIdx.y, blockIdx.z, gridDim.z, As, Bs, M, Neff, K, A, lda,
                   rowidx, Wt, ldw, bias, Cout, ldc, kchunk);
}

// XCD-friendly wrapper (x = ROW, y = col): consecutive blocks share the B col-panel and
// row-panel r's col-blocks all land on XCD r%8 (grid.x % 8 == 0) -> A fetched once per panel.
template <int OMODE>
__global__ __launch_bounds__(256) void k_mgemm2(int M, int Neff, int K,
                                                const ushort* __restrict__ A, int lda,
                                                const int* __restrict__ rowidx,
                                                const ushort* __restrict__ Wt, int ldw,
                                                const float* __restrict__ bias,
                                                void* __restrict__ Cout, int ldc, int kchunk) {
  __shared__ ushort As[4096];
  __shared__ ushort Bs[4096];
  dev_mgemm<OMODE>(blockIdx.y, blockIdx.x, blockIdx.z, gridDim.z, As, Bs, M, Neff, K, A, lda,
                   rowidx, Wt, ldw, bias, Cout, ldc, kchunk);
}

// ================= device FPS (wave 0 only), packed u64 argmax, register-resident ============
// latency-critical serial chain: runs at wave priority 3 so co-resident GEMM waves don't starve it
template <int NPL>
__device__ __forceinline__ void dev_fps(int b, int Np, int nsub, const float* __restrict__ pts,
                                        int stride, int* __restrict__ rows) {
  __builtin_amdgcn_s_setprio(3);
  int lane = threadIdx.x;  // caller guarantees < 64
  const float* pb = pts + (size_t)b * Np * stride;
  float px[NPL], py[NPL], dist[NPL];
#pragma unroll
  for (int i = 0; i < NPL; i++) {
    int j = lane + 64 * i;
    px[i] = pb[(size_t)j * stride + 0];
    py[i] = pb[(size_t)j * stride + 1];
    dist[i] = 1e10f;
  }
  int far = 0;
  float fx = pb[0], fy = pb[1];
  for (int s = 0; s < nsub; s++) {
    if (lane == 0) rows[b * nsub + s] = b * Np + far;
    unsigned long long best = 0ull;
#pragma unroll
    for (int i = 0; i < NPL; i++) {
      float dx = __fsub_rn(px[i], fx), dy = __fsub_rn(py[i], fy);
      float d = __fadd_rn(__fmul_rn(dx, dx), __fmul_rn(dy, dy));
      dist[i] = fminf(dist[i], d);
      unsigned long long pk =
          ((unsigned long long)__float_as_uint(dist[i]) << 32) | (unsigned)(~(lane + 64 * i));
      best = pk > best ? pk : best;
    }
#pragma unroll
    for (int off = 32; off; off >>= 1) {
      unsigned long long o = __shfl_xor(best, off);
      best = o > best ? o : best;
    }
    int j = (int)(~(unsigned)best);
    far = j;
    int chunk = j >> 6, owner = j & 63;
    float cx = px[0], cy = py[0];
#pragma unroll
    for (int i = 1; i < NPL; i++) {
      bool cnd = (chunk == i);
      cx = cnd ? px[i] : cx;
      cy = cnd ? py[i] : cy;
    }
    fx = __shfl(cx, owner);
    fy = __shfl(cy, owner);
  }
  __builtin_amdgcn_s_setprio(0);
}

// ================= device kNN (one wave per query) ==========================================
template <int NPL>
__device__ __forceinline__ void dev_knn(int bs, int S, int Np, const float* __restrict__ pts,
                                        int stride, const int* __restrict__ rows,
                                        int* __restrict__ nn) {
  int b = bs / S;
  int lane = threadIdx.x & 63;
  const float* pb = pts + (size_t)b * Np * stride;
  int arow = rows[bs];
  float ax = pts[(size_t)arow * stride + 0];
  float ay = pts[(size_t)arow * stride + 1];
  float d2[NPL];
#pragma unroll
  for (int i = 0; i < NPL; i++) {
    int j = lane + 64 * i;
    float dx = __fsub_rn(ax, pb[(size_t)j * stride + 0]);
    float dy = __fsub_rn(ay, pb[(size_t)j * stride + 1]);
    d2[i] = __fadd_rn(__fmul_rn(dx, dx), __fmul_rn(dy, dy));
  }
  unsigned mask = 0;
  for (int k = 0; k < K_; k++) {
    float bv = INFINITY;
    int bi = 0x7fffffff;
#pragma unroll
    for (int i = 0; i < NPL; i++) {
      int j = lane + 64 * i;
      bool used = (mask >> i) & 1u;
      if (!used && (d2[i] < bv || (d2[i] == bv && j < bi))) { bv = d2[i]; bi = j; }
    }
#pragma unroll
    for (int off = 32; off; off >>= 1) {
      float ov = __shfl_xor(bv, off);
      int oi = __shfl_xor(bi, off);
      if (ov < bv || (ov == bv && oi < bi)) { bv = ov; bi = oi; }
    }
    if ((bi & 63) == lane) mask |= 1u << (bi >> 6);
    if (lane == 0) nn[bs * K_ + k] = b * Np + bi;
  }
}

// ================= device bilinear ===========================================================
__device__ __forceinline__ void dev_bilinear(int r, const float* __restrict__ points,
                                             const float* __restrict__ fmT,
                                             ushort* __restrict__ X0) {
  float p0 = points[r * 2 + 0], p1 = points[r * 2 + 1];
  float g0 = __fsub_rn(__fmul_rn(2.0f, p1), 1.0f);
  float g1 = __fsub_rn(__fmul_rn(2.0f, p0), 1.0f);
  float x = __fmul_rn(__fmul_rn(__fadd_rn(g0, 1.0f), 0.5f), 31.0f);
  float y = __fmul_rn(__fmul_rn(__fadd_rn(g1, 1.0f), 0.5f), 31.0f);
  float x0f = floorf(x), y0f = floorf(y);
  float wx = __fsub_rn(x, x0f), wy = __fsub_rn(y, y0f);
  int x0i = (int)fminf(fmaxf(x0f, 0.f), 31.f);
  int x1i = (int)fminf(fmaxf(__fadd_rn(x0f, 1.f), 0.f), 31.f);
  int y0i = (int)fminf(fmaxf(y0f, 0.f), 31.f);
  int y1i = (int)fminf(fmaxf(__fadd_rn(y0f, 1.f), 0.f), 31.f);
  float omwx = __fsub_rn(1.f, wx), omwy = __fsub_rn(1.f, wy);
  size_t i00 = (size_t)(y0i * 32 + x0i) * 1024;
  size_t i01 = (size_t)(y0i * 32 + x1i) * 1024;
  size_t i10 = (size_t)(y1i * 32 + x0i) * 1024;
  size_t i11 = (size_t)(y1i * 32 + x1i) * 1024;
  int t = threadIdx.x;
  int c0 = t * 4;
  ushort* xr = X0 + (size_t)r * LDP_;
  float4 f00 = *(const float4*)(fmT + i00 + c0);
  float4 f01 = *(const float4*)(fmT + i01 + c0);
  float4 f10 = *(const float4*)(fmT + i10 + c0);
  float4 f11 = *(const float4*)(fmT + i11 + c0);
  float a[4] = {f00.x, f00.y, f00.z, f00.w};
  float b[4] = {f01.x, f01.y, f01.z, f01.w};
  float c[4] = {f10.x, f10.y, f10.z, f10.w};
  float d[4] = {f11.x, f11.y, f11.z, f11.w};
  ushort o[4];
#pragma unroll
  for (int i = 0; i < 4; i++) {
    float t1 = a[i] * omwx * omwy;
    float t2 = b[i] * wx * omwy;
    float t3 = c[i] * omwx * wy;
    float t4 = d[i] * wx * wy;
    o[i] = f2bf(((t1 + t2) + t3) + t4);
  }
  uint2 uv = {(unsigned)o[0] | ((unsigned)o[1] << 16), (unsigned)o[2] | ((unsigned)o[3] << 16)};
  *(uint2*)(xr + c0) = uv;
  if (t == 0) { xr[1024] = f2bf(p0); xr[1025] = f2bf(p1); }
  if (t < 126) xr[1026 + t] = 0;
}

// ================= merged weight prep: cvts + transposes + dvec + feat_map transpose =========
static const int PREP_CVT = 2304;  // per aw job: 1024*1152/2/256
static const int PREP_DMW = 7168;  // 3584*1024/2/256
static const int PREP_TT = 1296;   // 36x36 tiles
static const int PREP_FMT = 1024;  // 32x32 tiles of feat_map
static const int PREP_TOTAL = 4 * PREP_CVT + PREP_DMW + 2 * PREP_TT + 512 + PREP_FMT;

__global__ __launch_bounds__(256) void k_prep(
    const float* __restrict__ aw0, const float* __restrict__ aw1, const float* __restrict__ dmw,
    const float* __restrict__ dw0, const float* __restrict__ dw1, const float* __restrict__ db0,
    const float* __restrict__ ab0, const float* __restrict__ db1, const float* __restrict__ ab1,
    const float* __restrict__ feat_map, ushort* __restrict__ awdb0, ushort* __restrict__ awab0,
    ushort* __restrict__ awdb1, ushort* __restrict__ awab1, ushort* __restrict__ dmwb,
    ushort* __restrict__ dwT0, ushort* __restrict__ dwT1, float* __restrict__ dvp0,
    float* __restrict__ dvp1, float* __restrict__ fmT) {
  __shared__ float tile[32][33];
  int bid = blockIdx.x;
  if (bid < 4 * PREP_CVT) {
    int job = bid / PREP_CVT, lb = bid % PREP_CVT;
    const float* src = (job < 2) ? aw0 : aw1;
    int soff = (job & 1) ? C2_ : 0;
    ushort* dst = (job == 0) ? awdb0 : (job == 1) ? awab0 : (job == 2) ? awdb1 : awab1;
    unsigned e = (lb * 256u + threadIdx.x) * 2u;
    unsigned r = e / (unsigned)LDP_, c = e % (unsigned)LDP_;
    float v0 = 0.f, v1 = 0.f;
    const float* sp = src + (size_t)r * CC2_ + soff + c;
    if ((int)c < C2_) v0 = sp[0];
    if ((int)(c + 1) < C2_) v1 = sp[1];
    *(unsigned*)(dst + e) = (unsigned)f2bf(v0) | ((unsigned)f2bf(v1) << 16);
    return;
  }
  bid -= 4 * PREP_CVT;
  if (bid < PREP_DMW) {
    unsigned e = (bid * 256u + threadIdx.x) * 2u;
    float2 v = *(const float2*)(dmw + e);
    *(unsigned*)(dmwb + e) = (unsigned)f2bf(v.x) | ((unsigned)f2bf(v.y) << 16);
    return;
  }
  bid -= PREP_DMW;
  if (bid < 2 * PREP_TT) {
    int which = bid / PREP_TT, id = bid % PREP_TT;
    const float* src = which ? dw1 : dw0;
    ushort* dst = which ? dwT1 : dwT0;
    int bx = (id % 36) * 32, by = (id / 36) * 32;
    int tx = threadIdx.x & 31, ty4 = (threadIdx.x >> 5) * 4;
#pragma unroll
    for (int i = 0; i < 4; i++) {
      int r = by + ty4 + i, c = bx + tx;
      tile[ty4 + i][tx] = (r < C2_ && c < C2_) ? src[(size_t)r * C2_ + c] : 0.f;
    }
    __syncthreads();
#pragma unroll
    for (int i = 0; i < 4; i++)
      dst[(size_t)(bx + ty4 + i) * LDP_ + by + tx] = f2bf(tile[tx][ty4 + i]);
    return;
  }
  bid -= 2 * PREP_TT;
  if (bid < 512) {
    // dvec': dvp[c] = ab[c] + sum_d db[d]*aw[c,d]
    int which = bid >> 8;
    int cb = bid & 255;
    const float* aw = which ? aw1 : aw0;
    const float* db = which ? db1 : db0;
    const float* ab = which ? ab1 : ab0;
    float* dvp = which ? dvp1 : dvp0;
    int w = threadIdx.x >> 6, lane = threadIdx.x & 63;
    int c = cb * 4 + w;
    const float* wr = aw + (size_t)c * CC2_;
    float s = 0.f;
    for (int d = lane; d < C2_; d += 64) s += db[d] * wr[d];
#pragma unroll
    for (int off = 32; off; off >>= 1) s += __shfl_xor(s, off);
    if (lane == 0) dvp[c] = ab[c] + s;
    return;
  }
  bid -= 512;
  // feat_map transpose (C,H,W) -> (H*W, C)
  {
    int yx0 = (bid & 31) * 32, c0 = (bid >> 5) * 32;
    int tx = threadIdx.x & 31, ty = threadIdx.x >> 5;
#pragma unroll
    for (int i = 0; i < 4; i++)
      tile[ty + 8 * i][tx] = feat_map[(size_t)(c0 + ty + 8 * i) * 1024 + yx0 + tx];
    __syncthreads();
#pragma unroll
    for (int i = 0; i < 4; i++)
      fmT[(size_t)(yx0 + ty + 8 * i) * 1024 + c0 + tx] = tile[tx][ty + 8 * i];
  }
}

// ================= merged: FPS0 + Wc combine GEMMs + bilinear ================================
// FPS0 (latency-serial, prio 3) overlaps the memory-bound Wc/bilinear blocks which leave
// issue slots free. blocks: [0,32) FPS0 | [32,104) Wc0 | [104,176) Wc1 | [176,176+16384) bilinear
__global__ __launch_bounds__(256) void k_wc_bil(
    const ushort* __restrict__ awdb0, const ushort* __restrict__ dwT0, ushort* __restrict__ Wcb0,
    const ushort* __restrict__ awdb1, const ushort* __restrict__ dwT1, ushort* __restrict__ Wcb1,
    const float* __restrict__ points, const float* __restrict__ fmT, ushort* __restrict__ Xb0,
    int* __restrict__ rows0) {
  __shared__ ushort As[4096];
  __shared__ ushort Bs[4096];
  int bid = blockIdx.x;
  if (bid < 32) {
    if (threadIdx.x < 64) dev_fps<8>(bid, N_, S0_, points, 2, rows0);
    return;
  }
  bid -= 32;
  if (bid < 72) {
    dev_mgemm<1>(bid / 8, bid % 8, 0, 1, As, Bs, C_, C2_, LDP_, awdb0, LDP_, nullptr, dwT0, LDP_,
                 nullptr, Wcb0, LDP_, LDP_);
  } else if (bid < 144) {
    int b2 = bid - 72;
    dev_mgemm<1>(b2 / 8, b2 % 8, 0, 1, As, Bs, C_, C2_, LDP_, awdb1, LDP_, nullptr, dwT1, LDP_,
                 nullptr, Wcb1, LDP_, LDP_);
  } else {
    dev_bilinear(bid - 144, points, fmT, Xb0);
  }
}

// ================= merged: FPS (prio 3) + G-GEMM (XCD row-major mapping) ====================
template <int NPL>
__global__ __launch_bounds__(256) void k_gemm_fps(int nrb, int Mg, const ushort* __restrict__ A,
                                                  int lda, const ushort* __restrict__ Wt,
                                                  ushort* __restrict__ Gout, int Np, int nsub,
                                                  const float* __restrict__ pts, int stride,
                                                  int* __restrict__ rows) {
  __shared__ ushort As[4096];
  __shared__ ushort Bs[4096];
  int bid = blockIdx.x;
  if (bid < 32) {
    if (threadIdx.x < 64) dev_fps<NPL>(bid, Np, nsub, pts, stride, rows);
    return;
  }
  int b2 = bid - 32;
  dev_mgemm<1>(b2 / nrb, b2 % nrb, 0, 1, As, Bs, Mg, C_, LDP_, A, lda, nullptr, Wt, LDP_, nullptr,
               Gout, C_, LDP_);
}

// ================= merged: P-GEMM (XCD row-major) + kNN (4 queries/block) ===================
template <int NPL>
__global__ __launch_bounds__(256) void k_gemm_knn(int nrb, int Mp, const ushort* __restrict__ A,
                                                  int lda, const int* __restrict__ rowsA,
                                                  const ushort* __restrict__ Wt,
                                                  const float* __restrict__ bias,
                                                  ushort* __restrict__ Pout, int ngemm, int S,
                                                  int Np, const float* __restrict__ pts,
                                                  int stride, const int* __restrict__ rows,
                                                  int* __restrict__ nn) {
  __shared__ ushort As[4096];
  __shared__ ushort Bs[4096];
  int bid = blockIdx.x;
  if (bid < ngemm) {
    dev_mgemm<2>(bid / nrb, bid % nrb, 0, 1, As, Bs, Mp, C_, LDP_, A, lda, rowsA, Wt, LDP_, bias,
                 Pout, C_, LDP_);
  } else {
    int w = threadIdx.x >> 6;
    int qid = (bid - ngemm) * 4 + w;
    dev_knn<NPL>(qid, S, Np, pts, stride, rows, nn);
  }
}

// ================= flat head GEMM with fused f32->bf16 W conversion =========================
__global__ __launch_bounds__(256) void k_flat(const ushort* __restrict__ A,  // [32][65536] bf16
                                              const float* __restrict__ W,   // [1024][65536] f32
                                              float* __restrict__ Cp) {      // [32][32][1024]
  int t = threadIdx.x;
  int w = t >> 6, l = t & 63;
  int fr = l & 15, fg = l >> 4;
  int col0 = blockIdx.x * 128 + w * 32;
  size_t k0 = (size_t)blockIdx.z * 2048;
  f32x4 acc[2][2];
#pragma unroll
  for (int i = 0; i < 2; i++)
#pragma unroll
    for (int j = 0; j < 2; j++) acc[i][j] = (f32x4){0.f, 0.f, 0.f, 0.f};
  const ushort* a0 = A + (size_t)fr * 65536 + k0 + fg * 8;
  const ushort* a1 = A + (size_t)(16 + fr) * 65536 + k0 + fg * 8;
  const float* b0 = W + (size_t)(col0 + fr) * 65536 + k0 + fg * 8;
  const float* b1 = W + (size_t)(col0 + 16 + fr) * 65536 + k0 + fg * 8;
  for (int kt = 0; kt < 2048; kt += 32) {
    short8 af0 = *(const short8*)(a0 + kt);
    short8 af1 = *(const short8*)(a1 + kt);
    float4 p0 = *(const float4*)(b0 + kt);
    float4 p1 = *(const float4*)(b0 + kt + 4);
    float4 q0 = *(const float4*)(b1 + kt);
    float4 q1 = *(const float4*)(b1 + kt + 4);
    short8 bf0, bf1;
    bf0[0] = (short)f2bf(p0.x); bf0[1] = (short)f2bf(p0.y);
    bf0[2] = (short)f2bf(p0.z); bf0[3] = (short)f2bf(p0.w);
    bf0[4] = (short)f2bf(p1.x); bf0[5] = (short)f2bf(p1.y);
    bf0[6] = (short)f2bf(p1.z); bf0[7] = (short)f2bf(p1.w);
    bf1[0] = (short)f2bf(q0.x); bf1[1] = (short)f2bf(q0.y);
    bf1[2] = (short)f2bf(q0.z); bf1[3] = (short)f2bf(q0.w);
    bf1[4] = (short)f2bf(q1.x); bf1[5] = (short)f2bf(q1.y);
    bf1[6] = (short)f2bf(q1.z); bf1[7] = (short)f2bf(q1.w);
    acc[0][0] = __builtin_amdgcn_mfma_f32_16x16x32_bf16(af0, bf0, acc[0][0], 0, 0, 0);
    acc[1][0] = __builtin_amdgcn_mfma_f32_16x16x32_bf16(af1, bf0, acc[1][0], 0, 0, 0);
    acc[0][1] = __builtin_amdgcn_mfma_f32_16x16x32_bf16(af0, bf1, acc[0][1], 0, 0, 0);
    acc[1][1] = __builtin_amdgcn_mfma_f32_16x16x32_bf16(af1, bf1, acc[1][1], 0, 0, 0);
  }
  float* Cz = Cp + (size_t)blockIdx.z * 32 * 1024;
#pragma unroll
  for (int mi = 0; mi < 2; mi++)
#pragma unroll
    for (int ni = 0; ni < 2; ni++)
#pragma unroll
      for (int q = 0; q < 4; q++) {
        int r = mi * 16 + fg * 4 + q;
        int c = col0 + ni * 16 + fr;
        Cz[(size_t)r * 1024 + c] = acc[mi][ni][q];
      }
}

// ================= fused stage: wave-per-k, barrier-free k-loop =============================
__global__ __launch_bounds__(256) void k_fused_stage(
    const ushort* __restrict__ G, const ushort* __restrict__ Pb, const int* __restrict__ rows,
    const int* __restrict__ nn, const float* __restrict__ lng, const float* __restrict__ lnb,
    const float* __restrict__ prev_pts, int pts_stride, ushort* __restrict__ Xout, int ld_out,
    float* __restrict__ coords_out) {
  __shared__ float sm[4][1024];
  int bs = blockIdx.x;
  int t = threadIdx.x;
  int w = t >> 6, lane = t & 63;
  int c0 = lane * 16;
  int arow = rows[bs];
  float base[16], lg[16], lb[16], acc[16];
  {
    short8 pA = *(const short8*)(Pb + (size_t)bs * C_ + c0);
    short8 pB = *(const short8*)(Pb + (size_t)bs * C_ + c0 + 8);
    short8 gA = *(const short8*)(G + (size_t)arow * C_ + c0);
    short8 gB = *(const short8*)(G + (size_t)arow * C_ + c0 + 8);
#pragma unroll
    for (int i = 0; i < 8; i++) {
      base[i] = bf2f((ushort)pA[i]) - bf2f((ushort)gA[i]);
      base[8 + i] = bf2f((ushort)pB[i]) - bf2f((ushort)gB[i]);
    }
#pragma unroll
    for (int i = 0; i < 4; i++) {
      float4 gv = *(const float4*)(lng + c0 + 4 * i);
      float4 bv = *(const float4*)(lnb + c0 + 4 * i);
      lg[4 * i] = gv.x; lg[4 * i + 1] = gv.y; lg[4 * i + 2] = gv.z; lg[4 * i + 3] = gv.w;
      lb[4 * i] = bv.x; lb[4 * i + 1] = bv.y; lb[4 * i + 2] = bv.z; lb[4 * i + 3] = bv.w;
      acc[4 * i] = -INFINITY; acc[4 * i + 1] = -INFINITY;
      acc[4 * i + 2] = -INFINITY; acc[4 * i + 3] = -INFINITY;
    }
  }
#pragma unroll
  for (int kk = 0; kk < 4; kk++) {
    int g = nn[bs * K_ + w * 4 + kk];
    const ushort* Gr = G + (size_t)g * C_ + c0;
    short8 xA = *(const short8*)(Gr);
    short8 xB = *(const short8*)(Gr + 8);
    float v[16];
    float s1 = 0.f, s2 = 0.f;
#pragma unroll
    for (int i = 0; i < 8; i++) {
      float x = fmaxf(bf2f((ushort)xA[i]) + base[i], 0.f);
      v[i] = x; s1 += x; s2 += x * x;
      float y = fmaxf(bf2f((ushort)xB[i]) + base[8 + i], 0.f);
      v[8 + i] = y; s1 += y; s2 += y * y;
    }
#pragma unroll
    for (int off = 32; off; off >>= 1) {
      s1 += __shfl_xor(s1, off);
      s2 += __shfl_xor(s2, off);
    }
    float mu = s1 * (1.f / 1024.f);
    float var = s2 * (1.f / 1024.f) - mu * mu;
    float rstd = 1.f / sqrtf(var + 1e-5f);
#pragma unroll
    for (int i = 0; i < 16; i++) {
      float nv = (v[i] - mu) * rstd * lg[i] + lb[i];
      acc[i] = fmaxf(acc[i], nv);
    }
  }
#pragma unroll
  for (int i = 0; i < 16; i += 4) {
    f32x4 av = {acc[i], acc[i + 1], acc[i + 2], acc[i + 3]};
    *(f32x4*)&sm[w][c0 + i] = av;
  }
  __syncthreads();
  {
    int cc = t * 4;
    f32x4 m0 = *(const f32x4*)&sm[0][cc];
    f32x4 m1 = *(const f32x4*)&sm[1][cc];
    f32x4 m2 = *(const f32x4*)&sm[2][cc];
    f32x4 m3 = *(const f32x4*)&sm[3][cc];
    ushort o[4];
#pragma unroll
    for (int j = 0; j < 4; j++)
      o[j] = f2bf(fmaxf(fmaxf(m0[j], m1[j]), fmaxf(m2[j], m3[j])));
    uint2 uv = {(unsigned)o[0] | ((unsigned)o[1] << 16), (unsigned)o[2] | ((unsigned)o[3] << 16)};
    *(uint2*)(Xout + (size_t)bs * ld_out + cc) = uv;
  }
  if (prev_pts) {
    float p0 = prev_pts[(size_t)arow * pts_stride + 0];
    float p1 = prev_pts[(size_t)arow * pts_stride + 1];
    if (t == 0) {
      Xout[(size_t)bs * ld_out + 1024] = f2bf(p0);
      Xout[(size_t)bs * ld_out + 1025] = f2bf(p1);
      coords_out[bs * 2 + 0] = p0;
      coords_out[bs * 2 + 1] = p1;
    }
    if (t < 126) Xout[(size_t)bs * ld_out + 1026 + t] = 0;
  }
}

// ================= reduce K-split partials + bias; OUTBF: write bf16 ========================
template <int OUTBF>
__global__ __launch_bounds__(256) void k_reduce(int total, int Ncols, int nz,
                                                const float* __restrict__ part,
                                                const float* __restrict__ bias,
                                                void* __restrict__ out) {
  int i = blockIdx.x * 256 + threadIdx.x;
  if (i >= total) return;
  float s = bias[i % Ncols];
  for (int z = 0; z < nz; z++) s += part[(size_t)z * total + i];
  if (OUTBF)
    ((ushort*)out)[i] = f2bf(s);
  else
    ((float*)out)[i] = s;
}

// ================= launch ====================================================================
extern "C" void kernel_launch(void* const* d_in, const int* in_sizes, int n_in, void* d_out,
                              int out_size, void* d_ws, size_t ws_size, hipStream_t stream) {
  (void)in_sizes; (void)n_in; (void)out_size; (void)ws_size;
  const float* points = (const float*)d_in[0];
  const float* feat_map = (const float*)d_in[1];
  const float* dw0 = (const float*)d_in[2];
  const float* db0 = (const float*)d_in[3];
  const float* aw0 = (const float*)d_in[4];
  const float* ab0 = (const float*)d_in[5];
  const float* lg0 = (const float*)d_in[6];
  const float* lb0 = (const float*)d_in[7];
  const float* dw1 = (const float*)d_in[8];
  const float* db1 = (const float*)d_in[9];
  const float* aw1 = (const float*)d_in[10];
  const float* ab1 = (const float*)d_in[11];
  const float* lg1 = (const float*)d_in[12];
  const float* lb1 = (const float*)d_in[13];
  const float* fw = (const float*)d_in[14];
  const float* fb = (const float*)d_in[15];
  const float* dmw = (const float*)d_in[16];
  const float* dmb = (const float*)d_in[17];
  float* out = (float*)d_out;

  char* wsb = (char*)d_ws;
  size_t off = 0;
  auto alloc = [&](size_t bytes) -> void* {
    void* p = wsb + off;
    off = (off + bytes + 255) & ~(size_t)255;
    return p;
  };
  float* fmT = (float*)alloc((size_t)1024 * 1024 * 4);
  ushort* Xb0 = (ushort*)alloc((size_t)B_ * N_ * LDP_ * 2);
  ushort* Gb = (ushort*)alloc((size_t)B_ * N_ * C_ * 2);
  ushort* Pb = (ushort*)alloc((size_t)B_ * S0_ * C_ * 2);
  ushort* Xb1 = (ushort*)alloc((size_t)B_ * S0_ * LDP_ * 2);
  ushort* fts2b = (ushort*)alloc((size_t)B_ * S1_ * C_ * 2);
  float* coords1 = (float*)alloc((size_t)B_ * S0_ * 2 * 4);
  ushort* awdb0 = (ushort*)alloc((size_t)C_ * LDP_ * 2);
  ushort* awab0 = (ushort*)alloc((size_t)C_ * LDP_ * 2);
  ushort* awdb1 = (ushort*)alloc((size_t)C_ * LDP_ * 2);
  ushort* awab1 = (ushort*)alloc((size_t)C_ * LDP_ * 2);
  ushort* dwT0 = (ushort*)alloc((size_t)LDP_ * LDP_ * 2);
  ushort* dwT1 = (ushort*)alloc((size_t)LDP_ * LDP_ * 2);
  ushort* Wcb0 = (ushort*)alloc((size_t)C_ * LDP_ * 2);
  ushort* Wcb1 = (ushort*)alloc((size_t)C_ * LDP_ * 2);
  ushort* dmwb = (ushort*)alloc((size_t)OUT_ * C_ * 2);
  float* dvp0 = (float*)alloc(1024 * 4);
  float* dvp1 = (float*)alloc(1024 * 4);
  int* rows0 = (int*)alloc(B_ * S0_ * 4);
  int* nn0 = (int*)alloc(B_ * S0_ * K_ * 4);
  int* rows1 = (int*)alloc(B_ * S1_ * 4);
  int* nn1 = (int*)alloc(B_ * S1_ * K_ * 4);
  float* hpart = (float*)alloc((size_t)32 * B_ * C_ * 4);
  ushort* hidb = (ushort*)alloc((size_t)B_ * C_ * 2);
  float* opart = (float*)alloc((size_t)4 * B_ * OUT_ * 4);

  // 1) weight prep + feat_map transpose
  k_prep<<<PREP_TOTAL, 256, 0, stream>>>(aw0, aw1, dmw, dw0, dw1, db0, ab0, db1, ab1, feat_map,
                                         awdb0, awab0, awdb1, awab1, dmwb, dwT0, dwT1, dvp0, dvp1,
                                         fmT);
  // 2) FPS0 (prio 3) || Wc combine GEMMs || bilinear sample
  k_wc_bil<<<32 + 144 + B_ * N_, 256, 0, stream>>>(awdb0, dwT0, Wcb0, awdb1, dwT1, Wcb1, points,
                                                   fmT, Xb0, rows0);
  // 3) stage 0: G0 pure GEMM, XCD row-major (grid.x = 128 rows, grid.y = 8 cols)
  {
    dim3 g((B_ * N_) / 128, C_ / 128, 1);
    k_mgemm2<1><<<g, 256, 0, stream>>>(B_ * N_, C_, LDP_, Xb0, LDP_, nullptr, Wcb0, LDP_, nullptr,
                                       Gb, C_, LDP_);
  }
  // 4) stage 0: P0 GEMM (nrb=64) || kNN0
  k_gemm_knn<8><<<512 + (B_ * S0_) / 4, 256, 0, stream>>>(64, B_ * S0_, Xb0, LDP_, rows0, awab0,
                                                          dvp0, Pb, 512, S0_, N_, points, 2,
                                                          rows0, nn0);
  // 5) fused stage 0
  k_fused_stage<<<B_ * S0_, 256, 0, stream>>>(Gb, Pb, rows0, nn0, lg0, lb0, points, 2, Xb1, LDP_,
                                              coords1);
  // 6) stage 1: FPS1 (prio 3) || G1 GEMM (nrb=64)
  k_gemm_fps<4><<<32 + 512, 256, 0, stream>>>(64, B_ * S0_, Xb1, LDP_, Wcb1, Gb, S0_, S1_,
                                              coords1, 2, rows1);
  // 7) stage 1: P1 GEMM (nrb=16) || kNN1
  k_gemm_knn<4><<<128 + (B_ * S1_) / 4, 256, 0, stream>>>(16, B_ * S1_, Xb1, LDP_, rows1, awab1,
                                                          dvp1, Pb, 128, S1_, S0_, coords1, 2,
                                                          rows1, nn1);
  // 8) fused stage 1
  k_fused_stage<<<B_ * S1_, 256, 0, stream>>>(Gb, Pb, rows1, nn1, lg1, lb1, nullptr, 0, fts2b, C_,
                                              nullptr);
  // 9) flat head (fused f32 W conversion), K-split 32 x 2048
  {
    dim3 g(8, 1, 32);
    k_flat<<<g, 256, 0, stream>>>(fts2b, fw, hpart);
  }
  // 10) reduce -> hid (bf16)
  k_reduce<1><<<(B_ * C_ + 255) / 256, 256, 0, stream>>>(B_ * C_, C_, 32, hpart, fb, hidb);
  // 11) dim head: M=32, K=1024, z-split 4 x 256
  {
    dim3 g(OUT_ / 128, 1, 4);
    k_mgemm<0><<<g, 256, 0, stream>>>(B_, OUT_, C_, hidb, C_, nullptr, dmwb, C_, nullptr, opart,
                                      OUT_, 256);
  }
  // 12) reduce -> out
  k_reduce<0><<<(B_ * OUT_ + 255) / 256, 256, 0, stream>>>(B_ * OUT_, OUT_, 4, opart, dmb, out);
}